// Round 10
// baseline (1035.890 us; speedup 1.0000x reference)
//
#include <hip/hip_runtime.h>
#include <hip/hip_cooperative_groups.h>
#include <cstdint>
#include <cstddef>

namespace cg = cooperative_groups;

typedef unsigned short ushort;
typedef __attribute__((ext_vector_type(8))) short bf16x8;
typedef __attribute__((ext_vector_type(8))) unsigned short ushort8v;
typedef __attribute__((ext_vector_type(4))) float f32x4;

// 1/sqrt(1+1e-5)
#define BN_INV 0.9999950000374997f

__device__ inline ushort f2bf(float f) {
    union { float f; unsigned u; } x; x.f = f;
    unsigned r = x.u + 0x7fffu + ((x.u >> 16) & 1u);
    return (ushort)(r >> 16);
}
__device__ inline float bf2f(ushort u) {
    union { unsigned u; float f; } x; x.u = ((unsigned)u) << 16;
    return x.f;
}

// async global->LDS, 16B per lane. LDS dest is wave-uniform base + lane*16.
__device__ __forceinline__ void gload16(const void* g, void* l) {
    __builtin_amdgcn_global_load_lds(
        (const __attribute__((address_space(1))) unsigned int*)g,
        (__attribute__((address_space(3))) unsigned int*)l, 16, 0, 0);
}

// ======================= MFMA bf16 GEMM ====================================
// C[M,N] = A[M,K] @ B[N,K]^T.  B always bf16.
// AMODE 0: A bf16 via global_load_lds w/ pre-swizzled source.
// AMODE 1: A f32 (reg-converted), reg-staged swizzled LDS writes.
// XCD-chunked bijective swizzle, N-INNER (A panels L2-resident, B via L3).
// EPIL 5: split-write at N/2: n<N/2 -> C, else -> C2 (row stride N/2)
template<int AMODE, int EPIL, typename OutT>
__global__ __launch_bounds__(256)
void mgemm(const void* __restrict__ Asrc, const ushort* __restrict__ Bsrc,
           OutT* __restrict__ C, int M, int N, int K,
           const float* __restrict__ bias, ushort* __restrict__ C2)
{
    __shared__ ushort As[128 * 64];
    __shared__ ushort Bs[128 * 64];

    const int tid  = threadIdx.x;
    const int lane = tid & 63;
    const int wid  = tid >> 6;
    const int wr   = wid >> 1;
    const int wc   = wid & 1;

    const int nwg  = gridDim.x * gridDim.y;
    const int orig = blockIdx.y * gridDim.x + blockIdx.x;
    const int q    = nwg >> 3, r = nwg & 7;
    const int xcd  = orig & 7, ii = orig >> 3;
    const int wg   = (xcd < r ? xcd * (q + 1) : r * (q + 1) + (xcd - r) * q) + ii;
    const int m0   = (wg / gridDim.x) * 128;
    const int n0   = (wg % gridDim.x) * 128;

    const int lr  = lane & 15;
    const int lg  = lane >> 4;
    const int swz = (lr & 7) << 4;

    f32x4 acc[4][4];
#pragma unroll
    for (int i = 0; i < 4; i++)
#pragma unroll
        for (int j = 0; j < 4; j++) acc[i][j] = (f32x4){0.f, 0.f, 0.f, 0.f};

    for (int k0 = 0; k0 < K; k0 += 64) {
        if (k0) __syncthreads();
        if constexpr (AMODE == 0) {
#pragma unroll
            for (int i = 0; i < 4; i++) {
                int ch = i * 256 + tid;
                int rr = ch >> 3, c8 = ch & 7;
                int c8p = c8 ^ (rr & 7);
                int srow = m0 + rr; if (srow > M - 1) srow = M - 1;
                gload16((const ushort*)Asrc + (size_t)srow * K + k0 + c8p * 8,
                        (char*)As + (i * 256 + wid * 64) * 16);
                gload16(Bsrc + (size_t)(n0 + rr) * K + k0 + c8p * 8,
                        (char*)Bs + (i * 256 + wid * 64) * 16);
            }
        } else {
#pragma unroll
            for (int i = 0; i < 4; i++) {
                int ch = i * 256 + tid;
                int rr = ch >> 3, c8 = ch & 7;
                int lb = rr * 128 + ((c8 * 16) ^ ((rr & 7) << 4));
                int srow = m0 + rr; if (srow > M - 1) srow = M - 1;
                const float* ap = (const float*)Asrc + (size_t)srow * K + k0 + c8 * 8;
                float4 f0 = *(const float4*)ap;
                float4 f1 = *(const float4*)(ap + 4);
                ushort8v va;
                va[0] = f2bf(f0.x); va[1] = f2bf(f0.y); va[2] = f2bf(f0.z); va[3] = f2bf(f0.w);
                va[4] = f2bf(f1.x); va[5] = f2bf(f1.y); va[6] = f2bf(f1.z); va[7] = f2bf(f1.w);
                *(ushort8v*)((char*)As + lb) = va;
                ushort8v vb = *(const ushort8v*)(Bsrc + (size_t)(n0 + rr) * K + k0 + c8 * 8);
                *(ushort8v*)((char*)Bs + lb) = vb;
            }
        }
        __syncthreads();

        const char* Ab = (const char*)As + (wr * 64 + lr) * 128;
        const char* Bb = (const char*)Bs + (wc * 64 + lr) * 128;
#pragma unroll
        for (int ks = 0; ks < 2; ks++) {
            int kx = (ks * 64 + lg * 16) ^ swz;
            bf16x8 a0 = *(const bf16x8*)(Ab + 0 * 2048 + kx);
            bf16x8 a1 = *(const bf16x8*)(Ab + 1 * 2048 + kx);
            bf16x8 a2 = *(const bf16x8*)(Ab + 2 * 2048 + kx);
            bf16x8 a3 = *(const bf16x8*)(Ab + 3 * 2048 + kx);
            bf16x8 b0 = *(const bf16x8*)(Bb + 0 * 2048 + kx);
            bf16x8 b1 = *(const bf16x8*)(Bb + 1 * 2048 + kx);
            bf16x8 b2 = *(const bf16x8*)(Bb + 2 * 2048 + kx);
            bf16x8 b3 = *(const bf16x8*)(Bb + 3 * 2048 + kx);
            acc[0][0] = __builtin_amdgcn_mfma_f32_16x16x32_bf16(a0, b0, acc[0][0], 0, 0, 0);
            acc[0][1] = __builtin_amdgcn_mfma_f32_16x16x32_bf16(a0, b1, acc[0][1], 0, 0, 0);
            acc[0][2] = __builtin_amdgcn_mfma_f32_16x16x32_bf16(a0, b2, acc[0][2], 0, 0, 0);
            acc[0][3] = __builtin_amdgcn_mfma_f32_16x16x32_bf16(a0, b3, acc[0][3], 0, 0, 0);
            acc[1][0] = __builtin_amdgcn_mfma_f32_16x16x32_bf16(a1, b0, acc[1][0], 0, 0, 0);
            acc[1][1] = __builtin_amdgcn_mfma_f32_16x16x32_bf16(a1, b1, acc[1][1], 0, 0, 0);
            acc[1][2] = __builtin_amdgcn_mfma_f32_16x16x32_bf16(a1, b2, acc[1][2], 0, 0, 0);
            acc[1][3] = __builtin_amdgcn_mfma_f32_16x16x32_bf16(a1, b3, acc[1][3], 0, 0, 0);
            acc[2][0] = __builtin_amdgcn_mfma_f32_16x16x32_bf16(a2, b0, acc[2][0], 0, 0, 0);
            acc[2][1] = __builtin_amdgcn_mfma_f32_16x16x32_bf16(a2, b1, acc[2][1], 0, 0, 0);
            acc[2][2] = __builtin_amdgcn_mfma_f32_16x16x32_bf16(a2, b2, acc[2][2], 0, 0, 0);
            acc[2][3] = __builtin_amdgcn_mfma_f32_16x16x32_bf16(a2, b3, acc[2][3], 0, 0, 0);
            acc[3][0] = __builtin_amdgcn_mfma_f32_16x16x32_bf16(a3, b0, acc[3][0], 0, 0, 0);
            acc[3][1] = __builtin_amdgcn_mfma_f32_16x16x32_bf16(a3, b1, acc[3][1], 0, 0, 0);
            acc[3][2] = __builtin_amdgcn_mfma_f32_16x16x32_bf16(a3, b2, acc[3][2], 0, 0, 0);
            acc[3][3] = __builtin_amdgcn_mfma_f32_16x16x32_bf16(a3, b3, acc[3][3], 0, 0, 0);
        }
    }

#pragma unroll
    for (int mi = 0; mi < 4; mi++) {
#pragma unroll
        for (int ni = 0; ni < 4; ni++) {
            f32x4 a = acc[mi][ni];
            int n = n0 + wc * 64 + ni * 16 + lr;
#pragma unroll
            for (int j = 0; j < 4; j++) {
                int m = m0 + wr * 64 + mi * 16 + lg * 4 + j;
                if (m >= M) continue;
                float v = a[j];
                if (EPIL == 5) {
                    int half = N >> 1;
                    ushort* dst = (n < half) ? (ushort*)C : C2;
                    dst[(size_t)m * half + (n & (half - 1))] = f2bf(v);
                } else {
                    if (sizeof(OutT) == 2) ((ushort*)C)[(size_t)m * N + n] = f2bf(v);
                    else                   ((float*)C)[(size_t)m * N + n] = v;
                }
            }
        }
    }
}

// ==== fused gather + SAGE-1 epilogue: H1 = bn(relu(mean_j YL_j + b1 + YR)) ==
__global__ void gather_h1(const ushort* __restrict__ YL, const int* __restrict__ eidx,
                          const int* __restrict__ off, const ushort* __restrict__ YR,
                          const float* __restrict__ b1, const float* __restrict__ g,
                          const float* __restrict__ bb, ushort* __restrict__ H1)
{
    int n = blockIdx.x;
    int beg = off[n], end = off[n + 1];
    float inv = 1.f / fmaxf((float)(end - beg), 1.f);
    float s0 = 0, s1 = 0, s2 = 0, s3 = 0, s4 = 0, s5 = 0, s6 = 0, s7 = 0;
    for (int e = beg; e < end; e++) {
        ushort8v v = *(const ushort8v*)(YL + (size_t)eidx[e] * 1024 + threadIdx.x * 8);
        s0 += bf2f(v[0]); s1 += bf2f(v[1]); s2 += bf2f(v[2]); s3 += bf2f(v[3]);
        s4 += bf2f(v[4]); s5 += bf2f(v[5]); s6 += bf2f(v[6]); s7 += bf2f(v[7]);
    }
    float sv[8] = {s0, s1, s2, s3, s4, s5, s6, s7};
    ushort8v yr = *(const ushort8v*)(YR + (size_t)n * 1024 + threadIdx.x * 8);
    ushort8v o;
#pragma unroll
    for (int qq = 0; qq < 8; qq++) {
        int c = threadIdx.x * 8 + qq;
        float v = sv[qq] * inv + b1[c] + bf2f(yr[qq]);
        v = fmaxf(v, 0.f);
        v = g[c] * v * BN_INV + bb[c];
        o[qq] = f2bf(v);
    }
    *(ushort8v*)(H1 + (size_t)n * 1024 + threadIdx.x * 8) = o;
}

// ==== fused gather + SAGE-2 epilogue: XB = mean_j ZL_j + b2 + ZR ===========
__global__ void gather_xb(const ushort* __restrict__ ZL, const int* __restrict__ eidx,
                          const int* __restrict__ off, const ushort* __restrict__ ZR,
                          const float* __restrict__ b2, ushort* __restrict__ XB)
{
    int n = blockIdx.x;
    int beg = off[n], end = off[n + 1];
    float inv = 1.f / fmaxf((float)(end - beg), 1.f);
    float s0 = 0, s1 = 0, s2 = 0, s3 = 0, s4 = 0, s5 = 0, s6 = 0, s7 = 0;
    for (int e = beg; e < end; e++) {
        ushort8v v = *(const ushort8v*)(ZL + (size_t)eidx[e] * 512 + threadIdx.x * 8);
        s0 += bf2f(v[0]); s1 += bf2f(v[1]); s2 += bf2f(v[2]); s3 += bf2f(v[3]);
        s4 += bf2f(v[4]); s5 += bf2f(v[5]); s6 += bf2f(v[6]); s7 += bf2f(v[7]);
    }
    float sv[8] = {s0, s1, s2, s3, s4, s5, s6, s7};
    ushort8v zr = *(const ushort8v*)(ZR + (size_t)n * 512 + threadIdx.x * 8);
    ushort8v o;
#pragma unroll
    for (int qq = 0; qq < 8; qq++) {
        int c = threadIdx.x * 8 + qq;
        o[qq] = f2bf(sv[qq] * inv + b2[c] + bf2f(zr[qq]));
    }
    *(ushort8v*)(XB + (size_t)n * 512 + threadIdx.x * 8) = o;
}

// ==== fused attention MLP: A2 = tanh(XB@FA1^T + b1f)@FA2^T + b2f ===========
// one block per 128 rows; GEMM1 K=512, GEMM2 K=128 with A1 held in LDS bf16.
__global__ __launch_bounds__(256)
void attn_a1a2(const ushort* __restrict__ XB, const ushort* __restrict__ FA1,
               const float* __restrict__ fa1b, const ushort* __restrict__ FA2,
               const float* __restrict__ fa2b, float* __restrict__ A2, int M)
{
    __shared__ ushort As[128 * 64];
    __shared__ ushort Bs[128 * 64];
    __shared__ ushort A1a[128 * 64];
    __shared__ ushort A1b[128 * 64];

    const int tid  = threadIdx.x;
    const int lane = tid & 63;
    const int wid  = tid >> 6;
    const int wr   = wid >> 1;
    const int wc   = wid & 1;
    const int m0   = blockIdx.x * 128;
    const int lr   = lane & 15;
    const int lg   = lane >> 4;
    const int swz  = (lr & 7) << 4;

    f32x4 acc[4][4];
#pragma unroll
    for (int i = 0; i < 4; i++)
#pragma unroll
        for (int j = 0; j < 4; j++) acc[i][j] = (f32x4){0.f, 0.f, 0.f, 0.f};

    // ---- GEMM1: XB[128,512] @ FA1[128,512]^T ----
    for (int k0 = 0; k0 < 512; k0 += 64) {
        if (k0) __syncthreads();
#pragma unroll
        for (int i = 0; i < 4; i++) {
            int ch = i * 256 + tid;
            int rr = ch >> 3, c8 = ch & 7;
            int c8p = c8 ^ (rr & 7);
            int srow = m0 + rr; if (srow > M - 1) srow = M - 1;
            gload16(XB + (size_t)srow * 512 + k0 + c8p * 8,
                    (char*)As + (i * 256 + wid * 64) * 16);
            gload16(FA1 + (size_t)rr * 512 + k0 + c8p * 8,
                    (char*)Bs + (i * 256 + wid * 64) * 16);
        }
        __syncthreads();
        const char* Ab = (const char*)As + (wr * 64 + lr) * 128;
        const char* Bb = (const char*)Bs + (wc * 64 + lr) * 128;
#pragma unroll
        for (int ks = 0; ks < 2; ks++) {
            int kx = (ks * 64 + lg * 16) ^ swz;
            bf16x8 a0 = *(const bf16x8*)(Ab + 0 * 2048 + kx);
            bf16x8 a1 = *(const bf16x8*)(Ab + 1 * 2048 + kx);
            bf16x8 a2 = *(const bf16x8*)(Ab + 2 * 2048 + kx);
            bf16x8 a3 = *(const bf16x8*)(Ab + 3 * 2048 + kx);
            bf16x8 b0 = *(const bf16x8*)(Bb + 0 * 2048 + kx);
            bf16x8 b1 = *(const bf16x8*)(Bb + 1 * 2048 + kx);
            bf16x8 b2 = *(const bf16x8*)(Bb + 2 * 2048 + kx);
            bf16x8 b3 = *(const bf16x8*)(Bb + 3 * 2048 + kx);
            acc[0][0] = __builtin_amdgcn_mfma_f32_16x16x32_bf16(a0, b0, acc[0][0], 0, 0, 0);
            acc[0][1] = __builtin_amdgcn_mfma_f32_16x16x32_bf16(a0, b1, acc[0][1], 0, 0, 0);
            acc[0][2] = __builtin_amdgcn_mfma_f32_16x16x32_bf16(a0, b2, acc[0][2], 0, 0, 0);
            acc[0][3] = __builtin_amdgcn_mfma_f32_16x16x32_bf16(a0, b3, acc[0][3], 0, 0, 0);
            acc[1][0] = __builtin_amdgcn_mfma_f32_16x16x32_bf16(a1, b0, acc[1][0], 0, 0, 0);
            acc[1][1] = __builtin_amdgcn_mfma_f32_16x16x32_bf16(a1, b1, acc[1][1], 0, 0, 0);
            acc[1][2] = __builtin_amdgcn_mfma_f32_16x16x32_bf16(a1, b2, acc[1][2], 0, 0, 0);
            acc[1][3] = __builtin_amdgcn_mfma_f32_16x16x32_bf16(a1, b3, acc[1][3], 0, 0, 0);
            acc[2][0] = __builtin_amdgcn_mfma_f32_16x16x32_bf16(a2, b0, acc[2][0], 0, 0, 0);
            acc[2][1] = __builtin_amdgcn_mfma_f32_16x16x32_bf16(a2, b1, acc[2][1], 0, 0, 0);
            acc[2][2] = __builtin_amdgcn_mfma_f32_16x16x32_bf16(a2, b2, acc[2][2], 0, 0, 0);
            acc[2][3] = __builtin_amdgcn_mfma_f32_16x16x32_bf16(a2, b3, acc[2][3], 0, 0, 0);
            acc[3][0] = __builtin_amdgcn_mfma_f32_16x16x32_bf16(a3, b0, acc[3][0], 0, 0, 0);
            acc[3][1] = __builtin_amdgcn_mfma_f32_16x16x32_bf16(a3, b1, acc[3][1], 0, 0, 0);
            acc[3][2] = __builtin_amdgcn_mfma_f32_16x16x32_bf16(a3, b2, acc[3][2], 0, 0, 0);
            acc[3][3] = __builtin_amdgcn_mfma_f32_16x16x32_bf16(a3, b3, acc[3][3], 0, 0, 0);
        }
    }

    // tanh + bias -> A1 in LDS (swizzled bf16, two 64-col halves)
#pragma unroll
    for (int mi = 0; mi < 4; mi++)
#pragma unroll
    for (int ni = 0; ni < 4; ni++) {
        f32x4 a = acc[mi][ni];
        int n = wc * 64 + ni * 16 + lr;
        ushort* buf = (n < 64) ? A1a : A1b;
        int c = n & 63;
#pragma unroll
        for (int j = 0; j < 4; j++) {
            int m = wr * 64 + mi * 16 + lg * 4 + j;
            float v = tanhf(a[j] + fa1b[n]);
            int byo = m * 128 + (((c >> 3) * 16) ^ ((m & 7) << 4)) + (c & 7) * 2;
            *(ushort*)((char*)buf + byo) = f2bf(v);
        }
    }
    __syncthreads();

    // stage FA2 halves into As(k<64)/Bs(k>=64)
#pragma unroll
    for (int i = 0; i < 4; i++) {
        int ch = i * 256 + tid;
        int rr = ch >> 3, c8 = ch & 7;
        int c8p = c8 ^ (rr & 7);
        gload16(FA2 + (size_t)rr * 128 + c8p * 8,
                (char*)As + (i * 256 + wid * 64) * 16);
        gload16(FA2 + (size_t)rr * 128 + 64 + c8p * 8,
                (char*)Bs + (i * 256 + wid * 64) * 16);
    }
    __syncthreads();

    f32x4 acc2[4][4];
#pragma unroll
    for (int i = 0; i < 4; i++)
#pragma unroll
        for (int j = 0; j < 4; j++) acc2[i][j] = (f32x4){0.f, 0.f, 0.f, 0.f};

#pragma unroll
    for (int kb = 0; kb < 2; kb++) {
        const char* Ab = (const char*)(kb ? A1b : A1a) + (wr * 64 + lr) * 128;
        const char* Bb = (const char*)(kb ? Bs : As) + (wc * 64 + lr) * 128;
#pragma unroll
        for (int ks = 0; ks < 2; ks++) {
            int kx = (ks * 64 + lg * 16) ^ swz;
            bf16x8 a0 = *(const bf16x8*)(Ab + 0 * 2048 + kx);
            bf16x8 a1 = *(const bf16x8*)(Ab + 1 * 2048 + kx);
            bf16x8 a2 = *(const bf16x8*)(Ab + 2 * 2048 + kx);
            bf16x8 a3 = *(const bf16x8*)(Ab + 3 * 2048 + kx);
            bf16x8 b0 = *(const bf16x8*)(Bb + 0 * 2048 + kx);
            bf16x8 b1 = *(const bf16x8*)(Bb + 1 * 2048 + kx);
            bf16x8 b2 = *(const bf16x8*)(Bb + 2 * 2048 + kx);
            bf16x8 b3 = *(const bf16x8*)(Bb + 3 * 2048 + kx);
            acc2[0][0] = __builtin_amdgcn_mfma_f32_16x16x32_bf16(a0, b0, acc2[0][0], 0, 0, 0);
            acc2[0][1] = __builtin_amdgcn_mfma_f32_16x16x32_bf16(a0, b1, acc2[0][1], 0, 0, 0);
            acc2[0][2] = __builtin_amdgcn_mfma_f32_16x16x32_bf16(a0, b2, acc2[0][2], 0, 0, 0);
            acc2[0][3] = __builtin_amdgcn_mfma_f32_16x16x32_bf16(a0, b3, acc2[0][3], 0, 0, 0);
            acc2[1][0] = __builtin_amdgcn_mfma_f32_16x16x32_bf16(a1, b0, acc2[1][0], 0, 0, 0);
            acc2[1][1] = __builtin_amdgcn_mfma_f32_16x16x32_bf16(a1, b1, acc2[1][1], 0, 0, 0);
            acc2[1][2] = __builtin_amdgcn_mfma_f32_16x16x32_bf16(a1, b2, acc2[1][2], 0, 0, 0);
            acc2[1][3] = __builtin_amdgcn_mfma_f32_16x16x32_bf16(a1, b3, acc2[1][3], 0, 0, 0);
            acc2[2][0] = __builtin_amdgcn_mfma_f32_16x16x32_bf16(a2, b0, acc2[2][0], 0, 0, 0);
            acc2[2][1] = __builtin_amdgcn_mfma_f32_16x16x32_bf16(a2, b1, acc2[2][1], 0, 0, 0);
            acc2[2][2] = __builtin_amdgcn_mfma_f32_16x16x32_bf16(a2, b2, acc2[2][2], 0, 0, 0);
            acc2[2][3] = __builtin_amdgcn_mfma_f32_16x16x32_bf16(a2, b3, acc2[2][3], 0, 0, 0);
            acc2[3][0] = __builtin_amdgcn_mfma_f32_16x16x32_bf16(a3, b0, acc2[3][0], 0, 0, 0);
            acc2[3][1] = __builtin_amdgcn_mfma_f32_16x16x32_bf16(a3, b1, acc2[3][1], 0, 0, 0);
            acc2[3][2] = __builtin_amdgcn_mfma_f32_16x16x32_bf16(a3, b2, acc2[3][2], 0, 0, 0);
            acc2[3][3] = __builtin_amdgcn_mfma_f32_16x16x32_bf16(a3, b3, acc2[3][3], 0, 0, 0);
        }
    }

#pragma unroll
    for (int mi = 0; mi < 4; mi++)
#pragma unroll
    for (int ni = 0; ni < 4; ni++) {
        f32x4 a = acc2[mi][ni];
        int n = wc * 64 + ni * 16 + lr;
#pragma unroll
        for (int j = 0; j < 4; j++) {
            int m = m0 + wr * 64 + mi * 16 + lg * 4 + j;
            if (m >= M) continue;
            A2[(size_t)m * 128 + n] = a[j] + fa2b[n];
        }
    }
}

// ============ split-K MFMA GEMM for emb: PART[z] = A[128,Kc]@B[N,Kc]^T =====
__global__ __launch_bounds__(256)
void mgemm_splitk(const ushort* __restrict__ Asrc, const ushort* __restrict__ Bsrc,
                  float* __restrict__ PART, int N, int Kp, int nsteps, int spz)
{
    __shared__ ushort As[128 * 64];
    __shared__ ushort Bs[128 * 64];

    const int tid  = threadIdx.x;
    const int lane = tid & 63;
    const int wid  = tid >> 6;
    const int wr   = wid >> 1;
    const int wc   = wid & 1;
    const int n0   = blockIdx.x * 128;
    const int z    = blockIdx.z;

    const int lr  = lane & 15;
    const int lg  = lane >> 4;
    const int swz = (lr & 7) << 4;

    f32x4 acc[4][4];
#pragma unroll
    for (int i = 0; i < 4; i++)
#pragma unroll
        for (int j = 0; j < 4; j++) acc[i][j] = (f32x4){0.f, 0.f, 0.f, 0.f};

    const int sb = z * spz;
    const int se = min(sb + spz, nsteps);

    for (int s = sb; s < se; s++) {
        int k0 = s * 64;
        if (s != sb) __syncthreads();
#pragma unroll
        for (int i = 0; i < 4; i++) {
            int ch = i * 256 + tid;
            int rr = ch >> 3, c8 = ch & 7;
            int c8p = c8 ^ (rr & 7);
            gload16(Asrc + (size_t)rr * Kp + k0 + c8p * 8,
                    (char*)As + (i * 256 + wid * 64) * 16);
            gload16(Bsrc + (size_t)(n0 + rr) * Kp + k0 + c8p * 8,
                    (char*)Bs + (i * 256 + wid * 64) * 16);
        }
        __syncthreads();

        const char* Ab = (const char*)As + (wr * 64 + lr) * 128;
        const char* Bb = (const char*)Bs + (wc * 64 + lr) * 128;
#pragma unroll
        for (int ks = 0; ks < 2; ks++) {
            int kx = (ks * 64 + lg * 16) ^ swz;
            bf16x8 a0 = *(const bf16x8*)(Ab + 0 * 2048 + kx);
            bf16x8 a1 = *(const bf16x8*)(Ab + 1 * 2048 + kx);
            bf16x8 a2 = *(const bf16x8*)(Ab + 2 * 2048 + kx);
            bf16x8 a3 = *(const bf16x8*)(Ab + 3 * 2048 + kx);
            bf16x8 b0 = *(const bf16x8*)(Bb + 0 * 2048 + kx);
            bf16x8 b1 = *(const bf16x8*)(Bb + 1 * 2048 + kx);
            bf16x8 b2 = *(const bf16x8*)(Bb + 2 * 2048 + kx);
            bf16x8 b3 = *(const bf16x8*)(Bb + 3 * 2048 + kx);
            acc[0][0] = __builtin_amdgcn_mfma_f32_16x16x32_bf16(a0, b0, acc[0][0], 0, 0, 0);
            acc[0][1] = __builtin_amdgcn_mfma_f32_16x16x32_bf16(a0, b1, acc[0][1], 0, 0, 0);
            acc[0][2] = __builtin_amdgcn_mfma_f32_16x16x32_bf16(a0, b2, acc[0][2], 0, 0, 0);
            acc[0][3] = __builtin_amdgcn_mfma_f32_16x16x32_bf16(a0, b3, acc[0][3], 0, 0, 0);
            acc[1][0] = __builtin_amdgcn_mfma_f32_16x16x32_bf16(a1, b0, acc[1][0], 0, 0, 0);
            acc[1][1] = __builtin_amdgcn_mfma_f32_16x16x32_bf16(a1, b1, acc[1][1], 0, 0, 0);
            acc[1][2] = __builtin_amdgcn_mfma_f32_16x16x32_bf16(a1, b2, acc[1][2], 0, 0, 0);
            acc[1][3] = __builtin_amdgcn_mfma_f32_16x16x32_bf16(a1, b3, acc[1][3], 0, 0, 0);
            acc[2][0] = __builtin_amdgcn_mfma_f32_16x16x32_bf16(a2, b0, acc[2][0], 0, 0, 0);
            acc[2][1] = __builtin_amdgcn_mfma_f32_16x16x32_bf16(a2, b1, acc[2][1], 0, 0, 0);
            acc[2][2] = __builtin_amdgcn_mfma_f32_16x16x32_bf16(a2, b2, acc[2][2], 0, 0, 0);
            acc[2][3] = __builtin_amdgcn_mfma_f32_16x16x32_bf16(a2, b3, acc[2][3], 0, 0, 0);
            acc[3][0] = __builtin_amdgcn_mfma_f32_16x16x32_bf16(a3, b0, acc[3][0], 0, 0, 0);
            acc[3][1] = __builtin_amdgcn_mfma_f32_16x16x32_bf16(a3, b1, acc[3][1], 0, 0, 0);
            acc[3][2] = __builtin_amdgcn_mfma_f32_16x16x32_bf16(a3, b2, acc[3][2], 0, 0, 0);
            acc[3][3] = __builtin_amdgcn_mfma_f32_16x16x32_bf16(a3, b3, acc[3][3], 0, 0, 0);
        }
    }

    float* outp = PART + (size_t)z * 128 * 512;
#pragma unroll
    for (int mi = 0; mi < 4; mi++) {
#pragma unroll
        for (int ni = 0; ni < 4; ni++) {
            f32x4 a = acc[mi][ni];
            int n = n0 + wc * 64 + ni * 16 + lr;
#pragma unroll
            for (int j = 0; j < 4; j++) {
                int m = wr * 64 + mi * 16 + lg * 4 + j;
                outp[(size_t)m * 512 + n] = a[j];
            }
        }
    }
}

__global__ void reduce_part(const float* __restrict__ PART, float* __restrict__ EMB, int Z)
{
    int idx = blockIdx.x * blockDim.x + threadIdx.x;   // 0..65535
    float s = 0.f;
    for (int z = 0; z < Z; z++) s += PART[(size_t)z * 65536 + idx];
    EMB[idx] = s;
}

// attn weights, transposed + bf16 + zero-pad: ATTWT[c][n], n in [0,Kp)
__global__ void att_w_t(const float* __restrict__ a2, const float* __restrict__ ms,
                        const float* __restrict__ ss, ushort* __restrict__ W,
                        int Nn, int Kp)
{
    int idx = blockIdx.x * blockDim.x + threadIdx.x;
    if (idx >= 128 * Kp) return;
    int c = idx / Kp, n = idx % Kp;
    float v = 0.f;
    if (n < Nn) v = expf(a2[(size_t)n * 128 + c] - ms[c]) / ss[c];
    W[idx] = f2bf(v);
}

// XB [Nn][512] bf16 -> XBT [512][Kp] bf16 (zero-pad n >= Nn), 64x64 LDS tiles
__global__ __launch_bounds__(256)
void t_xb(const ushort* __restrict__ XB, ushort* __restrict__ XBT, int Nn, int Kp)
{
    __shared__ ushort tile[64][72];
    const int n0 = blockIdx.x * 64;
    const int d0 = blockIdx.y * 64;
    const int tid = threadIdx.x;
#pragma unroll
    for (int i = 0; i < 2; i++) {
        int ch = i * 256 + tid;
        int r = ch >> 3, c8 = ch & 7;
        int n = n0 + r;
        ushort8v v = {0, 0, 0, 0, 0, 0, 0, 0};
        if (n < Nn) v = *(const ushort8v*)(XB + (size_t)n * 512 + d0 + c8 * 8);
        *(ushort8v*)&tile[r][c8 * 8] = v;
    }
    __syncthreads();
#pragma unroll
    for (int i = 0; i < 2; i++) {
        int ch = i * 256 + tid;
        int dr = ch >> 3, n8 = ch & 7;
        ushort8v v;
#pragma unroll
        for (int q = 0; q < 8; q++) v[q] = tile[n8 * 8 + q][dr];
        *(ushort8v*)(XBT + (size_t)(d0 + dr) * Kp + n0 + n8 * 8) = v;
    }
}

// ============ conv tile device fn: 3x3 s2 p1, NHWC bf16, IC=64 =============
template<int NI>
__device__ void conv_tile(const ushort* __restrict__ in, const ushort* __restrict__ Wk,
                          const float* __restrict__ bias, const float* __restrict__ gamma,
                          const float* __restrict__ beta, ushort* __restrict__ outp,
                          int IH, int IW, int OH, int OW, int m0,
                          ushort* As, ushort* Bs)
{
    const int OC = NI * 16;
    const int tid  = threadIdx.x;
    const int lane = tid & 63;
    const int wv   = tid >> 6;
    const int lr   = lane & 15;
    const int lg   = lane >> 4;
    const int swz  = (lr & 7) << 4;
    const int M    = OH * OW;

    f32x4 acc[2][NI];
#pragma unroll
    for (int i = 0; i < 2; i++)
#pragma unroll
        for (int j = 0; j < NI; j++) acc[i][j] = (f32x4){0.f, 0.f, 0.f, 0.f};

    for (int r = 0; r < 9; r++) {
        const int kh = r / 3, kw = r % 3;
        if (r) __syncthreads();
#pragma unroll
        for (int i = 0; i < 4; i++) {
            int ch = i * 256 + tid;
            int p = ch >> 3, c8 = ch & 7;
            int lb = p * 128 + ((c8 * 16) ^ ((p & 7) << 4));
            int gp = m0 + p; if (gp > M - 1) gp = M - 1;
            int oh = gp / OW, ow = gp % OW;
            int ih = oh * 2 - 1 + kh, iw = ow * 2 - 1 + kw;
            ushort8v v = {0, 0, 0, 0, 0, 0, 0, 0};
            if (ih >= 0 && ih < IH && iw >= 0 && iw < IW)
                v = *(const ushort8v*)(in + ((size_t)ih * IW + iw) * 64 + c8 * 8);
            *(ushort8v*)((char*)As + lb) = v;
        }
        for (int ch = tid; ch < OC * 8; ch += 256) {
            int oc = ch >> 3, c8 = ch & 7;
            int lb = oc * 128 + ((c8 * 16) ^ ((oc & 7) << 4));
            ushort8v v = *(const ushort8v*)(Wk + (size_t)oc * 576 + r * 64 + c8 * 8);
            *(ushort8v*)((char*)Bs + lb) = v;
        }
        __syncthreads();

        const char* Ab = (const char*)As + (wv * 32 + lr) * 128;
        const char* Bb = (const char*)Bs + lr * 128;
#pragma unroll
        for (int ks = 0; ks < 2; ks++) {
            int kx = (ks * 64 + lg * 16) ^ swz;
            bf16x8 a0 = *(const bf16x8*)(Ab + 0 * 2048 + kx);
            bf16x8 a1 = *(const bf16x8*)(Ab + 1 * 2048 + kx);
#pragma unroll
            for (int ni = 0; ni < NI; ni++) {
                bf16x8 bfr = *(const bf16x8*)(Bb + ni * 2048 + kx);
                acc[0][ni] = __builtin_amdgcn_mfma_f32_16x16x32_bf16(a0, bfr, acc[0][ni], 0, 0, 0);
                acc[1][ni] = __builtin_amdgcn_mfma_f32_16x16x32_bf16(a1, bfr, acc[1][ni], 0, 0, 0);
            }
        }
    }

#pragma unroll
    for (int mi = 0; mi < 2; mi++)
#pragma unroll
    for (int ni = 0; ni < NI; ni++) {
        f32x4 a = acc[mi][ni];
        int oc = ni * 16 + lr;
        float bv = bias[oc], gv = gamma[oc], btv = beta[oc];
#pragma unroll
        for (int j = 0; j < 4; j++) {
            int gp = m0 + wv * 32 + mi * 16 + lg * 4 + j;
            if (gp >= M) continue;
            float v = a[j] + bv;
            v = gv * v * BN_INV + btv;
            v = fmaxf(v, 0.f);
            outp[(size_t)gp * OC + oc] = f2bf(v);
        }
    }
    __syncthreads();   // LDS reuse across tile loop
}

// ============ persistent cooperative CNN tail ==============================
// conv1 + 5x(conv+pool) + conv2 + head, grid.sync between phases.
__global__ __launch_bounds__(256)
void cnn_tail(const float* __restrict__ EMB,
              const float* __restrict__ cnn1w, const float* __restrict__ cnn1b,
              const float* __restrict__ normg, const float* __restrict__ normb,
              const ushort* __restrict__ WC1, const float* __restrict__ c1b,
              const float* __restrict__ c1g, const float* __restrict__ c1bb,
              const ushort* __restrict__ WC2, const float* __restrict__ c2b,
              const float* __restrict__ c2g, const float* __restrict__ c2bb,
              const float* __restrict__ fc1w, const float* __restrict__ fc1b,
              const float* __restrict__ fc2w, const float* __restrict__ fc2b,
              ushort* __restrict__ P16, ushort* __restrict__ Q16,
              float* __restrict__ outp)
{
    cg::grid_group grid = cg::this_grid();
    __shared__ ushort As[128 * 64];
    __shared__ ushort Bs[64 * 64];
    __shared__ float flat[432];
    __shared__ float t1[1024];

    const int tid = threadIdx.x;
    const int nb  = gridDim.x;

    // ---- conv1: emb (1ch f32) -> P16 [132][516][64] ----
    for (int oh = blockIdx.x; oh < 132; oh += nb) {
        for (int idx = tid; idx < 516 * 8; idx += 256) {
            int ow = idx >> 3, c8 = idx & 7;
            float pv[9];
#pragma unroll
            for (int kh = 0; kh < 3; kh++)
#pragma unroll
                for (int kw = 0; kw < 3; kw++) {
                    int ih = oh - 3 + kh, iw = ow - 3 + kw;
                    pv[kh * 3 + kw] = (ih >= 0 && ih < 128 && iw >= 0 && iw < 512)
                                      ? EMB[ih * 512 + iw] : 0.f;
                }
            ushort8v o;
#pragma unroll
            for (int qq = 0; qq < 8; qq++) {
                int oc = c8 * 8 + qq;
                float v = cnn1b[oc];
#pragma unroll
                for (int i = 0; i < 9; i++) v = fmaf(pv[i], cnn1w[oc * 9 + i], v);
                v = normg[oc] * v * BN_INV + normb[oc];
                v = fmaxf(v, 0.f);
                o[qq] = f2bf(v);
            }
            *(ushort8v*)(P16 + ((size_t)oh * 516 + ow) * 64 + c8 * 8) = o;
        }
    }
    grid.sync();

    int H = 132, W = 516;
    for (int it = 0; it < 5; it++) {
        int OH = (H - 1) / 2 + 1, OW = (W - 1) / 2 + 1;
        int M = OH * OW;
        int tiles = (M + 127) / 128;
        for (int t = blockIdx.x; t < tiles; t += nb)
            conv_tile<4>(P16, WC1, c1b, c1g, c1bb, Q16, H, W, OH, OW, t * 128, As, Bs);
        grid.sync();
        // pool Q16 -> P16
        int tot = OH * OW * 8;
        for (int idx = blockIdx.x * 256 + tid; idx < tot; idx += nb * 256) {
            int h = idx / (OW * 8);
            int rem = idx % (OW * 8);
            int w0 = rem >> 3, cgp = rem & 7;
            float mx[8];
#pragma unroll
            for (int qq = 0; qq < 8; qq++) mx[qq] = -1e30f;
            for (int dh = -1; dh <= 1; dh++) {
                int hh = h + dh; if (hh < 0 || hh >= OH) continue;
                for (int dw = -1; dw <= 1; dw++) {
                    int ww = w0 + dw; if (ww < 0 || ww >= OW) continue;
                    ushort8v v = *(const ushort8v*)(Q16 + ((size_t)hh * OW + ww) * 64 + cgp * 8);
#pragma unroll
                    for (int qq = 0; qq < 8; qq++) mx[qq] = fmaxf(mx[qq], bf2f(v[qq]));
                }
            }
            ushort8v o;
#pragma unroll
            for (int qq = 0; qq < 8; qq++) o[qq] = f2bf(mx[qq]);
            *(ushort8v*)(P16 + ((size_t)h * OW + w0) * 64 + cgp * 8) = o;
        }
        grid.sync();
        H = OH; W = OW;
    }

    // conv2: [5][17][64] -> [3][9][16] (one tile)
    if (blockIdx.x == 0)
        conv_tile<1>(P16, WC2, c2b, c2g, c2bb, Q16, H, W, 3, 9, 0, As, Bs);
    grid.sync();

    // head (block 0, 256 threads)
    if (blockIdx.x == 0) {
        for (int i = tid; i < 432; i += 256) {
            int c = i / 27, r = i % 27;
            int h = r / 9, w0 = r % 9;
            float m = -1e30f;
            for (int dh = -1; dh <= 1; dh++) {
                int hh = h + dh; if (hh < 0 || hh >= 3) continue;
                for (int dw = -1; dw <= 1; dw++) {
                    int ww = w0 + dw; if (ww < 0 || ww >= 9) continue;
                    m = fmaxf(m, bf2f(Q16[((size_t)hh * 9 + ww) * 16 + c]));
                }
            }
            flat[i] = m;
        }
        __syncthreads();
        for (int o = tid; o < 1024; o += 256) {
            float s = fc1b[o];
            const float* wr = fc1w + (size_t)o * 432;
            for (int k = 0; k < 432; k++) s = fmaf(flat[k], wr[k], s);
            t1[o] = s;
        }
        __syncthreads();
        int wv = tid >> 6, l = tid & 63;
        for (int o = wv; o < 14; o += 4) {
            float s = 0.f;
            const float* wr = fc2w + (size_t)o * 1024;
            for (int k = l; k < 1024; k += 64) s = fmaf(t1[k], wr[k], s);
            for (int sh = 32; sh > 0; sh >>= 1) s += __shfl_down(s, sh, 64);
            if (l == 0) outp[o] = 1.f / (1.f + expf(-(s + fc2b[o])));
        }
    }
}

// ---------------- fused weight prep (cvt + conv reorder) --------------------
__global__ void prep_all(const float* w1l, const float* w1r, const float* w2l,
                         const float* w2r, const float* fa1, const float* fa2,
                         const float* c1w, const float* c2w,
                         ushort* W1L, ushort* W1R, ushort* W2L, ushort* W2R,
                         ushort* FA1, ushort* FA2, ushort* WC1, ushort* WC2)
{
    int i = blockIdx.x * blockDim.x + threadIdx.x;
    if (i < 796672) {
        const float* s; ushort* d; int j;
        if      (i < 327680)  { s = w1l; d = W1L; j = i; }
        else if (i < 655360)  { s = w1r; d = W1R; j = i - 327680; }
        else if (i < 720896)  { s = w2l; d = W2L; j = i - 655360; }
        else if (i < 786432)  { s = w2r; d = W2R; j = i - 720896; }
        else if (i < 794624)  { s = fa1; d = FA1; j = i - 786432; }
        else                  { s = fa2; d = FA2; j = i - 794624; }
        const float4 f0 = *(const float4*)(s + (size_t)j * 8);
        const float4 f1 = *(const float4*)(s + (size_t)j * 8 + 4);
        ushort8v v;
        v[0] = f2bf(f0.x); v[1] = f2bf(f0.y); v[2] = f2bf(f0.z); v[3] = f2bf(f0.w);
        v[4] = f2bf(f1.x); v[5] = f2bf(f1.y); v[6] = f2bf(f1.z); v[7] = f2bf(f1.w);
        *(ushort8v*)(d + (size_t)j * 8) = v;
    } else {
        int k = i - 796672;
        if (k >= 80 * 576) return;
        const float* w; ushort* wk; int idx;
        if (k < 64 * 576) { w = c1w; wk = WC1; idx = k; }
        else              { w = c2w; wk = WC2; idx = k - 64 * 576; }
        int oc = idx / 576, t = idx % 576;
        int r = t / 64, ic = t % 64;
        int kh = r / 3, kw = r % 3;
        wk[idx] = f2bf(w[((oc * 64 + ic) * 3 + kh) * 3 + kw]);
    }
}

// ---------------- single-block CSR build ------------------------------------
__global__ __launch_bounds__(1024)
void csr_build(const int* __restrict__ src, const int* __restrict__ dst,
               int* __restrict__ off, int* __restrict__ eidx, int E, int n)
{
    __shared__ int h[10000];
    __shared__ int tmp[1024];
    const int t = threadIdx.x;
    for (int i = t; i < n; i += 1024) h[i] = 0;
    __syncthreads();
    for (int e = t; e < E; e += 1024) atomicAdd(&h[dst[e]], 1);
    __syncthreads();
    const int PT = (n + 1023) / 1024;   // 10
    int b = t * PT, ls = 0;
    for (int k = 0; k < PT; k++) { int i = b + k; if (i < n) ls += h[i]; }
    tmp[t] = ls;
    __syncthreads();
    for (int s = 1; s < 1024; s <<= 1) {
        int v = (t >= s) ? tmp[t - s] : 0;
        __syncthreads();
        tmp[t] += v;
        __syncthreads();
    }
    int run = tmp[t] - ls;
    int cur[10];
    for (int k = 0; k < PT; k++) {
        int i = b + k;
        if (i < n) { off[i] = run; cur[k] = run; run += h[i]; }
    }
    if (t == 1023) off[n] = tmp[1023];
    __syncthreads();
    for (int k = 0; k < PT; k++) { int i = b + k; if (i < n) h[i] = cur[k]; }
    __syncthreads();
    for (int e = t; e < E; e += 1024) {
        int pos = atomicAdd(&h[dst[e]], 1);
        eidx[pos] = src[e];
    }
}

// ---------------- f32 -> bf16 convert (x -> XBF) ----------------------------
__global__ void cvt_k(const float* __restrict__ in, ushort* __restrict__ out, int n8)
{
    int i = blockIdx.x * blockDim.x + threadIdx.x;
    if (i >= n8) return;
    const float4 f0 = *(const float4*)(in + (size_t)i * 8);
    const float4 f1 = *(const float4*)(in + (size_t)i * 8 + 4);
    ushort8v v;
    v[0] = f2bf(f0.x); v[1] = f2bf(f0.y); v[2] = f2bf(f0.z); v[3] = f2bf(f0.w);
    v[4] = f2bf(f1.x); v[5] = f2bf(f1.y); v[6] = f2bf(f1.z); v[7] = f2bf(f1.w);
    *(ushort8v*)(out + (size_t)i * 8) = v;
}

// ---------------- attention softmax over nodes ------------------------------
__global__ __launch_bounds__(256)
void softmax_stats(const float* __restrict__ a2, float* __restrict__ ms,
                   float* __restrict__ ss, int Nn)
{
    int c = blockIdx.x;
    __shared__ float red[256];
    float mx = -1e30f;
    for (int n = threadIdx.x; n < Nn; n += 256)
        mx = fmaxf(mx, a2[(size_t)n * 128 + c]);
    red[threadIdx.x] = mx;
    __syncthreads();
    for (int s = 128; s > 0; s >>= 1) {
        if (threadIdx.x < s) red[threadIdx.x] = fmaxf(red[threadIdx.x], red[threadIdx.x + s]);
        __syncthreads();
    }
    mx = red[0];
    __syncthreads();
    float sum = 0.f;
    for (int n = threadIdx.x; n < Nn; n += 256)
        sum += expf(a2[(size_t)n * 128 + c] - mx);
    red[threadIdx.x] = sum;
    __syncthreads();
    for (int s = 128; s > 0; s >>= 1) {
        if (threadIdx.x < s) red[threadIdx.x] += red[threadIdx.x + s];
        __syncthreads();
    }
    if (threadIdx.x == 0) { ms[c] = mx; ss[c] = red[0]; }
}

// ---------------------------------------------------------------------------
extern "C" void kernel_launch(void* const* d_in, const int* in_sizes, int n_in,
                              void* d_out, int out_size, void* d_ws, size_t ws_size,
                              hipStream_t stream)
{
    const float* x     = (const float*)d_in[0];
    const int*   ei    = (const int*)d_in[1];
    const float* w1l   = (const float*)d_in[2];
    const float* b1    = (const float*)d_in[3];
    const float* w1r   = (const float*)d_in[4];
    const float* bn1g  = (const float*)d_in[5];
    const float* bn1b  = (const float*)d_in[6];
    const float* w2l   = (const float*)d_in[7];
    const float* b2    = (const float*)d_in[8];
    const float* w2r   = (const float*)d_in[9];
    const float* fa1w  = (const float*)d_in[10];
    const float* fa1b  = (const float*)d_in[11];
    const float* fa2w  = (const float*)d_in[12];
    const float* fa2b  = (const float*)d_in[13];
    const float* cnn1w = (const float*)d_in[14];
    const float* cnn1b = (const float*)d_in[15];
    const float* normg = (const float*)d_in[16];
    const float* normb = (const float*)d_in[17];
    const float* c1w   = (const float*)d_in[18];
    const float* c1b   = (const float*)d_in[19];
    const float* c1g   = (const float*)d_in[20];
    const float* c1bb  = (const float*)d_in[21];
    const float* c2w   = (const float*)d_in[22];
    const float* c2b   = (const float*)d_in[23];
    const float* c2g   = (const float*)d_in[24];
    const float* c2bb  = (const float*)d_in[25];
    const float* fc1w  = (const float*)d_in[26];
    const float* fc1b  = (const float*)d_in[27];
    const float* fc2w  = (const float*)d_in[28];
    const float* fc2b  = (const float*)d_in[29];
    float* out = (float*)d_out;

    const int Nn = 10000, E = 160000;
    const int Kp = 10048;   // 157*64
    char* ws = (char*)d_ws;

    // ---- workspace layout (bytes) — phase-checked, no live overlaps ----
    ushort* YL    = (ushort*)(ws + 0);           // 20,480,000
    ushort* ATTWT = (ushort*)(ws + 0);           // 2,572,288 (YL dead after gather_h1)
    ushort* XBT   = (ushort*)(ws + 2572288);     // -> 12,861,440
    ushort* P16   = (ushort*)(ws + 0);           // 8,718,336
    ushort* Q16   = (ushort*)(ws + 13000000);    // -> 15,179,584
    ushort* H1   = (ushort*)(ws + 20480000);     // 20,480,000
    ushort* XB   = (ushort*)(ws + 20480000);     // 10,240,000
    float*  A2   = (float*)(ws + 33280000);      // 5,120,000 -> 38,400,000
    ushort* YR   = (ushort*)(ws + 40960000);     // 20,480,000
    ushort* ZL   = (ushort*)(ws + 40960000);     // 10,240,000
    ushort* ZR   = (ushort*)(ws + 51200000);     // -> 61,440,000
    float*  PART = (float*)(ws + 40960000);      // 10,485,760 (ZL/ZR dead by splitk)
    int*   off    = (int*)(ws + 61520000);       // 40,004
    int*   eidx   = (int*)(ws + 61560128);       // 640,000 -> 62,200,128
    float*  MS   = (float*)(ws + 67360128);
    float*  SS   = (float*)(ws + 67360640);
    float*  EMB  = (float*)(ws + 67361152);      // -> 67,623,296
    ushort* W1L = (ushort*)(ws + 67623296);      // W1L+W1R contiguous = [2048][2560]
    ushort* W1R = (ushort*)(ws + 72866176);
    ushort* W2L = (ushort*)(ws + 78109056);      // W2L+W2R contiguous = [1024][1024]
    ushort* W2R = (ushort*)(ws + 79157632);
    ushort* FA1 = (ushort*)(ws + 80206208);
    ushort* FA2 = (ushort*)(ws + 80337280);
    ushort* WC1 = (ushort*)(ws + 80370048);
    ushort* WC2 = (ushort*)(ws + 80443776);      // -> 80,462,208
    ushort* XBF = (ushort*)(ws + 80462208);      // 51,200,000 -> 131,662,208
    const bool use_xbf = (ws_size >= (size_t)131662208);

    const int* src = ei;
    const int* dst = ei + E;

    // ---- weight prep (1) + CSR build (1) ----
    prep_all<<<(796672 + 80 * 576 + 255) / 256, 256, 0, stream>>>(
        w1l, w1r, w2l, w2r, fa1w, fa2w, c1w, c2w,
        W1L, W1R, W2L, W2R, FA1, FA2, WC1, WC2);
    csr_build<<<1, 1024, 0, stream>>>(src, dst, off, eidx, E, Nn);

    const int GY = (Nn + 127) / 128;   // 79

    // ---- SAGE layer 1: fused [YL | YR] = x @ [W1L;W1R]^T (N=2048) ----
    if (use_xbf) {
        cvt_k<<<(3200000 + 255) / 256, 256, 0, stream>>>(x, XBF, 3200000);
        mgemm<0, 5, ushort><<<dim3(2048 / 128, GY), 256, 0, stream>>>(
            XBF, W1L, YL, Nn, 2048, 2560, nullptr, YR);
    } else {
        mgemm<1, 5, ushort><<<dim3(2048 / 128, GY), 256, 0, stream>>>(
            x, W1L, YL, Nn, 2048, 2560, nullptr, YR);
    }
    gather_h1<<<Nn, 128, 0, stream>>>(YL, eidx, off, YR, b1, bn1g, bn1b, H1);

    // ---- SAGE layer 2: fused [ZL | ZR] = h1 @ [W2L;W2R]^T (N=1024) ----
    mgemm<0, 5, ushort><<<dim3(1024 / 128, GY), 256, 0, stream>>>(
        H1, W2L, ZL, Nn, 1024, 1024, nullptr, ZR);
    gather_xb<<<Nn, 64, 0, stream>>>(ZL, eidx, off, ZR, b2, XB);

    // ---- attention (fused MLP) ----
    attn_a1a2<<<GY, 256, 0, stream>>>(XB, FA1, fa1b, FA2, fa2b, A2, Nn);
    softmax_stats<<<128, 256, 0, stream>>>(A2, MS, SS, Nn);
    att_w_t<<<(128 * Kp + 255) / 256, 256, 0, stream>>>(A2, MS, SS, ATTWT, Nn, Kp);
    t_xb<<<dim3(Kp / 64, 8), 256, 0, stream>>>(XB, XBT, Nn, Kp);
    mgemm_splitk<<<dim3(4, 1, 40), 256, 0, stream>>>(ATTWT, XBT, PART, 512, Kp, 157, 4);
    reduce_part<<<256, 256, 0, stream>>>(PART, EMB, 40);

    // ---- CNN tail: one cooperative persistent kernel ----
    {
        void* args[] = {
            (void*)&EMB, (void*)&cnn1w, (void*)&cnn1b, (void*)&normg, (void*)&normb,
            (void*)&WC1, (void*)&c1b, (void*)&c1g, (void*)&c1bb,
            (void*)&WC2, (void*)&c2b, (void*)&c2g, (void*)&c2bb,
            (void*)&fc1w, (void*)&fc1b, (void*)&fc2w, (void*)&fc2b,
            (void*)&P16, (void*)&Q16, (void*)&out
        };
        hipLaunchCooperativeKernel((const void*)cnn_tail, dim3(256), dim3(256),
                                   args, 0, stream);
    }
}

// Round 11
// 904.446 us; speedup vs baseline: 1.1453x; 1.1453x over previous
//
#include <hip/hip_runtime.h>
#include <cstdint>
#include <cstddef>

typedef unsigned short ushort;
typedef __attribute__((ext_vector_type(8))) short bf16x8;
typedef __attribute__((ext_vector_type(8))) unsigned short ushort8v;
typedef __attribute__((ext_vector_type(4))) float f32x4;

// 1/sqrt(1+1e-5)
#define BN_INV 0.9999950000374997f

__device__ inline ushort f2bf(float f) {
    union { float f; unsigned u; } x; x.f = f;
    unsigned r = x.u + 0x7fffu + ((x.u >> 16) & 1u);
    return (ushort)(r >> 16);
}
__device__ inline float bf2f(ushort u) {
    union { unsigned u; float f; } x; x.u = ((unsigned)u) << 16;
    return x.f;
}

// async global->LDS, 16B per lane. LDS dest is wave-uniform base + lane*16.
__device__ __forceinline__ void gload16(const void* g, void* l) {
    __builtin_amdgcn_global_load_lds(
        (const __attribute__((address_space(1))) unsigned int*)g,
        (__attribute__((address_space(3))) unsigned int*)l, 16, 0, 0);
}

// ======================= MFMA bf16 GEMM ====================================
// C[M,N] = A[M,K] @ B[N,K]^T.  B always bf16.
// AMODE 0: A bf16 via global_load_lds w/ pre-swizzled source.
// AMODE 1: A f32 (reg-converted), reg-staged swizzled LDS writes.
// XCD-chunked bijective swizzle, N-INNER (A panels L2-resident, B via L3).
// EPIL 5: split-write at N/2: n<N/2 -> C, else -> C2 (row stride N/2)
template<int AMODE, int EPIL, typename OutT>
__global__ __launch_bounds__(256)
void mgemm(const void* __restrict__ Asrc, const ushort* __restrict__ Bsrc,
           OutT* __restrict__ C, int M, int N, int K,
           const float* __restrict__ bias, ushort* __restrict__ C2)
{
    __shared__ ushort As[128 * 64];
    __shared__ ushort Bs[128 * 64];

    const int tid  = threadIdx.x;
    const int lane = tid & 63;
    const int wid  = tid >> 6;
    const int wr   = wid >> 1;
    const int wc   = wid & 1;

    const int nwg  = gridDim.x * gridDim.y;
    const int orig = blockIdx.y * gridDim.x + blockIdx.x;
    const int q    = nwg >> 3, r = nwg & 7;
    const int xcd  = orig & 7, ii = orig >> 3;
    const int wg   = (xcd < r ? xcd * (q + 1) : r * (q + 1) + (xcd - r) * q) + ii;
    const int m0   = (wg / gridDim.x) * 128;
    const int n0   = (wg % gridDim.x) * 128;

    const int lr  = lane & 15;
    const int lg  = lane >> 4;
    const int swz = (lr & 7) << 4;

    f32x4 acc[4][4];
#pragma unroll
    for (int i = 0; i < 4; i++)
#pragma unroll
        for (int j = 0; j < 4; j++) acc[i][j] = (f32x4){0.f, 0.f, 0.f, 0.f};

    for (int k0 = 0; k0 < K; k0 += 64) {
        if (k0) __syncthreads();
        if constexpr (AMODE == 0) {
#pragma unroll
            for (int i = 0; i < 4; i++) {
                int ch = i * 256 + tid;
                int rr = ch >> 3, c8 = ch & 7;
                int c8p = c8 ^ (rr & 7);
                int srow = m0 + rr; if (srow > M - 1) srow = M - 1;
                gload16((const ushort*)Asrc + (size_t)srow * K + k0 + c8p * 8,
                        (char*)As + (i * 256 + wid * 64) * 16);
                gload16(Bsrc + (size_t)(n0 + rr) * K + k0 + c8p * 8,
                        (char*)Bs + (i * 256 + wid * 64) * 16);
            }
        } else {
#pragma unroll
            for (int i = 0; i < 4; i++) {
                int ch = i * 256 + tid;
                int rr = ch >> 3, c8 = ch & 7;
                int lb = rr * 128 + ((c8 * 16) ^ ((rr & 7) << 4));
                int srow = m0 + rr; if (srow > M - 1) srow = M - 1;
                const float* ap = (const float*)Asrc + (size_t)srow * K + k0 + c8 * 8;
                float4 f0 = *(const float4*)ap;
                float4 f1 = *(const float4*)(ap + 4);
                ushort8v va;
                va[0] = f2bf(f0.x); va[1] = f2bf(f0.y); va[2] = f2bf(f0.z); va[3] = f2bf(f0.w);
                va[4] = f2bf(f1.x); va[5] = f2bf(f1.y); va[6] = f2bf(f1.z); va[7] = f2bf(f1.w);
                *(ushort8v*)((char*)As + lb) = va;
                ushort8v vb = *(const ushort8v*)(Bsrc + (size_t)(n0 + rr) * K + k0 + c8 * 8);
                *(ushort8v*)((char*)Bs + lb) = vb;
            }
        }
        __syncthreads();

        const char* Ab = (const char*)As + (wr * 64 + lr) * 128;
        const char* Bb = (const char*)Bs + (wc * 64 + lr) * 128;
#pragma unroll
        for (int ks = 0; ks < 2; ks++) {
            int kx = (ks * 64 + lg * 16) ^ swz;
            bf16x8 a0 = *(const bf16x8*)(Ab + 0 * 2048 + kx);
            bf16x8 a1 = *(const bf16x8*)(Ab + 1 * 2048 + kx);
            bf16x8 a2 = *(const bf16x8*)(Ab + 2 * 2048 + kx);
            bf16x8 a3 = *(const bf16x8*)(Ab + 3 * 2048 + kx);
            bf16x8 b0 = *(const bf16x8*)(Bb + 0 * 2048 + kx);
            bf16x8 b1 = *(const bf16x8*)(Bb + 1 * 2048 + kx);
            bf16x8 b2 = *(const bf16x8*)(Bb + 2 * 2048 + kx);
            bf16x8 b3 = *(const bf16x8*)(Bb + 3 * 2048 + kx);
            acc[0][0] = __builtin_amdgcn_mfma_f32_16x16x32_bf16(a0, b0, acc[0][0], 0, 0, 0);
            acc[0][1] = __builtin_amdgcn_mfma_f32_16x16x32_bf16(a0, b1, acc[0][1], 0, 0, 0);
            acc[0][2] = __builtin_amdgcn_mfma_f32_16x16x32_bf16(a0, b2, acc[0][2], 0, 0, 0);
            acc[0][3] = __builtin_amdgcn_mfma_f32_16x16x32_bf16(a0, b3, acc[0][3], 0, 0, 0);
            acc[1][0] = __builtin_amdgcn_mfma_f32_16x16x32_bf16(a1, b0, acc[1][0], 0, 0, 0);
            acc[1][1] = __builtin_amdgcn_mfma_f32_16x16x32_bf16(a1, b1, acc[1][1], 0, 0, 0);
            acc[1][2] = __builtin_amdgcn_mfma_f32_16x16x32_bf16(a1, b2, acc[1][2], 0, 0, 0);
            acc[1][3] = __builtin_amdgcn_mfma_f32_16x16x32_bf16(a1, b3, acc[1][3], 0, 0, 0);
            acc[2][0] = __builtin_amdgcn_mfma_f32_16x16x32_bf16(a2, b0, acc[2][0], 0, 0, 0);
            acc[2][1] = __builtin_amdgcn_mfma_f32_16x16x32_bf16(a2, b1, acc[2][1], 0, 0, 0);
            acc[2][2] = __builtin_amdgcn_mfma_f32_16x16x32_bf16(a2, b2, acc[2][2], 0, 0, 0);
            acc[2][3] = __builtin_amdgcn_mfma_f32_16x16x32_bf16(a2, b3, acc[2][3], 0, 0, 0);
            acc[3][0] = __builtin_amdgcn_mfma_f32_16x16x32_bf16(a3, b0, acc[3][0], 0, 0, 0);
            acc[3][1] = __builtin_amdgcn_mfma_f32_16x16x32_bf16(a3, b1, acc[3][1], 0, 0, 0);
            acc[3][2] = __builtin_amdgcn_mfma_f32_16x16x32_bf16(a3, b2, acc[3][2], 0, 0, 0);
            acc[3][3] = __builtin_amdgcn_mfma_f32_16x16x32_bf16(a3, b3, acc[3][3], 0, 0, 0);
        }
    }

#pragma unroll
    for (int mi = 0; mi < 4; mi++) {
#pragma unroll
        for (int ni = 0; ni < 4; ni++) {
            f32x4 a = acc[mi][ni];
            int n = n0 + wc * 64 + ni * 16 + lr;
#pragma unroll
            for (int j = 0; j < 4; j++) {
                int m = m0 + wr * 64 + mi * 16 + lg * 4 + j;
                if (m >= M) continue;
                float v = a[j];
                if (EPIL == 5) {
                    int half = N >> 1;
                    ushort* dst = (n < half) ? (ushort*)C : C2;
                    dst[(size_t)m * half + (n & (half - 1))] = f2bf(v);
                } else {
                    if (sizeof(OutT) == 2) ((ushort*)C)[(size_t)m * N + n] = f2bf(v);
                    else                   ((float*)C)[(size_t)m * N + n] = v;
                }
            }
        }
    }
}

// ==== fused gather + SAGE-1 epilogue: H1 = bn(relu(mean_j YL_j + b1 + YR)) ==
__global__ void gather_h1(const ushort* __restrict__ YL, const int* __restrict__ eidx,
                          const int* __restrict__ off, const ushort* __restrict__ YR,
                          const float* __restrict__ b1, const float* __restrict__ g,
                          const float* __restrict__ bb, ushort* __restrict__ H1)
{
    int n = blockIdx.x;
    int beg = off[n], end = off[n + 1];
    float inv = 1.f / fmaxf((float)(end - beg), 1.f);
    float s0 = 0, s1 = 0, s2 = 0, s3 = 0, s4 = 0, s5 = 0, s6 = 0, s7 = 0;
    for (int e = beg; e < end; e++) {
        ushort8v v = *(const ushort8v*)(YL + (size_t)eidx[e] * 1024 + threadIdx.x * 8);
        s0 += bf2f(v[0]); s1 += bf2f(v[1]); s2 += bf2f(v[2]); s3 += bf2f(v[3]);
        s4 += bf2f(v[4]); s5 += bf2f(v[5]); s6 += bf2f(v[6]); s7 += bf2f(v[7]);
    }
    float sv[8] = {s0, s1, s2, s3, s4, s5, s6, s7};
    ushort8v yr = *(const ushort8v*)(YR + (size_t)n * 1024 + threadIdx.x * 8);
    ushort8v o;
#pragma unroll
    for (int qq = 0; qq < 8; qq++) {
        int c = threadIdx.x * 8 + qq;
        float v = sv[qq] * inv + b1[c] + bf2f(yr[qq]);
        v = fmaxf(v, 0.f);
        v = g[c] * v * BN_INV + bb[c];
        o[qq] = f2bf(v);
    }
    *(ushort8v*)(H1 + (size_t)n * 1024 + threadIdx.x * 8) = o;
}

// ==== fused gather + SAGE-2 epilogue: XB = mean_j ZL_j + b2 + ZR ===========
__global__ void gather_xb(const ushort* __restrict__ ZL, const int* __restrict__ eidx,
                          const int* __restrict__ off, const ushort* __restrict__ ZR,
                          const float* __restrict__ b2, ushort* __restrict__ XB)
{
    int n = blockIdx.x;
    int beg = off[n], end = off[n + 1];
    float inv = 1.f / fmaxf((float)(end - beg), 1.f);
    float s0 = 0, s1 = 0, s2 = 0, s3 = 0, s4 = 0, s5 = 0, s6 = 0, s7 = 0;
    for (int e = beg; e < end; e++) {
        ushort8v v = *(const ushort8v*)(ZL + (size_t)eidx[e] * 512 + threadIdx.x * 8);
        s0 += bf2f(v[0]); s1 += bf2f(v[1]); s2 += bf2f(v[2]); s3 += bf2f(v[3]);
        s4 += bf2f(v[4]); s5 += bf2f(v[5]); s6 += bf2f(v[6]); s7 += bf2f(v[7]);
    }
    float sv[8] = {s0, s1, s2, s3, s4, s5, s6, s7};
    ushort8v zr = *(const ushort8v*)(ZR + (size_t)n * 512 + threadIdx.x * 8);
    ushort8v o;
#pragma unroll
    for (int qq = 0; qq < 8; qq++) {
        int c = threadIdx.x * 8 + qq;
        o[qq] = f2bf(sv[qq] * inv + b2[c] + bf2f(zr[qq]));
    }
    *(ushort8v*)(XB + (size_t)n * 512 + threadIdx.x * 8) = o;
}

// ==== fused attention MLP: A2 = tanh(XB@FA1^T + b1f)@FA2^T + b2f ===========
__global__ __launch_bounds__(256)
void attn_a1a2(const ushort* __restrict__ XB, const ushort* __restrict__ FA1,
               const float* __restrict__ fa1b, const ushort* __restrict__ FA2,
               const float* __restrict__ fa2b, float* __restrict__ A2, int M)
{
    __shared__ ushort As[128 * 64];
    __shared__ ushort Bs[128 * 64];
    __shared__ ushort A1a[128 * 64];
    __shared__ ushort A1b[128 * 64];

    const int tid  = threadIdx.x;
    const int lane = tid & 63;
    const int wid  = tid >> 6;
    const int wr   = wid >> 1;
    const int wc   = wid & 1;
    const int m0   = blockIdx.x * 128;
    const int lr   = lane & 15;
    const int lg   = lane >> 4;
    const int swz  = (lr & 7) << 4;

    f32x4 acc[4][4];
#pragma unroll
    for (int i = 0; i < 4; i++)
#pragma unroll
        for (int j = 0; j < 4; j++) acc[i][j] = (f32x4){0.f, 0.f, 0.f, 0.f};

    for (int k0 = 0; k0 < 512; k0 += 64) {
        if (k0) __syncthreads();
#pragma unroll
        for (int i = 0; i < 4; i++) {
            int ch = i * 256 + tid;
            int rr = ch >> 3, c8 = ch & 7;
            int c8p = c8 ^ (rr & 7);
            int srow = m0 + rr; if (srow > M - 1) srow = M - 1;
            gload16(XB + (size_t)srow * 512 + k0 + c8p * 8,
                    (char*)As + (i * 256 + wid * 64) * 16);
            gload16(FA1 + (size_t)rr * 512 + k0 + c8p * 8,
                    (char*)Bs + (i * 256 + wid * 64) * 16);
        }
        __syncthreads();
        const char* Ab = (const char*)As + (wr * 64 + lr) * 128;
        const char* Bb = (const char*)Bs + (wc * 64 + lr) * 128;
#pragma unroll
        for (int ks = 0; ks < 2; ks++) {
            int kx = (ks * 64 + lg * 16) ^ swz;
            bf16x8 a0 = *(const bf16x8*)(Ab + 0 * 2048 + kx);
            bf16x8 a1 = *(const bf16x8*)(Ab + 1 * 2048 + kx);
            bf16x8 a2 = *(const bf16x8*)(Ab + 2 * 2048 + kx);
            bf16x8 a3 = *(const bf16x8*)(Ab + 3 * 2048 + kx);
            bf16x8 b0 = *(const bf16x8*)(Bb + 0 * 2048 + kx);
            bf16x8 b1 = *(const bf16x8*)(Bb + 1 * 2048 + kx);
            bf16x8 b2 = *(const bf16x8*)(Bb + 2 * 2048 + kx);
            bf16x8 b3 = *(const bf16x8*)(Bb + 3 * 2048 + kx);
            acc[0][0] = __builtin_amdgcn_mfma_f32_16x16x32_bf16(a0, b0, acc[0][0], 0, 0, 0);
            acc[0][1] = __builtin_amdgcn_mfma_f32_16x16x32_bf16(a0, b1, acc[0][1], 0, 0, 0);
            acc[0][2] = __builtin_amdgcn_mfma_f32_16x16x32_bf16(a0, b2, acc[0][2], 0, 0, 0);
            acc[0][3] = __builtin_amdgcn_mfma_f32_16x16x32_bf16(a0, b3, acc[0][3], 0, 0, 0);
            acc[1][0] = __builtin_amdgcn_mfma_f32_16x16x32_bf16(a1, b0, acc[1][0], 0, 0, 0);
            acc[1][1] = __builtin_amdgcn_mfma_f32_16x16x32_bf16(a1, b1, acc[1][1], 0, 0, 0);
            acc[1][2] = __builtin_amdgcn_mfma_f32_16x16x32_bf16(a1, b2, acc[1][2], 0, 0, 0);
            acc[1][3] = __builtin_amdgcn_mfma_f32_16x16x32_bf16(a1, b3, acc[1][3], 0, 0, 0);
            acc[2][0] = __builtin_amdgcn_mfma_f32_16x16x32_bf16(a2, b0, acc[2][0], 0, 0, 0);
            acc[2][1] = __builtin_amdgcn_mfma_f32_16x16x32_bf16(a2, b1, acc[2][1], 0, 0, 0);
            acc[2][2] = __builtin_amdgcn_mfma_f32_16x16x32_bf16(a2, b2, acc[2][2], 0, 0, 0);
            acc[2][3] = __builtin_amdgcn_mfma_f32_16x16x32_bf16(a2, b3, acc[2][3], 0, 0, 0);
            acc[3][0] = __builtin_amdgcn_mfma_f32_16x16x32_bf16(a3, b0, acc[3][0], 0, 0, 0);
            acc[3][1] = __builtin_amdgcn_mfma_f32_16x16x32_bf16(a3, b1, acc[3][1], 0, 0, 0);
            acc[3][2] = __builtin_amdgcn_mfma_f32_16x16x32_bf16(a3, b2, acc[3][2], 0, 0, 0);
            acc[3][3] = __builtin_amdgcn_mfma_f32_16x16x32_bf16(a3, b3, acc[3][3], 0, 0, 0);
        }
    }

    // tanh + bias -> A1 in LDS (swizzled bf16, two 64-col halves)
#pragma unroll
    for (int mi = 0; mi < 4; mi++)
#pragma unroll
    for (int ni = 0; ni < 4; ni++) {
        f32x4 a = acc[mi][ni];
        int n = wc * 64 + ni * 16 + lr;
        ushort* buf = (n < 64) ? A1a : A1b;
        int c = n & 63;
#pragma unroll
        for (int j = 0; j < 4; j++) {
            int m = wr * 64 + mi * 16 + lg * 4 + j;
            float v = tanhf(a[j] + fa1b[n]);
            int byo = m * 128 + (((c >> 3) * 16) ^ ((m & 7) << 4)) + (c & 7) * 2;
            *(ushort*)((char*)buf + byo) = f2bf(v);
        }
    }
    __syncthreads();

#pragma unroll
    for (int i = 0; i < 4; i++) {
        int ch = i * 256 + tid;
        int rr = ch >> 3, c8 = ch & 7;
        int c8p = c8 ^ (rr & 7);
        gload16(FA2 + (size_t)rr * 128 + c8p * 8,
                (char*)As + (i * 256 + wid * 64) * 16);
        gload16(FA2 + (size_t)rr * 128 + 64 + c8p * 8,
                (char*)Bs + (i * 256 + wid * 64) * 16);
    }
    __syncthreads();

    f32x4 acc2[4][4];
#pragma unroll
    for (int i = 0; i < 4; i++)
#pragma unroll
        for (int j = 0; j < 4; j++) acc2[i][j] = (f32x4){0.f, 0.f, 0.f, 0.f};

#pragma unroll
    for (int kb = 0; kb < 2; kb++) {
        const char* Ab = (const char*)(kb ? A1b : A1a) + (wr * 64 + lr) * 128;
        const char* Bb = (const char*)(kb ? Bs : As) + (wc * 64 + lr) * 128;
#pragma unroll
        for (int ks = 0; ks < 2; ks++) {
            int kx = (ks * 64 + lg * 16) ^ swz;
            bf16x8 a0 = *(const bf16x8*)(Ab + 0 * 2048 + kx);
            bf16x8 a1 = *(const bf16x8*)(Ab + 1 * 2048 + kx);
            bf16x8 a2 = *(const bf16x8*)(Ab + 2 * 2048 + kx);
            bf16x8 a3 = *(const bf16x8*)(Ab + 3 * 2048 + kx);
            bf16x8 b0 = *(const bf16x8*)(Bb + 0 * 2048 + kx);
            bf16x8 b1 = *(const bf16x8*)(Bb + 1 * 2048 + kx);
            bf16x8 b2 = *(const bf16x8*)(Bb + 2 * 2048 + kx);
            bf16x8 b3 = *(const bf16x8*)(Bb + 3 * 2048 + kx);
            acc2[0][0] = __builtin_amdgcn_mfma_f32_16x16x32_bf16(a0, b0, acc2[0][0], 0, 0, 0);
            acc2[0][1] = __builtin_amdgcn_mfma_f32_16x16x32_bf16(a0, b1, acc2[0][1], 0, 0, 0);
            acc2[0][2] = __builtin_amdgcn_mfma_f32_16x16x32_bf16(a0, b2, acc2[0][2], 0, 0, 0);
            acc2[0][3] = __builtin_amdgcn_mfma_f32_16x16x32_bf16(a0, b3, acc2[0][3], 0, 0, 0);
            acc2[1][0] = __builtin_amdgcn_mfma_f32_16x16x32_bf16(a1, b0, acc2[1][0], 0, 0, 0);
            acc2[1][1] = __builtin_amdgcn_mfma_f32_16x16x32_bf16(a1, b1, acc2[1][1], 0, 0, 0);
            acc2[1][2] = __builtin_amdgcn_mfma_f32_16x16x32_bf16(a1, b2, acc2[1][2], 0, 0, 0);
            acc2[1][3] = __builtin_amdgcn_mfma_f32_16x16x32_bf16(a1, b3, acc2[1][3], 0, 0, 0);
            acc2[2][0] = __builtin_amdgcn_mfma_f32_16x16x32_bf16(a2, b0, acc2[2][0], 0, 0, 0);
            acc2[2][1] = __builtin_amdgcn_mfma_f32_16x16x32_bf16(a2, b1, acc2[2][1], 0, 0, 0);
            acc2[2][2] = __builtin_amdgcn_mfma_f32_16x16x32_bf16(a2, b2, acc2[2][2], 0, 0, 0);
            acc2[2][3] = __builtin_amdgcn_mfma_f32_16x16x32_bf16(a2, b3, acc2[2][3], 0, 0, 0);
            acc2[3][0] = __builtin_amdgcn_mfma_f32_16x16x32_bf16(a3, b0, acc2[3][0], 0, 0, 0);
            acc2[3][1] = __builtin_amdgcn_mfma_f32_16x16x32_bf16(a3, b1, acc2[3][1], 0, 0, 0);
            acc2[3][2] = __builtin_amdgcn_mfma_f32_16x16x32_bf16(a3, b2, acc2[3][2], 0, 0, 0);
            acc2[3][3] = __builtin_amdgcn_mfma_f32_16x16x32_bf16(a3, b3, acc2[3][3], 0, 0, 0);
        }
    }

#pragma unroll
    for (int mi = 0; mi < 4; mi++)
#pragma unroll
    for (int ni = 0; ni < 4; ni++) {
        f32x4 a = acc2[mi][ni];
        int n = wc * 64 + ni * 16 + lr;
#pragma unroll
        for (int j = 0; j < 4; j++) {
            int m = m0 + wr * 64 + mi * 16 + lg * 4 + j;
            if (m >= M) continue;
            A2[(size_t)m * 128 + n] = a[j] + fa2b[n];
        }
    }
}

// ============ split-K MFMA GEMM for emb: PART[z] = A[128,Kc]@B[N,Kc]^T =====
__global__ __launch_bounds__(256)
void mgemm_splitk(const ushort* __restrict__ Asrc, const ushort* __restrict__ Bsrc,
                  float* __restrict__ PART, int N, int Kp, int nsteps, int spz)
{
    __shared__ ushort As[128 * 64];
    __shared__ ushort Bs[128 * 64];

    const int tid  = threadIdx.x;
    const int lane = tid & 63;
    const int wid  = tid >> 6;
    const int wr   = wid >> 1;
    const int wc   = wid & 1;
    const int n0   = blockIdx.x * 128;
    const int z    = blockIdx.z;

    const int lr  = lane & 15;
    const int lg  = lane >> 4;
    const int swz = (lr & 7) << 4;

    f32x4 acc[4][4];
#pragma unroll
    for (int i = 0; i < 4; i++)
#pragma unroll
        for (int j = 0; j < 4; j++) acc[i][j] = (f32x4){0.f, 0.f, 0.f, 0.f};

    const int sb = z * spz;
    const int se = min(sb + spz, nsteps);

    for (int s = sb; s < se; s++) {
        int k0 = s * 64;
        if (s != sb) __syncthreads();
#pragma unroll
        for (int i = 0; i < 4; i++) {
            int ch = i * 256 + tid;
            int rr = ch >> 3, c8 = ch & 7;
            int c8p = c8 ^ (rr & 7);
            gload16(Asrc + (size_t)rr * Kp + k0 + c8p * 8,
                    (char*)As + (i * 256 + wid * 64) * 16);
            gload16(Bsrc + (size_t)(n0 + rr) * Kp + k0 + c8p * 8,
                    (char*)Bs + (i * 256 + wid * 64) * 16);
        }
        __syncthreads();

        const char* Ab = (const char*)As + (wr * 64 + lr) * 128;
        const char* Bb = (const char*)Bs + (wc * 64 + lr) * 128;
#pragma unroll
        for (int ks = 0; ks < 2; ks++) {
            int kx = (ks * 64 + lg * 16) ^ swz;
            bf16x8 a0 = *(const bf16x8*)(Ab + 0 * 2048 + kx);
            bf16x8 a1 = *(const bf16x8*)(Ab + 1 * 2048 + kx);
            bf16x8 a2 = *(const bf16x8*)(Ab + 2 * 2048 + kx);
            bf16x8 a3 = *(const bf16x8*)(Ab + 3 * 2048 + kx);
            bf16x8 b0 = *(const bf16x8*)(Bb + 0 * 2048 + kx);
            bf16x8 b1 = *(const bf16x8*)(Bb + 1 * 2048 + kx);
            bf16x8 b2 = *(const bf16x8*)(Bb + 2 * 2048 + kx);
            bf16x8 b3 = *(const bf16x8*)(Bb + 3 * 2048 + kx);
            acc[0][0] = __builtin_amdgcn_mfma_f32_16x16x32_bf16(a0, b0, acc[0][0], 0, 0, 0);
            acc[0][1] = __builtin_amdgcn_mfma_f32_16x16x32_bf16(a0, b1, acc[0][1], 0, 0, 0);
            acc[0][2] = __builtin_amdgcn_mfma_f32_16x16x32_bf16(a0, b2, acc[0][2], 0, 0, 0);
            acc[0][3] = __builtin_amdgcn_mfma_f32_16x16x32_bf16(a0, b3, acc[0][3], 0, 0, 0);
            acc[1][0] = __builtin_amdgcn_mfma_f32_16x16x32_bf16(a1, b0, acc[1][0], 0, 0, 0);
            acc[1][1] = __builtin_amdgcn_mfma_f32_16x16x32_bf16(a1, b1, acc[1][1], 0, 0, 0);
            acc[1][2] = __builtin_amdgcn_mfma_f32_16x16x32_bf16(a1, b2, acc[1][2], 0, 0, 0);
            acc[1][3] = __builtin_amdgcn_mfma_f32_16x16x32_bf16(a1, b3, acc[1][3], 0, 0, 0);
            acc[2][0] = __builtin_amdgcn_mfma_f32_16x16x32_bf16(a2, b0, acc[2][0], 0, 0, 0);
            acc[2][1] = __builtin_amdgcn_mfma_f32_16x16x32_bf16(a2, b1, acc[2][1], 0, 0, 0);
            acc[2][2] = __builtin_amdgcn_mfma_f32_16x16x32_bf16(a2, b2, acc[2][2], 0, 0, 0);
            acc[2][3] = __builtin_amdgcn_mfma_f32_16x16x32_bf16(a2, b3, acc[2][3], 0, 0, 0);
            acc[3][0] = __builtin_amdgcn_mfma_f32_16x16x32_bf16(a3, b0, acc[3][0], 0, 0, 0);
            acc[3][1] = __builtin_amdgcn_mfma_f32_16x16x32_bf16(a3, b1, acc[3][1], 0, 0, 0);
            acc[3][2] = __builtin_amdgcn_mfma_f32_16x16x32_bf16(a3, b2, acc[3][2], 0, 0, 0);
            acc[3][3] = __builtin_amdgcn_mfma_f32_16x16x32_bf16(a3, b3, acc[3][3], 0, 0, 0);
        }
    }

    float* outp = PART + (size_t)z * 128 * 512;
#pragma unroll
    for (int mi = 0; mi < 4; mi++) {
#pragma unroll
        for (int ni = 0; ni < 4; ni++) {
            f32x4 a = acc[mi][ni];
            int n = n0 + wc * 64 + ni * 16 + lr;
#pragma unroll
            for (int j = 0; j < 4; j++) {
                int m = wr * 64 + mi * 16 + lg * 4 + j;
                outp[(size_t)m * 512 + n] = a[j];
            }
        }
    }
}

__global__ void reduce_part(const float* __restrict__ PART, float* __restrict__ EMB, int Z)
{
    int idx = blockIdx.x * blockDim.x + threadIdx.x;   // 0..65535
    float s = 0.f;
    for (int z = 0; z < Z; z++) s += PART[(size_t)z * 65536 + idx];
    EMB[idx] = s;
}

// attn weights, transposed + bf16 + zero-pad: ATTWT[c][n], n in [0,Kp)
__global__ void att_w_t(const float* __restrict__ a2, const float* __restrict__ ms,
                        const float* __restrict__ ss, ushort* __restrict__ W,
                        int Nn, int Kp)
{
    int idx = blockIdx.x * blockDim.x + threadIdx.x;
    if (idx >= 128 * Kp) return;
    int c = idx / Kp, n = idx % Kp;
    float v = 0.f;
    if (n < Nn) v = expf(a2[(size_t)n * 128 + c] - ms[c]) / ss[c];
    W[idx] = f2bf(v);
}

// XB [Nn][512] bf16 -> XBT [512][Kp] bf16 (zero-pad n >= Nn), 64x64 LDS tiles
__global__ __launch_bounds__(256)
void t_xb(const ushort* __restrict__ XB, ushort* __restrict__ XBT, int Nn, int Kp)
{
    __shared__ ushort tile[64][72];
    const int n0 = blockIdx.x * 64;
    const int d0 = blockIdx.y * 64;
    const int tid = threadIdx.x;
#pragma unroll
    for (int i = 0; i < 2; i++) {
        int ch = i * 256 + tid;
        int r = ch >> 3, c8 = ch & 7;
        int n = n0 + r;
        ushort8v v = {0, 0, 0, 0, 0, 0, 0, 0};
        if (n < Nn) v = *(const ushort8v*)(XB + (size_t)n * 512 + d0 + c8 * 8);
        *(ushort8v*)&tile[r][c8 * 8] = v;
    }
    __syncthreads();
#pragma unroll
    for (int i = 0; i < 2; i++) {
        int ch = i * 256 + tid;
        int dr = ch >> 3, n8 = ch & 7;
        ushort8v v;
#pragma unroll
        for (int q = 0; q < 8; q++) v[q] = tile[n8 * 8 + q][dr];
        *(ushort8v*)(XBT + (size_t)(d0 + dr) * Kp + n0 + n8 * 8) = v;
    }
}

// ============ implicit-GEMM conv 3x3 stride2 pad1, NHWC bf16, IC=64 ========
template<int NI>
__global__ __launch_bounds__(256)
void conv_mfma(const ushort* __restrict__ in, const ushort* __restrict__ Wk,
               const float* __restrict__ bias, const float* __restrict__ gamma,
               const float* __restrict__ beta, ushort* __restrict__ outp,
               int IH, int IW, int OH, int OW)
{
    const int OC = NI * 16;
    __shared__ ushort As[128 * 64];
    __shared__ ushort Bs[NI * 16 * 64];

    const int tid  = threadIdx.x;
    const int lane = tid & 63;
    const int wv   = tid >> 6;
    const int lr   = lane & 15;
    const int lg   = lane >> 4;
    const int swz  = (lr & 7) << 4;
    const int m0   = blockIdx.x * 128;
    const int M    = OH * OW;

    f32x4 acc[2][NI];
#pragma unroll
    for (int i = 0; i < 2; i++)
#pragma unroll
        for (int j = 0; j < NI; j++) acc[i][j] = (f32x4){0.f, 0.f, 0.f, 0.f};

    for (int r = 0; r < 9; r++) {
        const int kh = r / 3, kw = r % 3;
        if (r) __syncthreads();
#pragma unroll
        for (int i = 0; i < 4; i++) {
            int ch = i * 256 + tid;
            int p = ch >> 3, c8 = ch & 7;
            int lb = p * 128 + ((c8 * 16) ^ ((p & 7) << 4));
            int gp = m0 + p; if (gp > M - 1) gp = M - 1;
            int oh = gp / OW, ow = gp % OW;
            int ih = oh * 2 - 1 + kh, iw = ow * 2 - 1 + kw;
            ushort8v v = {0, 0, 0, 0, 0, 0, 0, 0};
            if (ih >= 0 && ih < IH && iw >= 0 && iw < IW)
                v = *(const ushort8v*)(in + ((size_t)ih * IW + iw) * 64 + c8 * 8);
            *(ushort8v*)((char*)As + lb) = v;
        }
        for (int ch = tid; ch < OC * 8; ch += 256) {
            int oc = ch >> 3, c8 = ch & 7;
            int lb = oc * 128 + ((c8 * 16) ^ ((oc & 7) << 4));
            ushort8v v = *(const ushort8v*)(Wk + (size_t)oc * 576 + r * 64 + c8 * 8);
            *(ushort8v*)((char*)Bs + lb) = v;
        }
        __syncthreads();

        const char* Ab = (const char*)As + (wv * 32 + lr) * 128;
        const char* Bb = (const char*)Bs + lr * 128;
#pragma unroll
        for (int ks = 0; ks < 2; ks++) {
            int kx = (ks * 64 + lg * 16) ^ swz;
            bf16x8 a0 = *(const bf16x8*)(Ab + 0 * 2048 + kx);
            bf16x8 a1 = *(const bf16x8*)(Ab + 1 * 2048 + kx);
#pragma unroll
            for (int ni = 0; ni < NI; ni++) {
                bf16x8 bfr = *(const bf16x8*)(Bb + ni * 2048 + kx);
                acc[0][ni] = __builtin_amdgcn_mfma_f32_16x16x32_bf16(a0, bfr, acc[0][ni], 0, 0, 0);
                acc[1][ni] = __builtin_amdgcn_mfma_f32_16x16x32_bf16(a1, bfr, acc[1][ni], 0, 0, 0);
            }
        }
    }

#pragma unroll
    for (int mi = 0; mi < 2; mi++)
#pragma unroll
    for (int ni = 0; ni < NI; ni++) {
        f32x4 a = acc[mi][ni];
        int oc = ni * 16 + lr;
        float bv = bias[oc], gv = gamma[oc], btv = beta[oc];
#pragma unroll
        for (int j = 0; j < 4; j++) {
            int gp = m0 + wv * 32 + mi * 16 + lg * 4 + j;
            if (gp >= M) continue;
            float v = a[j] + bv;
            v = gv * v * BN_INV + btv;
            v = fmaxf(v, 0.f);
            outp[(size_t)gp * OC + oc] = f2bf(v);
        }
    }
}

// conv1: emb[128][512] f32 (1ch) -> e0[132][516][64] NHWC bf16, k3 s1 pad3, bn+relu
__global__ void conv1_nhwc(const float* __restrict__ emb, const float* __restrict__ w,
                           const float* __restrict__ b, const float* __restrict__ g,
                           const float* __restrict__ bb, ushort* __restrict__ outp)
{
    int oh = blockIdx.x;  // 0..131
    for (int idx = threadIdx.x; idx < 516 * 8; idx += 256) {
        int ow = idx >> 3, c8 = idx & 7;
        float pv[9];
#pragma unroll
        for (int kh = 0; kh < 3; kh++)
#pragma unroll
            for (int kw = 0; kw < 3; kw++) {
                int ih = oh - 3 + kh, iw = ow - 3 + kw;
                pv[kh * 3 + kw] = (ih >= 0 && ih < 128 && iw >= 0 && iw < 512)
                                  ? emb[ih * 512 + iw] : 0.f;
            }
        ushort8v o;
#pragma unroll
        for (int q = 0; q < 8; q++) {
            int oc = c8 * 8 + q;
            float v = b[oc];
#pragma unroll
            for (int i = 0; i < 9; i++) v = fmaf(pv[i], w[oc * 9 + i], v);
            v = g[oc] * v * BN_INV + bb[oc];
            v = fmaxf(v, 0.f);
            o[q] = f2bf(v);
        }
        *(ushort8v*)(outp + ((size_t)oh * 516 + ow) * 64 + c8 * 8) = o;
    }
}

// 3x3 maxpool s1 p1, NHWC bf16 (valid cells only)
__global__ void maxpool_nhwc(const ushort* __restrict__ in, ushort* __restrict__ out,
                             int H, int W, int C8)
{
    int h = blockIdx.x;
    int tot = W * C8;
    for (int idx = threadIdx.x; idx < tot; idx += blockDim.x) {
        int w0 = idx / C8, cg = idx % C8;
        float mx[8];
#pragma unroll
        for (int q = 0; q < 8; q++) mx[q] = -1e30f;
        for (int dh = -1; dh <= 1; dh++) {
            int hh = h + dh; if (hh < 0 || hh >= H) continue;
            for (int dw = -1; dw <= 1; dw++) {
                int ww = w0 + dw; if (ww < 0 || ww >= W) continue;
                ushort8v v = *(const ushort8v*)(in + ((size_t)hh * W + ww) * C8 * 8 + cg * 8);
#pragma unroll
                for (int q = 0; q < 8; q++) mx[q] = fmaxf(mx[q], bf2f(v[q]));
            }
        }
        ushort8v o;
#pragma unroll
        for (int q = 0; q < 8; q++) o[q] = f2bf(mx[q]);
        *(ushort8v*)(out + ((size_t)h * W + w0) * C8 * 8 + cg * 8) = o;
    }
}

// ==== fused conv2 + head (both single-block): [5][17][64] -> out[14] =======
__global__ __launch_bounds__(256)
void conv2_head(const ushort* __restrict__ in, const ushort* __restrict__ WC2,
                const float* __restrict__ c2b, const float* __restrict__ c2g,
                const float* __restrict__ c2bb,
                const float* __restrict__ fc1w, const float* __restrict__ fc1b,
                const float* __restrict__ fc2w, const float* __restrict__ fc2b,
                ushort* __restrict__ Q16, float* __restrict__ outp,
                int IH, int IW)
{
    __shared__ ushort As[128 * 64];
    __shared__ ushort Bs[16 * 64];
    __shared__ float flat[432];
    __shared__ float t1[1024];

    const int tid  = threadIdx.x;
    const int lane = tid & 63;
    const int wv   = tid >> 6;
    const int lr   = lane & 15;
    const int lg   = lane >> 4;
    const int swz  = (lr & 7) << 4;
    const int OH = 3, OW = 9, M = 27;

    f32x4 acc[2];
    acc[0] = (f32x4){0.f, 0.f, 0.f, 0.f};
    acc[1] = (f32x4){0.f, 0.f, 0.f, 0.f};

    for (int r = 0; r < 9; r++) {
        const int kh = r / 3, kw = r % 3;
        if (r) __syncthreads();
#pragma unroll
        for (int i = 0; i < 4; i++) {
            int ch = i * 256 + tid;
            int p = ch >> 3, c8 = ch & 7;
            int lb = p * 128 + ((c8 * 16) ^ ((p & 7) << 4));
            int gp = p; if (gp > M - 1) gp = M - 1;
            int oh = gp / OW, ow = gp % OW;
            int ih = oh * 2 - 1 + kh, iw = ow * 2 - 1 + kw;
            ushort8v v = {0, 0, 0, 0, 0, 0, 0, 0};
            if (ih >= 0 && ih < IH && iw >= 0 && iw < IW)
                v = *(const ushort8v*)(in + ((size_t)ih * IW + iw) * 64 + c8 * 8);
            *(ushort8v*)((char*)As + lb) = v;
        }
        for (int ch = tid; ch < 16 * 8; ch += 256) {
            int oc = ch >> 3, c8 = ch & 7;
            int lb = oc * 128 + ((c8 * 16) ^ ((oc & 7) << 4));
            ushort8v v = *(const ushort8v*)(WC2 + (size_t)oc * 576 + r * 64 + c8 * 8);
            *(ushort8v*)((char*)Bs + lb) = v;
        }
        __syncthreads();

        const char* Ab = (const char*)As + (wv * 32 + lr) * 128;
        const char* Bb = (const char*)Bs + lr * 128;
#pragma unroll
        for (int ks = 0; ks < 2; ks++) {
            int kx = (ks * 64 + lg * 16) ^ swz;
            bf16x8 a0 = *(const bf16x8*)(Ab + 0 * 2048 + kx);
            bf16x8 a1 = *(const bf16x8*)(Ab + 1 * 2048 + kx);
            bf16x8 bfr = *(const bf16x8*)(Bb + kx);
            acc[0] = __builtin_amdgcn_mfma_f32_16x16x32_bf16(a0, bfr, acc[0], 0, 0, 0);
            acc[1] = __builtin_amdgcn_mfma_f32_16x16x32_bf16(a1, bfr, acc[1], 0, 0, 0);
        }
    }

#pragma unroll
    for (int mi = 0; mi < 2; mi++) {
        f32x4 a = acc[mi];
        int oc = lr;
        float bv = c2b[oc], gv = c2g[oc], btv = c2bb[oc];
#pragma unroll
        for (int j = 0; j < 4; j++) {
            int gp = wv * 32 + mi * 16 + lg * 4 + j;
            if (gp >= M) continue;
            float v = a[j] + bv;
            v = gv * v * BN_INV + btv;
            v = fmaxf(v, 0.f);
            Q16[(size_t)gp * 16 + oc] = f2bf(v);
        }
    }
    __syncthreads();

    // head: maxpool [3][9][16] -> fc1 -> fc2 -> sigmoid
    for (int i = tid; i < 432; i += 256) {
        int c = i / 27, r = i % 27;
        int h = r / 9, w0 = r % 9;
        float m = -1e30f;
        for (int dh = -1; dh <= 1; dh++) {
            int hh = h + dh; if (hh < 0 || hh >= 3) continue;
            for (int dw = -1; dw <= 1; dw++) {
                int ww = w0 + dw; if (ww < 0 || ww >= 9) continue;
                m = fmaxf(m, bf2f(Q16[((size_t)hh * 9 + ww) * 16 + c]));
            }
        }
        flat[i] = m;
    }
    __syncthreads();
    for (int o = tid; o < 1024; o += 256) {
        float s = fc1b[o];
        const float* wr = fc1w + (size_t)o * 432;
        for (int k = 0; k < 432; k++) s = fmaf(flat[k], wr[k], s);
        t1[o] = s;
    }
    __syncthreads();
    int l = tid & 63;
    for (int o = wv; o < 14; o += 4) {
        float s = 0.f;
        const float* wr = fc2w + (size_t)o * 1024;
        for (int k = l; k < 1024; k += 64) s = fmaf(t1[k], wr[k], s);
        for (int sh = 32; sh > 0; sh >>= 1) s += __shfl_down(s, sh, 64);
        if (l == 0) outp[o] = 1.f / (1.f + expf(-(s + fc2b[o])));
    }
}

// ---------------- fused weight prep (cvt + conv reorder) --------------------
__global__ void prep_all(const float* w1l, const float* w1r, const float* w2l,
                         const float* w2r, const float* fa1, const float* fa2,
                         const float* c1w, const float* c2w,
                         ushort* W1L, ushort* W1R, ushort* W2L, ushort* W2R,
                         ushort* FA1, ushort* FA2, ushort* WC1, ushort* WC2)
{
    int i = blockIdx.x * blockDim.x + threadIdx.x;
    if (i < 796672) {
        const float* s; ushort* d; int j;
        if      (i < 327680)  { s = w1l; d = W1L; j = i; }
        else if (i < 655360)  { s = w1r; d = W1R; j = i - 327680; }
        else if (i < 720896)  { s = w2l; d = W2L; j = i - 655360; }
        else if (i < 786432)  { s = w2r; d = W2R; j = i - 720896; }
        else if (i < 794624)  { s = fa1; d = FA1; j = i - 786432; }
        else                  { s = fa2; d = FA2; j = i - 794624; }
        const float4 f0 = *(const float4*)(s + (size_t)j * 8);
        const float4 f1 = *(const float4*)(s + (size_t)j * 8 + 4);
        ushort8v v;
        v[0] = f2bf(f0.x); v[1] = f2bf(f0.y); v[2] = f2bf(f0.z); v[3] = f2bf(f0.w);
        v[4] = f2bf(f1.x); v[5] = f2bf(f1.y); v[6] = f2bf(f1.z); v[7] = f2bf(f1.w);
        *(ushort8v*)(d + (size_t)j * 8) = v;
    } else {
        int k = i - 796672;
        if (k >= 80 * 576) return;
        const float* w; ushort* wk; int idx;
        if (k < 64 * 576) { w = c1w; wk = WC1; idx = k; }
        else              { w = c2w; wk = WC2; idx = k - 64 * 576; }
        int oc = idx / 576, t = idx % 576;
        int r = t / 64, ic = t % 64;
        int kh = r / 3, kw = r % 3;
        wk[idx] = f2bf(w[((oc * 64 + ic) * 3 + kh) * 3 + kw]);
    }
}

// ---------------- single-block CSR build ------------------------------------
__global__ __launch_bounds__(1024)
void csr_build(const int* __restrict__ src, const int* __restrict__ dst,
               int* __restrict__ off, int* __restrict__ eidx, int E, int n)
{
    __shared__ int h[10000];
    __shared__ int tmp[1024];
    const int t = threadIdx.x;
    for (int i = t; i < n; i += 1024) h[i] = 0;
    __syncthreads();
    for (int e = t; e < E; e += 1024) atomicAdd(&h[dst[e]], 1);
    __syncthreads();
    const int PT = (n + 1023) / 1024;   // 10
    int b = t * PT, ls = 0;
    for (int k = 0; k < PT; k++) { int i = b + k; if (i < n) ls += h[i]; }
    tmp[t] = ls;
    __syncthreads();
    for (int s = 1; s < 1024; s <<= 1) {
        int v = (t >= s) ? tmp[t - s] : 0;
        __syncthreads();
        tmp[t] += v;
        __syncthreads();
    }
    int run = tmp[t] - ls;
    int cur[10];
    for (int k = 0; k < PT; k++) {
        int i = b + k;
        if (i < n) { off[i] = run; cur[k] = run; run += h[i]; }
    }
    if (t == 1023) off[n] = tmp[1023];
    __syncthreads();
    for (int k = 0; k < PT; k++) { int i = b + k; if (i < n) h[i] = cur[k]; }
    __syncthreads();
    for (int e = t; e < E; e += 1024) {
        int pos = atomicAdd(&h[dst[e]], 1);
        eidx[pos] = src[e];
    }
}

// ---------------- f32 -> bf16 convert (x -> XBF) ----------------------------
__global__ void cvt_k(const float* __restrict__ in, ushort* __restrict__ out, int n8)
{
    int i = blockIdx.x * blockDim.x + threadIdx.x;
    if (i >= n8) return;
    const float4 f0 = *(const float4*)(in + (size_t)i * 8);
    const float4 f1 = *(const float4*)(in + (size_t)i * 8 + 4);
    ushort8v v;
    v[0] = f2bf(f0.x); v[1] = f2bf(f0.y); v[2] = f2bf(f0.z); v[3] = f2bf(f0.w);
    v[4] = f2bf(f1.x); v[5] = f2bf(f1.y); v[6] = f2bf(f1.z); v[7] = f2bf(f1.w);
    *(ushort8v*)(out + (size_t)i * 8) = v;
}

// ---------------- attention softmax over nodes ------------------------------
__global__ __launch_bounds__(256)
void softmax_stats(const float* __restrict__ a2, float* __restrict__ ms,
                   float* __restrict__ ss, int Nn)
{
    int c = blockIdx.x;
    __shared__ float red[256];
    float mx = -1e30f;
    for (int n = threadIdx.x; n < Nn; n += 256)
        mx = fmaxf(mx, a2[(size_t)n * 128 + c]);
    red[threadIdx.x] = mx;
    __syncthreads();
    for (int s = 128; s > 0; s >>= 1) {
        if (threadIdx.x < s) red[threadIdx.x] = fmaxf(red[threadIdx.x], red[threadIdx.x + s]);
        __syncthreads();
    }
    mx = red[0];
    __syncthreads();
    float sum = 0.f;
    for (int n = threadIdx.x; n < Nn; n += 256)
        sum += expf(a2[(size_t)n * 128 + c] - mx);
    red[threadIdx.x] = sum;
    __syncthreads();
    for (int s = 128; s > 0; s >>= 1) {
        if (threadIdx.x < s) red[threadIdx.x] += red[threadIdx.x + s];
        __syncthreads();
    }
    if (threadIdx.x == 0) { ms[c] = mx; ss[c] = red[0]; }
}

// ---------------------------------------------------------------------------
extern "C" void kernel_launch(void* const* d_in, const int* in_sizes, int n_in,
                              void* d_out, int out_size, void* d_ws, size_t ws_size,
                              hipStream_t stream)
{
    const float* x     = (const float*)d_in[0];
    const int*   ei    = (const int*)d_in[1];
    const float* w1l   = (const float*)d_in[2];
    const float* b1    = (const float*)d_in[3];
    const float* w1r   = (const float*)d_in[4];
    const float* bn1g  = (const float*)d_in[5];
    const float* bn1b  = (const float*)d_in[6];
    const float* w2l   = (const float*)d_in[7];
    const float* b2    = (const float*)d_in[8];
    const float* w2r   = (const float*)d_in[9];
    const float* fa1w  = (const float*)d_in[10];
    const float* fa1b  = (const float*)d_in[11];
    const float* fa2w  = (const float*)d_in[12];
    const float* fa2b  = (const float*)d_in[13];
    const float* cnn1w = (const float*)d_in[14];
    const float* cnn1b = (const float*)d_in[15];
    const float* normg = (const float*)d_in[16];
    const float* normb = (const float*)d_in[17];
    const float* c1w   = (const float*)d_in[18];
    const float* c1b   = (const float*)d_in[19];
    const float* c1g   = (const float*)d_in[20];
    const float* c1bb  = (const float*)d_in[21];
    const float* c2w   = (const float*)d_in[22];
    const float* c2b   = (const float*)d_in[23];
    const float* c2g   = (const float*)d_in[24];
    const float* c2bb  = (const float*)d_in[25];
    const float* fc1w  = (const float*)d_in[26];
    const float* fc1b  = (const float*)d_in[27];
    const float* fc2w  = (const float*)d_in[28];
    const float* fc2b  = (const float*)d_in[29];
    float* out = (float*)d_out;

    const int Nn = 10000, E = 160000;
    const int Kp = 10048;   // 157*64
    char* ws = (char*)d_ws;

    // ---- workspace layout (bytes) — phase-checked, no live overlaps ----
    ushort* YL    = (ushort*)(ws + 0);           // 20,480,000
    ushort* ATTWT = (ushort*)(ws + 0);           // 2,572,288 (YL dead after gather_h1)
    ushort* XBT   = (ushort*)(ws + 2572288);     // -> 12,861,440
    ushort* P16   = (ushort*)(ws + 0);           // 8,718,336
    ushort* Q16   = (ushort*)(ws + 13000000);    // -> 15,179,584
    ushort* H1   = (ushort*)(ws + 20480000);     // 20,480,000
    ushort* XB   = (ushort*)(ws + 20480000);     // 10,240,000
    float*  A2   = (float*)(ws + 33280000);      // 5,120,000 -> 38,400,000
    ushort* YR   = (ushort*)(ws + 40960000);     // 20,480,000
    ushort* ZL   = (ushort*)(ws + 40960000);     // 10,240,000
    ushort* ZR   = (ushort*)(ws + 51200000);     // -> 61,440,000
    float*  PART = (float*)(ws + 40960000);      // 10,485,760 (ZL/ZR dead by splitk)
    int*   off    = (int*)(ws + 61520000);       // 40,004
    int*   eidx   = (int*)(ws + 61560128);       // 640,000 -> 62,200,128
    float*  MS   = (float*)(ws + 67360128);
    float*  SS   = (float*)(ws + 67360640);
    float*  EMB  = (float*)(ws + 67361152);      // -> 67,623,296
    ushort* W1L = (ushort*)(ws + 67623296);      // W1L+W1R contiguous = [2048][2560]
    ushort* W1R = (ushort*)(ws + 72866176);
    ushort* W2L = (ushort*)(ws + 78109056);      // W2L+W2R contiguous = [1024][1024]
    ushort* W2R = (ushort*)(ws + 79157632);
    ushort* FA1 = (ushort*)(ws + 80206208);
    ushort* FA2 = (ushort*)(ws + 80337280);
    ushort* WC1 = (ushort*)(ws + 80370048);
    ushort* WC2 = (ushort*)(ws + 80443776);      // -> 80,462,208
    ushort* XBF = (ushort*)(ws + 80462208);      // 51,200,000 -> 131,662,208
    const bool use_xbf = (ws_size >= (size_t)131662208);

    const int* src = ei;
    const int* dst = ei + E;

    // ---- weight prep (1) + CSR build (1) ----
    prep_all<<<(796672 + 80 * 576 + 255) / 256, 256, 0, stream>>>(
        w1l, w1r, w2l, w2r, fa1w, fa2w, c1w, c2w,
        W1L, W1R, W2L, W2R, FA1, FA2, WC1, WC2);
    csr_build<<<1, 1024, 0, stream>>>(src, dst, off, eidx, E, Nn);

    const int GY = (Nn + 127) / 128;   // 79

    // ---- SAGE layer 1: fused [YL | YR] = x @ [W1L;W1R]^T (N=2048) ----
    if (use_xbf) {
        cvt_k<<<(3200000 + 255) / 256, 256, 0, stream>>>(x, XBF, 3200000);
        mgemm<0, 5, ushort><<<dim3(2048 / 128, GY), 256, 0, stream>>>(
            XBF, W1L, YL, Nn, 2048, 2560, nullptr, YR);
    } else {
        mgemm<1, 5, ushort><<<dim3(2048 / 128, GY), 256, 0, stream>>>(
            x, W1L, YL, Nn, 2048, 2560, nullptr, YR);
    }
    gather_h1<<<Nn, 128, 0, stream>>>(YL, eidx, off, YR, b1, bn1g, bn1b, H1);

    // ---- SAGE layer 2: fused [ZL | ZR] = h1 @ [W2L;W2R]^T (N=1024) ----
    mgemm<0, 5, ushort><<<dim3(1024 / 128, GY), 256, 0, stream>>>(
        H1, W2L, ZL, Nn, 1024, 1024, nullptr, ZR);
    gather_xb<<<Nn, 64, 0, stream>>>(ZL, eidx, off, ZR, b2, XB);

    // ---- attention (fused MLP) ----
    attn_a1a2<<<GY, 256, 0, stream>>>(XB, FA1, fa1b, FA2, fa2b, A2, Nn);
    softmax_stats<<<128, 256, 0, stream>>>(A2, MS, SS, Nn);
    att_w_t<<<(128 * Kp + 255) / 256, 256, 0, stream>>>(A2, MS, SS, ATTWT, Nn, Kp);
    t_xb<<<dim3(Kp / 64, 8), 256, 0, stream>>>(XB, XBT, Nn, Kp);
    mgemm_splitk<<<dim3(4, 1, 40), 256, 0, stream>>>(ATTWT, XBT, PART, 512, Kp, 157, 4);
    reduce_part<<<256, 256, 0, stream>>>(PART, EMB, 40);

    // ---- CNN (separate kernels — cooperative tail was 543 us, reverted) ----
    conv1_nhwc<<<132, 256, 0, stream>>>(EMB, cnn1w, cnn1b, normg, normb, P16);
    int H = 132, W = 516;
    for (int it = 0; it < 5; it++) {
        int OH = (H - 1) / 2 + 1, OW = (W - 1) / 2 + 1;
        int M = OH * OW;
        conv_mfma<4><<<(M + 127) / 128, 256, 0, stream>>>(
            P16, WC1, c1b, c1g, c1bb, Q16, H, W, OH, OW);
        maxpool_nhwc<<<OH, 256, 0, stream>>>(Q16, P16, OH, OW, 8);
        H = OH; W = OW;
    }
    // conv2 + head fused (both single-block)
    conv2_head<<<1, 256, 0, stream>>>(P16, WC2, c2b, c2g, c2bb,
                                      fc1w, fc1b, fc2w, fc2b, Q16, out, H, W);
}

// Round 12
// 662.120 us; speedup vs baseline: 1.5645x; 1.3660x over previous
//
#include <hip/hip_runtime.h>
#include <cstdint>
#include <cstddef>

typedef unsigned short ushort;
typedef __attribute__((ext_vector_type(8))) short bf16x8;
typedef __attribute__((ext_vector_type(8))) unsigned short ushort8v;
typedef __attribute__((ext_vector_type(4))) float f32x4;

// 1/sqrt(1+1e-5)
#define BN_INV 0.9999950000374997f

__device__ inline ushort f2bf(float f) {
    union { float f; unsigned u; } x; x.f = f;
    unsigned r = x.u + 0x7fffu + ((x.u >> 16) & 1u);
    return (ushort)(r >> 16);
}
__device__ inline float bf2f(ushort u) {
    union { unsigned u; float f; } x; x.u = ((unsigned)u) << 16;
    return x.f;
}

// async global->LDS, 16B per lane. LDS dest is wave-uniform base + lane*16.
__device__ __forceinline__ void gload16(const void* g, void* l) {
    __builtin_amdgcn_global_load_lds(
        (const __attribute__((address_space(1))) unsigned int*)g,
        (__attribute__((address_space(3))) unsigned int*)l, 16, 0, 0);
}

// ======================= MFMA bf16 GEMM ====================================
// C[M,N] = A[M,K] @ B[N,K]^T.  B always bf16.
// AMODE 0: A bf16 via global_load_lds w/ pre-swizzled source.
// AMODE 1: A f32 (reg-converted), reg-staged swizzled LDS writes.
// XCD-chunked bijective swizzle, N-INNER (A panels L2-resident, B via L3).
// EPIL 5: split-write at N/2: n<N/2 -> C, else -> C2 (row stride N/2)
template<int AMODE, int EPIL, typename OutT>
__global__ __launch_bounds__(256)
void mgemm(const void* __restrict__ Asrc, const ushort* __restrict__ Bsrc,
           OutT* __restrict__ C, int M, int N, int K,
           const float* __restrict__ bias, ushort* __restrict__ C2)
{
    __shared__ ushort As[128 * 64];
    __shared__ ushort Bs[128 * 64];

    const int tid  = threadIdx.x;
    const int lane = tid & 63;
    const int wid  = tid >> 6;
    const int wr   = wid >> 1;
    const int wc   = wid & 1;

    const int nwg  = gridDim.x * gridDim.y;
    const int orig = blockIdx.y * gridDim.x + blockIdx.x;
    const int q    = nwg >> 3, r = nwg & 7;
    const int xcd  = orig & 7, ii = orig >> 3;
    const int wg   = (xcd < r ? xcd * (q + 1) : r * (q + 1) + (xcd - r) * q) + ii;
    const int m0   = (wg / gridDim.x) * 128;
    const int n0   = (wg % gridDim.x) * 128;

    const int lr  = lane & 15;
    const int lg  = lane >> 4;
    const int swz = (lr & 7) << 4;

    f32x4 acc[4][4];
#pragma unroll
    for (int i = 0; i < 4; i++)
#pragma unroll
        for (int j = 0; j < 4; j++) acc[i][j] = (f32x4){0.f, 0.f, 0.f, 0.f};

    for (int k0 = 0; k0 < K; k0 += 64) {
        if (k0) __syncthreads();
        if constexpr (AMODE == 0) {
#pragma unroll
            for (int i = 0; i < 4; i++) {
                int ch = i * 256 + tid;
                int rr = ch >> 3, c8 = ch & 7;
                int c8p = c8 ^ (rr & 7);
                int srow = m0 + rr; if (srow > M - 1) srow = M - 1;
                gload16((const ushort*)Asrc + (size_t)srow * K + k0 + c8p * 8,
                        (char*)As + (i * 256 + wid * 64) * 16);
                gload16(Bsrc + (size_t)(n0 + rr) * K + k0 + c8p * 8,
                        (char*)Bs + (i * 256 + wid * 64) * 16);
            }
        } else {
#pragma unroll
            for (int i = 0; i < 4; i++) {
                int ch = i * 256 + tid;
                int rr = ch >> 3, c8 = ch & 7;
                int lb = rr * 128 + ((c8 * 16) ^ ((rr & 7) << 4));
                int srow = m0 + rr; if (srow > M - 1) srow = M - 1;
                const float* ap = (const float*)Asrc + (size_t)srow * K + k0 + c8 * 8;
                float4 f0 = *(const float4*)ap;
                float4 f1 = *(const float4*)(ap + 4);
                ushort8v va;
                va[0] = f2bf(f0.x); va[1] = f2bf(f0.y); va[2] = f2bf(f0.z); va[3] = f2bf(f0.w);
                va[4] = f2bf(f1.x); va[5] = f2bf(f1.y); va[6] = f2bf(f1.z); va[7] = f2bf(f1.w);
                *(ushort8v*)((char*)As + lb) = va;
                ushort8v vb = *(const ushort8v*)(Bsrc + (size_t)(n0 + rr) * K + k0 + c8 * 8);
                *(ushort8v*)((char*)Bs + lb) = vb;
            }
        }
        __syncthreads();

        const char* Ab = (const char*)As + (wr * 64 + lr) * 128;
        const char* Bb = (const char*)Bs + (wc * 64 + lr) * 128;
#pragma unroll
        for (int ks = 0; ks < 2; ks++) {
            int kx = (ks * 64 + lg * 16) ^ swz;
            bf16x8 a0 = *(const bf16x8*)(Ab + 0 * 2048 + kx);
            bf16x8 a1 = *(const bf16x8*)(Ab + 1 * 2048 + kx);
            bf16x8 a2 = *(const bf16x8*)(Ab + 2 * 2048 + kx);
            bf16x8 a3 = *(const bf16x8*)(Ab + 3 * 2048 + kx);
            bf16x8 b0 = *(const bf16x8*)(Bb + 0 * 2048 + kx);
            bf16x8 b1 = *(const bf16x8*)(Bb + 1 * 2048 + kx);
            bf16x8 b2 = *(const bf16x8*)(Bb + 2 * 2048 + kx);
            bf16x8 b3 = *(const bf16x8*)(Bb + 3 * 2048 + kx);
            acc[0][0] = __builtin_amdgcn_mfma_f32_16x16x32_bf16(a0, b0, acc[0][0], 0, 0, 0);
            acc[0][1] = __builtin_amdgcn_mfma_f32_16x16x32_bf16(a0, b1, acc[0][1], 0, 0, 0);
            acc[0][2] = __builtin_amdgcn_mfma_f32_16x16x32_bf16(a0, b2, acc[0][2], 0, 0, 0);
            acc[0][3] = __builtin_amdgcn_mfma_f32_16x16x32_bf16(a0, b3, acc[0][3], 0, 0, 0);
            acc[1][0] = __builtin_amdgcn_mfma_f32_16x16x32_bf16(a1, b0, acc[1][0], 0, 0, 0);
            acc[1][1] = __builtin_amdgcn_mfma_f32_16x16x32_bf16(a1, b1, acc[1][1], 0, 0, 0);
            acc[1][2] = __builtin_amdgcn_mfma_f32_16x16x32_bf16(a1, b2, acc[1][2], 0, 0, 0);
            acc[1][3] = __builtin_amdgcn_mfma_f32_16x16x32_bf16(a1, b3, acc[1][3], 0, 0, 0);
            acc[2][0] = __builtin_amdgcn_mfma_f32_16x16x32_bf16(a2, b0, acc[2][0], 0, 0, 0);
            acc[2][1] = __builtin_amdgcn_mfma_f32_16x16x32_bf16(a2, b1, acc[2][1], 0, 0, 0);
            acc[2][2] = __builtin_amdgcn_mfma_f32_16x16x32_bf16(a2, b2, acc[2][2], 0, 0, 0);
            acc[2][3] = __builtin_amdgcn_mfma_f32_16x16x32_bf16(a2, b3, acc[2][3], 0, 0, 0);
            acc[3][0] = __builtin_amdgcn_mfma_f32_16x16x32_bf16(a3, b0, acc[3][0], 0, 0, 0);
            acc[3][1] = __builtin_amdgcn_mfma_f32_16x16x32_bf16(a3, b1, acc[3][1], 0, 0, 0);
            acc[3][2] = __builtin_amdgcn_mfma_f32_16x16x32_bf16(a3, b2, acc[3][2], 0, 0, 0);
            acc[3][3] = __builtin_amdgcn_mfma_f32_16x16x32_bf16(a3, b3, acc[3][3], 0, 0, 0);
        }
    }

#pragma unroll
    for (int mi = 0; mi < 4; mi++) {
#pragma unroll
        for (int ni = 0; ni < 4; ni++) {
            f32x4 a = acc[mi][ni];
            int n = n0 + wc * 64 + ni * 16 + lr;
#pragma unroll
            for (int j = 0; j < 4; j++) {
                int m = m0 + wr * 64 + mi * 16 + lg * 4 + j;
                if (m >= M) continue;
                float v = a[j];
                if (EPIL == 5) {
                    int half = N >> 1;
                    ushort* dst = (n < half) ? (ushort*)C : C2;
                    dst[(size_t)m * half + (n & (half - 1))] = f2bf(v);
                } else {
                    if (sizeof(OutT) == 2) ((ushort*)C)[(size_t)m * N + n] = f2bf(v);
                    else                   ((float*)C)[(size_t)m * N + n] = v;
                }
            }
        }
    }
}

// ==== fused gather + SAGE-1 epilogue: H1 = bn(relu(mean_j YL_j + b1 + YR)) ==
__global__ void gather_h1(const ushort* __restrict__ YL, const int* __restrict__ eidx,
                          const int* __restrict__ off, const ushort* __restrict__ YR,
                          const float* __restrict__ b1, const float* __restrict__ g,
                          const float* __restrict__ bb, ushort* __restrict__ H1)
{
    int n = blockIdx.x;
    int beg = off[n], end = off[n + 1];
    float inv = 1.f / fmaxf((float)(end - beg), 1.f);
    float s0 = 0, s1 = 0, s2 = 0, s3 = 0, s4 = 0, s5 = 0, s6 = 0, s7 = 0;
    for (int e = beg; e < end; e++) {
        ushort8v v = *(const ushort8v*)(YL + (size_t)eidx[e] * 1024 + threadIdx.x * 8);
        s0 += bf2f(v[0]); s1 += bf2f(v[1]); s2 += bf2f(v[2]); s3 += bf2f(v[3]);
        s4 += bf2f(v[4]); s5 += bf2f(v[5]); s6 += bf2f(v[6]); s7 += bf2f(v[7]);
    }
    float sv[8] = {s0, s1, s2, s3, s4, s5, s6, s7};
    ushort8v yr = *(const ushort8v*)(YR + (size_t)n * 1024 + threadIdx.x * 8);
    ushort8v o;
#pragma unroll
    for (int qq = 0; qq < 8; qq++) {
        int c = threadIdx.x * 8 + qq;
        float v = sv[qq] * inv + b1[c] + bf2f(yr[qq]);
        v = fmaxf(v, 0.f);
        v = g[c] * v * BN_INV + bb[c];
        o[qq] = f2bf(v);
    }
    *(ushort8v*)(H1 + (size_t)n * 1024 + threadIdx.x * 8) = o;
}

// ==== fused gather + SAGE-2 epilogue: XB = mean_j ZL_j + b2 + ZR ===========
__global__ void gather_xb(const ushort* __restrict__ ZL, const int* __restrict__ eidx,
                          const int* __restrict__ off, const ushort* __restrict__ ZR,
                          const float* __restrict__ b2, ushort* __restrict__ XB)
{
    int n = blockIdx.x;
    int beg = off[n], end = off[n + 1];
    float inv = 1.f / fmaxf((float)(end - beg), 1.f);
    float s0 = 0, s1 = 0, s2 = 0, s3 = 0, s4 = 0, s5 = 0, s6 = 0, s7 = 0;
    for (int e = beg; e < end; e++) {
        ushort8v v = *(const ushort8v*)(ZL + (size_t)eidx[e] * 512 + threadIdx.x * 8);
        s0 += bf2f(v[0]); s1 += bf2f(v[1]); s2 += bf2f(v[2]); s3 += bf2f(v[3]);
        s4 += bf2f(v[4]); s5 += bf2f(v[5]); s6 += bf2f(v[6]); s7 += bf2f(v[7]);
    }
    float sv[8] = {s0, s1, s2, s3, s4, s5, s6, s7};
    ushort8v zr = *(const ushort8v*)(ZR + (size_t)n * 512 + threadIdx.x * 8);
    ushort8v o;
#pragma unroll
    for (int qq = 0; qq < 8; qq++) {
        int c = threadIdx.x * 8 + qq;
        o[qq] = f2bf(sv[qq] * inv + b2[c] + bf2f(zr[qq]));
    }
    *(ushort8v*)(XB + (size_t)n * 512 + threadIdx.x * 8) = o;
}

// ==== fused attention MLP: A2 = tanh(XB@FA1^T + b1f)@FA2^T + b2f ===========
__global__ __launch_bounds__(256)
void attn_a1a2(const ushort* __restrict__ XB, const ushort* __restrict__ FA1,
               const float* __restrict__ fa1b, const ushort* __restrict__ FA2,
               const float* __restrict__ fa2b, float* __restrict__ A2, int M)
{
    __shared__ ushort As[128 * 64];
    __shared__ ushort Bs[128 * 64];
    __shared__ ushort A1a[128 * 64];
    __shared__ ushort A1b[128 * 64];

    const int tid  = threadIdx.x;
    const int lane = tid & 63;
    const int wid  = tid >> 6;
    const int wr   = wid >> 1;
    const int wc   = wid & 1;
    const int m0   = blockIdx.x * 128;
    const int lr   = lane & 15;
    const int lg   = lane >> 4;
    const int swz  = (lr & 7) << 4;

    f32x4 acc[4][4];
#pragma unroll
    for (int i = 0; i < 4; i++)
#pragma unroll
        for (int j = 0; j < 4; j++) acc[i][j] = (f32x4){0.f, 0.f, 0.f, 0.f};

    for (int k0 = 0; k0 < 512; k0 += 64) {
        if (k0) __syncthreads();
#pragma unroll
        for (int i = 0; i < 4; i++) {
            int ch = i * 256 + tid;
            int rr = ch >> 3, c8 = ch & 7;
            int c8p = c8 ^ (rr & 7);
            int srow = m0 + rr; if (srow > M - 1) srow = M - 1;
            gload16(XB + (size_t)srow * 512 + k0 + c8p * 8,
                    (char*)As + (i * 256 + wid * 64) * 16);
            gload16(FA1 + (size_t)rr * 512 + k0 + c8p * 8,
                    (char*)Bs + (i * 256 + wid * 64) * 16);
        }
        __syncthreads();
        const char* Ab = (const char*)As + (wr * 64 + lr) * 128;
        const char* Bb = (const char*)Bs + (wc * 64 + lr) * 128;
#pragma unroll
        for (int ks = 0; ks < 2; ks++) {
            int kx = (ks * 64 + lg * 16) ^ swz;
            bf16x8 a0 = *(const bf16x8*)(Ab + 0 * 2048 + kx);
            bf16x8 a1 = *(const bf16x8*)(Ab + 1 * 2048 + kx);
            bf16x8 a2 = *(const bf16x8*)(Ab + 2 * 2048 + kx);
            bf16x8 a3 = *(const bf16x8*)(Ab + 3 * 2048 + kx);
            bf16x8 b0 = *(const bf16x8*)(Bb + 0 * 2048 + kx);
            bf16x8 b1 = *(const bf16x8*)(Bb + 1 * 2048 + kx);
            bf16x8 b2 = *(const bf16x8*)(Bb + 2 * 2048 + kx);
            bf16x8 b3 = *(const bf16x8*)(Bb + 3 * 2048 + kx);
            acc[0][0] = __builtin_amdgcn_mfma_f32_16x16x32_bf16(a0, b0, acc[0][0], 0, 0, 0);
            acc[0][1] = __builtin_amdgcn_mfma_f32_16x16x32_bf16(a0, b1, acc[0][1], 0, 0, 0);
            acc[0][2] = __builtin_amdgcn_mfma_f32_16x16x32_bf16(a0, b2, acc[0][2], 0, 0, 0);
            acc[0][3] = __builtin_amdgcn_mfma_f32_16x16x32_bf16(a0, b3, acc[0][3], 0, 0, 0);
            acc[1][0] = __builtin_amdgcn_mfma_f32_16x16x32_bf16(a1, b0, acc[1][0], 0, 0, 0);
            acc[1][1] = __builtin_amdgcn_mfma_f32_16x16x32_bf16(a1, b1, acc[1][1], 0, 0, 0);
            acc[1][2] = __builtin_amdgcn_mfma_f32_16x16x32_bf16(a1, b2, acc[1][2], 0, 0, 0);
            acc[1][3] = __builtin_amdgcn_mfma_f32_16x16x32_bf16(a1, b3, acc[1][3], 0, 0, 0);
            acc[2][0] = __builtin_amdgcn_mfma_f32_16x16x32_bf16(a2, b0, acc[2][0], 0, 0, 0);
            acc[2][1] = __builtin_amdgcn_mfma_f32_16x16x32_bf16(a2, b1, acc[2][1], 0, 0, 0);
            acc[2][2] = __builtin_amdgcn_mfma_f32_16x16x32_bf16(a2, b2, acc[2][2], 0, 0, 0);
            acc[2][3] = __builtin_amdgcn_mfma_f32_16x16x32_bf16(a2, b3, acc[2][3], 0, 0, 0);
            acc[3][0] = __builtin_amdgcn_mfma_f32_16x16x32_bf16(a3, b0, acc[3][0], 0, 0, 0);
            acc[3][1] = __builtin_amdgcn_mfma_f32_16x16x32_bf16(a3, b1, acc[3][1], 0, 0, 0);
            acc[3][2] = __builtin_amdgcn_mfma_f32_16x16x32_bf16(a3, b2, acc[3][2], 0, 0, 0);
            acc[3][3] = __builtin_amdgcn_mfma_f32_16x16x32_bf16(a3, b3, acc[3][3], 0, 0, 0);
        }
    }

    // tanh + bias -> A1 in LDS (swizzled bf16, two 64-col halves)
#pragma unroll
    for (int mi = 0; mi < 4; mi++)
#pragma unroll
    for (int ni = 0; ni < 4; ni++) {
        f32x4 a = acc[mi][ni];
        int n = wc * 64 + ni * 16 + lr;
        ushort* buf = (n < 64) ? A1a : A1b;
        int c = n & 63;
#pragma unroll
        for (int j = 0; j < 4; j++) {
            int m = wr * 64 + mi * 16 + lg * 4 + j;
            float v = tanhf(a[j] + fa1b[n]);
            int byo = m * 128 + (((c >> 3) * 16) ^ ((m & 7) << 4)) + (c & 7) * 2;
            *(ushort*)((char*)buf + byo) = f2bf(v);
        }
    }
    __syncthreads();

#pragma unroll
    for (int i = 0; i < 4; i++) {
        int ch = i * 256 + tid;
        int rr = ch >> 3, c8 = ch & 7;
        int c8p = c8 ^ (rr & 7);
        gload16(FA2 + (size_t)rr * 128 + c8p * 8,
                (char*)As + (i * 256 + wid * 64) * 16);
        gload16(FA2 + (size_t)rr * 128 + 64 + c8p * 8,
                (char*)Bs + (i * 256 + wid * 64) * 16);
    }
    __syncthreads();

    f32x4 acc2[4][4];
#pragma unroll
    for (int i = 0; i < 4; i++)
#pragma unroll
        for (int j = 0; j < 4; j++) acc2[i][j] = (f32x4){0.f, 0.f, 0.f, 0.f};

#pragma unroll
    for (int kb = 0; kb < 2; kb++) {
        const char* Ab = (const char*)(kb ? A1b : A1a) + (wr * 64 + lr) * 128;
        const char* Bb = (const char*)(kb ? Bs : As) + (wc * 64 + lr) * 128;
#pragma unroll
        for (int ks = 0; ks < 2; ks++) {
            int kx = (ks * 64 + lg * 16) ^ swz;
            bf16x8 a0 = *(const bf16x8*)(Ab + 0 * 2048 + kx);
            bf16x8 a1 = *(const bf16x8*)(Ab + 1 * 2048 + kx);
            bf16x8 a2 = *(const bf16x8*)(Ab + 2 * 2048 + kx);
            bf16x8 a3 = *(const bf16x8*)(Ab + 3 * 2048 + kx);
            bf16x8 b0 = *(const bf16x8*)(Bb + 0 * 2048 + kx);
            bf16x8 b1 = *(const bf16x8*)(Bb + 1 * 2048 + kx);
            bf16x8 b2 = *(const bf16x8*)(Bb + 2 * 2048 + kx);
            bf16x8 b3 = *(const bf16x8*)(Bb + 3 * 2048 + kx);
            acc2[0][0] = __builtin_amdgcn_mfma_f32_16x16x32_bf16(a0, b0, acc2[0][0], 0, 0, 0);
            acc2[0][1] = __builtin_amdgcn_mfma_f32_16x16x32_bf16(a0, b1, acc2[0][1], 0, 0, 0);
            acc2[0][2] = __builtin_amdgcn_mfma_f32_16x16x32_bf16(a0, b2, acc2[0][2], 0, 0, 0);
            acc2[0][3] = __builtin_amdgcn_mfma_f32_16x16x32_bf16(a0, b3, acc2[0][3], 0, 0, 0);
            acc2[1][0] = __builtin_amdgcn_mfma_f32_16x16x32_bf16(a1, b0, acc2[1][0], 0, 0, 0);
            acc2[1][1] = __builtin_amdgcn_mfma_f32_16x16x32_bf16(a1, b1, acc2[1][1], 0, 0, 0);
            acc2[1][2] = __builtin_amdgcn_mfma_f32_16x16x32_bf16(a1, b2, acc2[1][2], 0, 0, 0);
            acc2[1][3] = __builtin_amdgcn_mfma_f32_16x16x32_bf16(a1, b3, acc2[1][3], 0, 0, 0);
            acc2[2][0] = __builtin_amdgcn_mfma_f32_16x16x32_bf16(a2, b0, acc2[2][0], 0, 0, 0);
            acc2[2][1] = __builtin_amdgcn_mfma_f32_16x16x32_bf16(a2, b1, acc2[2][1], 0, 0, 0);
            acc2[2][2] = __builtin_amdgcn_mfma_f32_16x16x32_bf16(a2, b2, acc2[2][2], 0, 0, 0);
            acc2[2][3] = __builtin_amdgcn_mfma_f32_16x16x32_bf16(a2, b3, acc2[2][3], 0, 0, 0);
            acc2[3][0] = __builtin_amdgcn_mfma_f32_16x16x32_bf16(a3, b0, acc2[3][0], 0, 0, 0);
            acc2[3][1] = __builtin_amdgcn_mfma_f32_16x16x32_bf16(a3, b1, acc2[3][1], 0, 0, 0);
            acc2[3][2] = __builtin_amdgcn_mfma_f32_16x16x32_bf16(a3, b2, acc2[3][2], 0, 0, 0);
            acc2[3][3] = __builtin_amdgcn_mfma_f32_16x16x32_bf16(a3, b3, acc2[3][3], 0, 0, 0);
        }
    }

#pragma unroll
    for (int mi = 0; mi < 4; mi++)
#pragma unroll
    for (int ni = 0; ni < 4; ni++) {
        f32x4 a = acc2[mi][ni];
        int n = wc * 64 + ni * 16 + lr;
#pragma unroll
        for (int j = 0; j < 4; j++) {
            int m = m0 + wr * 64 + mi * 16 + lg * 4 + j;
            if (m >= M) continue;
            A2[(size_t)m * 128 + n] = a[j] + fa2b[n];
        }
    }
}

// ============ split-K MFMA GEMM for emb: PART[z] = A[128,Kc]@B[N,Kc]^T =====
__global__ __launch_bounds__(256)
void mgemm_splitk(const ushort* __restrict__ Asrc, const ushort* __restrict__ Bsrc,
                  float* __restrict__ PART, int N, int Kp, int nsteps, int spz)
{
    __shared__ ushort As[128 * 64];
    __shared__ ushort Bs[128 * 64];

    const int tid  = threadIdx.x;
    const int lane = tid & 63;
    const int wid  = tid >> 6;
    const int wr   = wid >> 1;
    const int wc   = wid & 1;
    const int n0   = blockIdx.x * 128;
    const int z    = blockIdx.z;

    const int lr  = lane & 15;
    const int lg  = lane >> 4;
    const int swz = (lr & 7) << 4;

    f32x4 acc[4][4];
#pragma unroll
    for (int i = 0; i < 4; i++)
#pragma unroll
        for (int j = 0; j < 4; j++) acc[i][j] = (f32x4){0.f, 0.f, 0.f, 0.f};

    const int sb = z * spz;
    const int se = min(sb + spz, nsteps);

    for (int s = sb; s < se; s++) {
        int k0 = s * 64;
        if (s != sb) __syncthreads();
#pragma unroll
        for (int i = 0; i < 4; i++) {
            int ch = i * 256 + tid;
            int rr = ch >> 3, c8 = ch & 7;
            int c8p = c8 ^ (rr & 7);
            gload16(Asrc + (size_t)rr * Kp + k0 + c8p * 8,
                    (char*)As + (i * 256 + wid * 64) * 16);
            gload16(Bsrc + (size_t)(n0 + rr) * Kp + k0 + c8p * 8,
                    (char*)Bs + (i * 256 + wid * 64) * 16);
        }
        __syncthreads();

        const char* Ab = (const char*)As + (wr * 64 + lr) * 128;
        const char* Bb = (const char*)Bs + (wc * 64 + lr) * 128;
#pragma unroll
        for (int ks = 0; ks < 2; ks++) {
            int kx = (ks * 64 + lg * 16) ^ swz;
            bf16x8 a0 = *(const bf16x8*)(Ab + 0 * 2048 + kx);
            bf16x8 a1 = *(const bf16x8*)(Ab + 1 * 2048 + kx);
            bf16x8 a2 = *(const bf16x8*)(Ab + 2 * 2048 + kx);
            bf16x8 a3 = *(const bf16x8*)(Ab + 3 * 2048 + kx);
            bf16x8 b0 = *(const bf16x8*)(Bb + 0 * 2048 + kx);
            bf16x8 b1 = *(const bf16x8*)(Bb + 1 * 2048 + kx);
            bf16x8 b2 = *(const bf16x8*)(Bb + 2 * 2048 + kx);
            bf16x8 b3 = *(const bf16x8*)(Bb + 3 * 2048 + kx);
            acc[0][0] = __builtin_amdgcn_mfma_f32_16x16x32_bf16(a0, b0, acc[0][0], 0, 0, 0);
            acc[0][1] = __builtin_amdgcn_mfma_f32_16x16x32_bf16(a0, b1, acc[0][1], 0, 0, 0);
            acc[0][2] = __builtin_amdgcn_mfma_f32_16x16x32_bf16(a0, b2, acc[0][2], 0, 0, 0);
            acc[0][3] = __builtin_amdgcn_mfma_f32_16x16x32_bf16(a0, b3, acc[0][3], 0, 0, 0);
            acc[1][0] = __builtin_amdgcn_mfma_f32_16x16x32_bf16(a1, b0, acc[1][0], 0, 0, 0);
            acc[1][1] = __builtin_amdgcn_mfma_f32_16x16x32_bf16(a1, b1, acc[1][1], 0, 0, 0);
            acc[1][2] = __builtin_amdgcn_mfma_f32_16x16x32_bf16(a1, b2, acc[1][2], 0, 0, 0);
            acc[1][3] = __builtin_amdgcn_mfma_f32_16x16x32_bf16(a1, b3, acc[1][3], 0, 0, 0);
            acc[2][0] = __builtin_amdgcn_mfma_f32_16x16x32_bf16(a2, b0, acc[2][0], 0, 0, 0);
            acc[2][1] = __builtin_amdgcn_mfma_f32_16x16x32_bf16(a2, b1, acc[2][1], 0, 0, 0);
            acc[2][2] = __builtin_amdgcn_mfma_f32_16x16x32_bf16(a2, b2, acc[2][2], 0, 0, 0);
            acc[2][3] = __builtin_amdgcn_mfma_f32_16x16x32_bf16(a2, b3, acc[2][3], 0, 0, 0);
            acc[3][0] = __builtin_amdgcn_mfma_f32_16x16x32_bf16(a3, b0, acc[3][0], 0, 0, 0);
            acc[3][1] = __builtin_amdgcn_mfma_f32_16x16x32_bf16(a3, b1, acc[3][1], 0, 0, 0);
            acc[3][2] = __builtin_amdgcn_mfma_f32_16x16x32_bf16(a3, b2, acc[3][2], 0, 0, 0);
            acc[3][3] = __builtin_amdgcn_mfma_f32_16x16x32_bf16(a3, b3, acc[3][3], 0, 0, 0);
        }
    }

    float* outp = PART + (size_t)z * 128 * 512;
#pragma unroll
    for (int mi = 0; mi < 4; mi++) {
#pragma unroll
        for (int ni = 0; ni < 4; ni++) {
            f32x4 a = acc[mi][ni];
            int n = n0 + wc * 64 + ni * 16 + lr;
#pragma unroll
            for (int j = 0; j < 4; j++) {
                int m = wr * 64 + mi * 16 + lg * 4 + j;
                outp[(size_t)m * 512 + n] = a[j];
            }
        }
    }
}

__global__ void reduce_part(const float* __restrict__ PART, float* __restrict__ EMB, int Z)
{
    int idx = blockIdx.x * blockDim.x + threadIdx.x;   // 0..65535
    float s = 0.f;
    for (int z = 0; z < Z; z++) s += PART[(size_t)z * 65536 + idx];
    EMB[idx] = s;
}

// attn weights, transposed + bf16 + zero-pad: ATTWT[c][n], n in [0,Kp)
__global__ void att_w_t(const float* __restrict__ a2, const float* __restrict__ ms,
                        const float* __restrict__ ss, ushort* __restrict__ W,
                        int Nn, int Kp)
{
    int idx = blockIdx.x * blockDim.x + threadIdx.x;
    if (idx >= 128 * Kp) return;
    int c = idx / Kp, n = idx % Kp;
    float v = 0.f;
    if (n < Nn) v = expf(a2[(size_t)n * 128 + c] - ms[c]) / ss[c];
    W[idx] = f2bf(v);
}

// XB [Nn][512] bf16 -> XBT [512][Kp] bf16 (zero-pad n >= Nn), 64x64 LDS tiles
__global__ __launch_bounds__(256)
void t_xb(const ushort* __restrict__ XB, ushort* __restrict__ XBT, int Nn, int Kp)
{
    __shared__ ushort tile[64][72];
    const int n0 = blockIdx.x * 64;
    const int d0 = blockIdx.y * 64;
    const int tid = threadIdx.x;
#pragma unroll
    for (int i = 0; i < 2; i++) {
        int ch = i * 256 + tid;
        int r = ch >> 3, c8 = ch & 7;
        int n = n0 + r;
        ushort8v v = {0, 0, 0, 0, 0, 0, 0, 0};
        if (n < Nn) v = *(const ushort8v*)(XB + (size_t)n * 512 + d0 + c8 * 8);
        *(ushort8v*)&tile[r][c8 * 8] = v;
    }
    __syncthreads();
#pragma unroll
    for (int i = 0; i < 2; i++) {
        int ch = i * 256 + tid;
        int dr = ch >> 3, n8 = ch & 7;
        ushort8v v;
#pragma unroll
        for (int q = 0; q < 8; q++) v[q] = tile[n8 * 8 + q][dr];
        *(ushort8v*)(XBT + (size_t)(d0 + dr) * Kp + n0 + n8 * 8) = v;
    }
}

// ============ implicit-GEMM conv 3x3 stride2 pad1, NHWC bf16, IC=64 ========
template<int NI>
__global__ __launch_bounds__(256)
void conv_mfma(const ushort* __restrict__ in, const ushort* __restrict__ Wk,
               const float* __restrict__ bias, const float* __restrict__ gamma,
               const float* __restrict__ beta, ushort* __restrict__ outp,
               int IH, int IW, int OH, int OW)
{
    const int OC = NI * 16;
    __shared__ ushort As[128 * 64];
    __shared__ ushort Bs[NI * 16 * 64];

    const int tid  = threadIdx.x;
    const int lane = tid & 63;
    const int wv   = tid >> 6;
    const int lr   = lane & 15;
    const int lg   = lane >> 4;
    const int swz  = (lr & 7) << 4;
    const int m0   = blockIdx.x * 128;
    const int M    = OH * OW;

    f32x4 acc[2][NI];
#pragma unroll
    for (int i = 0; i < 2; i++)
#pragma unroll
        for (int j = 0; j < NI; j++) acc[i][j] = (f32x4){0.f, 0.f, 0.f, 0.f};

    for (int r = 0; r < 9; r++) {
        const int kh = r / 3, kw = r % 3;
        if (r) __syncthreads();
#pragma unroll
        for (int i = 0; i < 4; i++) {
            int ch = i * 256 + tid;
            int p = ch >> 3, c8 = ch & 7;
            int lb = p * 128 + ((c8 * 16) ^ ((p & 7) << 4));
            int gp = m0 + p; if (gp > M - 1) gp = M - 1;
            int oh = gp / OW, ow = gp % OW;
            int ih = oh * 2 - 1 + kh, iw = ow * 2 - 1 + kw;
            ushort8v v = {0, 0, 0, 0, 0, 0, 0, 0};
            if (ih >= 0 && ih < IH && iw >= 0 && iw < IW)
                v = *(const ushort8v*)(in + ((size_t)ih * IW + iw) * 64 + c8 * 8);
            *(ushort8v*)((char*)As + lb) = v;
        }
        for (int ch = tid; ch < OC * 8; ch += 256) {
            int oc = ch >> 3, c8 = ch & 7;
            int lb = oc * 128 + ((c8 * 16) ^ ((oc & 7) << 4));
            ushort8v v = *(const ushort8v*)(Wk + (size_t)oc * 576 + r * 64 + c8 * 8);
            *(ushort8v*)((char*)Bs + lb) = v;
        }
        __syncthreads();

        const char* Ab = (const char*)As + (wv * 32 + lr) * 128;
        const char* Bb = (const char*)Bs + lr * 128;
#pragma unroll
        for (int ks = 0; ks < 2; ks++) {
            int kx = (ks * 64 + lg * 16) ^ swz;
            bf16x8 a0 = *(const bf16x8*)(Ab + 0 * 2048 + kx);
            bf16x8 a1 = *(const bf16x8*)(Ab + 1 * 2048 + kx);
#pragma unroll
            for (int ni = 0; ni < NI; ni++) {
                bf16x8 bfr = *(const bf16x8*)(Bb + ni * 2048 + kx);
                acc[0][ni] = __builtin_amdgcn_mfma_f32_16x16x32_bf16(a0, bfr, acc[0][ni], 0, 0, 0);
                acc[1][ni] = __builtin_amdgcn_mfma_f32_16x16x32_bf16(a1, bfr, acc[1][ni], 0, 0, 0);
            }
        }
    }

#pragma unroll
    for (int mi = 0; mi < 2; mi++)
#pragma unroll
    for (int ni = 0; ni < NI; ni++) {
        f32x4 a = acc[mi][ni];
        int oc = ni * 16 + lr;
        float bv = bias[oc], gv = gamma[oc], btv = beta[oc];
#pragma unroll
        for (int j = 0; j < 4; j++) {
            int gp = m0 + wv * 32 + mi * 16 + lg * 4 + j;
            if (gp >= M) continue;
            float v = a[j] + bv;
            v = gv * v * BN_INV + btv;
            v = fmaxf(v, 0.f);
            outp[(size_t)gp * OC + oc] = f2bf(v);
        }
    }
}

// conv1: emb[128][512] f32 (1ch) -> e0[132][516][64] NHWC bf16, k3 s1 pad3, bn+relu
__global__ void conv1_nhwc(const float* __restrict__ emb, const float* __restrict__ w,
                           const float* __restrict__ b, const float* __restrict__ g,
                           const float* __restrict__ bb, ushort* __restrict__ outp)
{
    int oh = blockIdx.x;  // 0..131
    for (int idx = threadIdx.x; idx < 516 * 8; idx += 256) {
        int ow = idx >> 3, c8 = idx & 7;
        float pv[9];
#pragma unroll
        for (int kh = 0; kh < 3; kh++)
#pragma unroll
            for (int kw = 0; kw < 3; kw++) {
                int ih = oh - 3 + kh, iw = ow - 3 + kw;
                pv[kh * 3 + kw] = (ih >= 0 && ih < 128 && iw >= 0 && iw < 512)
                                  ? emb[ih * 512 + iw] : 0.f;
            }
        ushort8v o;
#pragma unroll
        for (int q = 0; q < 8; q++) {
            int oc = c8 * 8 + q;
            float v = b[oc];
#pragma unroll
            for (int i = 0; i < 9; i++) v = fmaf(pv[i], w[oc * 9 + i], v);
            v = g[oc] * v * BN_INV + bb[oc];
            v = fmaxf(v, 0.f);
            o[q] = f2bf(v);
        }
        *(ushort8v*)(outp + ((size_t)oh * 516 + ow) * 64 + c8 * 8) = o;
    }
}

// 3x3 maxpool s1 p1, NHWC bf16 (valid cells only)
__global__ void maxpool_nhwc(const ushort* __restrict__ in, ushort* __restrict__ out,
                             int H, int W, int C8)
{
    int h = blockIdx.x;
    int tot = W * C8;
    for (int idx = threadIdx.x; idx < tot; idx += blockDim.x) {
        int w0 = idx / C8, cg = idx % C8;
        float mx[8];
#pragma unroll
        for (int q = 0; q < 8; q++) mx[q] = -1e30f;
        for (int dh = -1; dh <= 1; dh++) {
            int hh = h + dh; if (hh < 0 || hh >= H) continue;
            for (int dw = -1; dw <= 1; dw++) {
                int ww = w0 + dw; if (ww < 0 || ww >= W) continue;
                ushort8v v = *(const ushort8v*)(in + ((size_t)hh * W + ww) * C8 * 8 + cg * 8);
#pragma unroll
                for (int q = 0; q < 8; q++) mx[q] = fmaxf(mx[q], bf2f(v[q]));
            }
        }
        ushort8v o;
#pragma unroll
        for (int q = 0; q < 8; q++) o[q] = f2bf(mx[q]);
        *(ushort8v*)(out + ((size_t)h * W + w0) * C8 * 8 + cg * 8) = o;
    }
}

// ==== fused conv2 + head (both single-block): [5][17][64] -> out[14] =======
__global__ __launch_bounds__(256)
void conv2_head(const ushort* __restrict__ in, const ushort* __restrict__ WC2,
                const float* __restrict__ c2b, const float* __restrict__ c2g,
                const float* __restrict__ c2bb,
                const float* __restrict__ fc1w, const float* __restrict__ fc1b,
                const float* __restrict__ fc2w, const float* __restrict__ fc2b,
                ushort* __restrict__ Q16, float* __restrict__ outp,
                int IH, int IW)
{
    __shared__ ushort As[128 * 64];
    __shared__ ushort Bs[16 * 64];
    __shared__ float flat[432];
    __shared__ float t1[1024];

    const int tid  = threadIdx.x;
    const int lane = tid & 63;
    const int wv   = tid >> 6;
    const int lr   = lane & 15;
    const int lg   = lane >> 4;
    const int swz  = (lr & 7) << 4;
    const int OH = 3, OW = 9, M = 27;

    f32x4 acc[2];
    acc[0] = (f32x4){0.f, 0.f, 0.f, 0.f};
    acc[1] = (f32x4){0.f, 0.f, 0.f, 0.f};

    for (int r = 0; r < 9; r++) {
        const int kh = r / 3, kw = r % 3;
        if (r) __syncthreads();
#pragma unroll
        for (int i = 0; i < 4; i++) {
            int ch = i * 256 + tid;
            int p = ch >> 3, c8 = ch & 7;
            int lb = p * 128 + ((c8 * 16) ^ ((p & 7) << 4));
            int gp = p; if (gp > M - 1) gp = M - 1;
            int oh = gp / OW, ow = gp % OW;
            int ih = oh * 2 - 1 + kh, iw = ow * 2 - 1 + kw;
            ushort8v v = {0, 0, 0, 0, 0, 0, 0, 0};
            if (ih >= 0 && ih < IH && iw >= 0 && iw < IW)
                v = *(const ushort8v*)(in + ((size_t)ih * IW + iw) * 64 + c8 * 8);
            *(ushort8v*)((char*)As + lb) = v;
        }
        for (int ch = tid; ch < 16 * 8; ch += 256) {
            int oc = ch >> 3, c8 = ch & 7;
            int lb = oc * 128 + ((c8 * 16) ^ ((oc & 7) << 4));
            ushort8v v = *(const ushort8v*)(WC2 + (size_t)oc * 576 + r * 64 + c8 * 8);
            *(ushort8v*)((char*)Bs + lb) = v;
        }
        __syncthreads();

        const char* Ab = (const char*)As + (wv * 32 + lr) * 128;
        const char* Bb = (const char*)Bs + lr * 128;
#pragma unroll
        for (int ks = 0; ks < 2; ks++) {
            int kx = (ks * 64 + lg * 16) ^ swz;
            bf16x8 a0 = *(const bf16x8*)(Ab + 0 * 2048 + kx);
            bf16x8 a1 = *(const bf16x8*)(Ab + 1 * 2048 + kx);
            bf16x8 bfr = *(const bf16x8*)(Bb + kx);
            acc[0] = __builtin_amdgcn_mfma_f32_16x16x32_bf16(a0, bfr, acc[0], 0, 0, 0);
            acc[1] = __builtin_amdgcn_mfma_f32_16x16x32_bf16(a1, bfr, acc[1], 0, 0, 0);
        }
    }

#pragma unroll
    for (int mi = 0; mi < 2; mi++) {
        f32x4 a = acc[mi];
        int oc = lr;
        float bv = c2b[oc], gv = c2g[oc], btv = c2bb[oc];
#pragma unroll
        for (int j = 0; j < 4; j++) {
            int gp = wv * 32 + mi * 16 + lg * 4 + j;
            if (gp >= M) continue;
            float v = a[j] + bv;
            v = gv * v * BN_INV + btv;
            v = fmaxf(v, 0.f);
            Q16[(size_t)gp * 16 + oc] = f2bf(v);
        }
    }
    __syncthreads();

    // head: maxpool [3][9][16] -> fc1 -> fc2 -> sigmoid
    for (int i = tid; i < 432; i += 256) {
        int c = i / 27, r = i % 27;
        int h = r / 9, w0 = r % 9;
        float m = -1e30f;
        for (int dh = -1; dh <= 1; dh++) {
            int hh = h + dh; if (hh < 0 || hh >= 3) continue;
            for (int dw = -1; dw <= 1; dw++) {
                int ww = w0 + dw; if (ww < 0 || ww >= 9) continue;
                m = fmaxf(m, bf2f(Q16[((size_t)hh * 9 + ww) * 16 + c]));
            }
        }
        flat[i] = m;
    }
    __syncthreads();
    for (int o = tid; o < 1024; o += 256) {
        float s = fc1b[o];
        const float* wr = fc1w + (size_t)o * 432;
        for (int k = 0; k < 432; k++) s = fmaf(flat[k], wr[k], s);
        t1[o] = s;
    }
    __syncthreads();
    int l = tid & 63;
    for (int o = wv; o < 14; o += 4) {
        float s = 0.f;
        const float* wr = fc2w + (size_t)o * 1024;
        for (int k = l; k < 1024; k += 64) s = fmaf(t1[k], wr[k], s);
        for (int sh = 32; sh > 0; sh >>= 1) s += __shfl_down(s, sh, 64);
        if (l == 0) outp[o] = 1.f / (1.f + expf(-(s + fc2b[o])));
    }
}

// ---------------- fused weight prep (cvt + conv reorder) --------------------
__global__ void prep_all(const float* w1l, const float* w1r, const float* w2l,
                         const float* w2r, const float* fa1, const float* fa2,
                         const float* c1w, const float* c2w,
                         ushort* W1L, ushort* W1R, ushort* W2L, ushort* W2R,
                         ushort* FA1, ushort* FA2, ushort* WC1, ushort* WC2)
{
    int i = blockIdx.x * blockDim.x + threadIdx.x;
    if (i < 796672) {
        const float* s; ushort* d; int j;
        if      (i < 327680)  { s = w1l; d = W1L; j = i; }
        else if (i < 655360)  { s = w1r; d = W1R; j = i - 327680; }
        else if (i < 720896)  { s = w2l; d = W2L; j = i - 655360; }
        else if (i < 786432)  { s = w2r; d = W2R; j = i - 720896; }
        else if (i < 794624)  { s = fa1; d = FA1; j = i - 786432; }
        else                  { s = fa2; d = FA2; j = i - 794624; }
        const float4 f0 = *(const float4*)(s + (size_t)j * 8);
        const float4 f1 = *(const float4*)(s + (size_t)j * 8 + 4);
        ushort8v v;
        v[0] = f2bf(f0.x); v[1] = f2bf(f0.y); v[2] = f2bf(f0.z); v[3] = f2bf(f0.w);
        v[4] = f2bf(f1.x); v[5] = f2bf(f1.y); v[6] = f2bf(f1.z); v[7] = f2bf(f1.w);
        *(ushort8v*)(d + (size_t)j * 8) = v;
    } else {
        int k = i - 796672;
        if (k >= 80 * 576) return;
        const float* w; ushort* wk; int idx;
        if (k < 64 * 576) { w = c1w; wk = WC1; idx = k; }
        else              { w = c2w; wk = WC2; idx = k - 64 * 576; }
        int oc = idx / 576, t = idx % 576;
        int r = t / 64, ic = t % 64;
        int kh = r / 3, kw = r % 3;
        wk[idx] = f2bf(w[((oc * 64 + ic) * 3 + kh) * 3 + kw]);
    }
}

// ---------------- parallel CSR build (4 dispatches) -------------------------
__global__ void hist_k(const int* __restrict__ dst, int* __restrict__ hist, int E)
{
    int e = blockIdx.x * blockDim.x + threadIdx.x;
    if (e < E) atomicAdd(&hist[dst[e]], 1);
}

// parallel scan: PT elems/thread serial + one 1024-wide block scan
__global__ __launch_bounds__(1024)
void scan_k(const int* __restrict__ hist, int* __restrict__ off, int n)
{
    __shared__ int tmp[1024];
    const int PT = (n + 1023) / 1024;
    int t = threadIdx.x;
    int b = t * PT;
    int ls = 0;
    for (int k = 0; k < PT; k++) { int i = b + k; if (i < n) ls += hist[i]; }
    tmp[t] = ls;
    __syncthreads();
    for (int s = 1; s < 1024; s <<= 1) {
        int v = (t >= s) ? tmp[t - s] : 0;
        __syncthreads();
        tmp[t] += v;
        __syncthreads();
    }
    int run = tmp[t] - ls;
    for (int k = 0; k < PT; k++) {
        int i = b + k;
        if (i < n) { off[i] = run; run += hist[i]; }
    }
    if (t == 1023) off[n] = tmp[1023];
}

__global__ void fill_k(const int* __restrict__ src, const int* __restrict__ dst,
                       const int* __restrict__ off, int* __restrict__ cursor,
                       int* __restrict__ eidx, int E)
{
    int e = blockIdx.x * blockDim.x + threadIdx.x;
    if (e >= E) return;
    int d = dst[e];
    int pos = atomicAdd(&cursor[d], 1);
    eidx[off[d] + pos] = src[e];
}

// ---------------- f32 -> bf16 convert (x -> XBF) ----------------------------
__global__ void cvt_k(const float* __restrict__ in, ushort* __restrict__ out, int n8)
{
    int i = blockIdx.x * blockDim.x + threadIdx.x;
    if (i >= n8) return;
    const float4 f0 = *(const float4*)(in + (size_t)i * 8);
    const float4 f1 = *(const float4*)(in + (size_t)i * 8 + 4);
    ushort8v v;
    v[0] = f2bf(f0.x); v[1] = f2bf(f0.y); v[2] = f2bf(f0.z); v[3] = f2bf(f0.w);
    v[4] = f2bf(f1.x); v[5] = f2bf(f1.y); v[6] = f2bf(f1.z); v[7] = f2bf(f1.w);
    *(ushort8v*)(out + (size_t)i * 8) = v;
}

// ---------------- attention softmax over nodes ------------------------------
__global__ __launch_bounds__(256)
void softmax_stats(const float* __restrict__ a2, float* __restrict__ ms,
                   float* __restrict__ ss, int Nn)
{
    int c = blockIdx.x;
    __shared__ float red[256];
    float mx = -1e30f;
    for (int n = threadIdx.x; n < Nn; n += 256)
        mx = fmaxf(mx, a2[(size_t)n * 128 + c]);
    red[threadIdx.x] = mx;
    __syncthreads();
    for (int s = 128; s > 0; s >>= 1) {
        if (threadIdx.x < s) red[threadIdx.x] = fmaxf(red[threadIdx.x], red[threadIdx.x + s]);
        __syncthreads();
    }
    mx = red[0];
    __syncthreads();
    float sum = 0.f;
    for (int n = threadIdx.x; n < Nn; n += 256)
        sum += expf(a2[(size_t)n * 128 + c] - mx);
    red[threadIdx.x] = sum;
    __syncthreads();
    for (int s = 128; s > 0; s >>= 1) {
        if (threadIdx.x < s) red[threadIdx.x] += red[threadIdx.x + s];
        __syncthreads();
    }
    if (threadIdx.x == 0) { ms[c] = mx; ss[c] = red[0]; }
}

// ---------------------------------------------------------------------------
extern "C" void kernel_launch(void* const* d_in, const int* in_sizes, int n_in,
                              void* d_out, int out_size, void* d_ws, size_t ws_size,
                              hipStream_t stream)
{
    const float* x     = (const float*)d_in[0];
    const int*   ei    = (const int*)d_in[1];
    const float* w1l   = (const float*)d_in[2];
    const float* b1    = (const float*)d_in[3];
    const float* w1r   = (const float*)d_in[4];
    const float* bn1g  = (const float*)d_in[5];
    const float* bn1b  = (const float*)d_in[6];
    const float* w2l   = (const float*)d_in[7];
    const float* b2    = (const float*)d_in[8];
    const float* w2r   = (const float*)d_in[9];
    const float* fa1w  = (const float*)d_in[10];
    const float* fa1b  = (const float*)d_in[11];
    const float* fa2w  = (const float*)d_in[12];
    const float* fa2b  = (const float*)d_in[13];
    const float* cnn1w = (const float*)d_in[14];
    const float* cnn1b = (const float*)d_in[15];
    const float* normg = (const float*)d_in[16];
    const float* normb = (const float*)d_in[17];
    const float* c1w   = (const float*)d_in[18];
    const float* c1b   = (const float*)d_in[19];
    const float* c1g   = (const float*)d_in[20];
    const float* c1bb  = (const float*)d_in[21];
    const float* c2w   = (const float*)d_in[22];
    const float* c2b   = (const float*)d_in[23];
    const float* c2g   = (const float*)d_in[24];
    const float* c2bb  = (const float*)d_in[25];
    const float* fc1w  = (const float*)d_in[26];
    const float* fc1b  = (const float*)d_in[27];
    const float* fc2w  = (const float*)d_in[28];
    const float* fc2b  = (const float*)d_in[29];
    float* out = (float*)d_out;

    const int Nn = 10000, E = 160000;
    const int Kp = 10048;   // 157*64
    char* ws = (char*)d_ws;

    // ---- workspace layout (bytes) — phase-checked, no live overlaps ----
    ushort* YL    = (ushort*)(ws + 0);           // 20,480,000
    ushort* ATTWT = (ushort*)(ws + 0);           // 2,572,288 (YL dead after gather_h1)
    ushort* XBT   = (ushort*)(ws + 2572288);     // -> 12,861,440
    ushort* P16   = (ushort*)(ws + 0);           // 8,718,336
    ushort* Q16   = (ushort*)(ws + 13000000);    // -> 15,179,584
    ushort* H1   = (ushort*)(ws + 20480000);     // 20,480,000
    ushort* XB   = (ushort*)(ws + 20480000);     // 10,240,000
    float*  A2   = (float*)(ws + 33280000);      // 5,120,000 -> 38,400,000
    ushort* YR   = (ushort*)(ws + 40960000);     // 20,480,000
    ushort* ZL   = (ushort*)(ws + 40960000);     // 10,240,000
    ushort* ZR   = (ushort*)(ws + 51200000);     // -> 61,440,000
    float*  PART = (float*)(ws + 40960000);      // 10,485,760 (ZL/ZR dead by splitk)
    int*   hist   = (int*)(ws + 61440000);       // 40,000
    int*   cursor = (int*)(ws + 61480000);       // 40,000
    int*   off    = (int*)(ws + 61520000);       // 40,004
    int*   eidx   = (int*)(ws + 61560128);       // 640,000 -> 62,200,128
    float*  MS   = (float*)(ws + 67360128);
    float*  SS   = (float*)(ws + 67360640);
    float*  EMB  = (float*)(ws + 67361152);      // -> 67,623,296
    ushort* W1L = (ushort*)(ws + 67623296);      // W1L+W1R contiguous = [2048][2560]
    ushort* W1R = (ushort*)(ws + 72866176);
    ushort* W2L = (ushort*)(ws + 78109056);      // W2L+W2R contiguous = [1024][1024]
    ushort* W2R = (ushort*)(ws + 79157632);
    ushort* FA1 = (ushort*)(ws + 80206208);
    ushort* FA2 = (ushort*)(ws + 80337280);
    ushort* WC1 = (ushort*)(ws + 80370048);
    ushort* WC2 = (ushort*)(ws + 80443776);      // -> 80,462,208
    ushort* XBF = (ushort*)(ws + 80462208);      // 51,200,000 -> 131,662,208
    const bool use_xbf = (ws_size >= (size_t)131662208);

    const int* src = ei;
    const int* dst = ei + E;

    // ---- weight prep (1) + parallel CSR build (4) ----
    prep_all<<<(796672 + 80 * 576 + 255) / 256, 256, 0, stream>>>(
        w1l, w1r, w2l, w2r, fa1w, fa2w, c1w, c2w,
        W1L, W1R, W2L, W2R, FA1, FA2, WC1, WC2);
    hipMemsetAsync(hist, 0, 80000, stream);   // hist + cursor (adjacent)
    hist_k<<<(E + 255) / 256, 256, 0, stream>>>(dst, hist, E);
    scan_k<<<1, 1024, 0, stream>>>(hist, off, Nn);
    fill_k<<<(E + 255) / 256, 256, 0, stream>>>(src, dst, off, cursor, eidx, E);

    const int GY = (Nn + 127) / 128;   // 79

    // ---- SAGE layer 1: fused [YL | YR] = x @ [W1L;W1R]^T (N=2048) ----
    if (use_xbf) {
        cvt_k<<<(3200000 + 255) / 256, 256, 0, stream>>>(x, XBF, 3200000);
        mgemm<0, 5, ushort><<<dim3(2048 / 128, GY), 256, 0, stream>>>(
            XBF, W1L, YL, Nn, 2048, 2560, nullptr, YR);
    } else {
        mgemm<1, 5, ushort><<<dim3(2048 / 128, GY), 256, 0, stream>>>(
            x, W1L, YL, Nn, 2048, 2560, nullptr, YR);
    }
    gather_h1<<<Nn, 128, 0, stream>>>(YL, eidx, off, YR, b1, bn1g, bn1b, H1);

    // ---- SAGE layer 2: fused [ZL | ZR] = h1 @ [W2L;W2R]^T (N=1024) ----
    mgemm<0, 5, ushort><<<dim3(1024 / 128, GY), 256, 0, stream>>>(
        H1, W2L, ZL, Nn, 1024, 1024, nullptr, ZR);
    gather_xb<<<Nn, 64, 0, stream>>>(ZL, eidx, off, ZR, b2, XB);

    // ---- attention (fused MLP) ----
    attn_a1a2<<<GY, 256, 0, stream>>>(XB, FA1, fa1b, FA2, fa2b, A2, Nn);
    softmax_stats<<<128, 256, 0, stream>>>(A2, MS, SS, Nn);
    att_w_t<<<(128 * Kp + 255) / 256, 256, 0, stream>>>(A2, MS, SS, ATTWT, Nn, Kp);
    t_xb<<<dim3(Kp / 64, 8), 256, 0, stream>>>(XB, XBT, Nn, Kp);
    mgemm_splitk<<<dim3(4, 1, 40), 256, 0, stream>>>(ATTWT, XBT, PART, 512, Kp, 157, 4);
    reduce_part<<<256, 256, 0, stream>>>(PART, EMB, 40);

    // ---- CNN (separate kernels) ----
    conv1_nhwc<<<132, 256, 0, stream>>>(EMB, cnn1w, cnn1b, normg, normb, P16);
    int H = 132, W = 516;
    for (int it = 0; it < 5; it++) {
        int OH = (H - 1) / 2 + 1, OW = (W - 1) / 2 + 1;
        int M = OH * OW;
        conv_mfma<4><<<(M + 127) / 128, 256, 0, stream>>>(
            P16, WC1, c1b, c1g, c1bb, Q16, H, W, OH, OW);
        maxpool_nhwc<<<OH, 256, 0, stream>>>(Q16, P16, OH, OW, 8);
        H = OH; W = OW;
    }
    // conv2 + head fused (both single-block)
    conv2_head<<<1, 256, 0, stream>>>(P16, WC2, c2b, c2g, c2bb,
                                      fc1w, fc1b, fc2w, fc2b, Q16, out, H, W);
}

// Round 13
// 565.425 us; speedup vs baseline: 1.8321x; 1.1710x over previous
//
#include <hip/hip_runtime.h>
#include <cstdint>
#include <cstddef>

typedef unsigned short ushort;
typedef __attribute__((ext_vector_type(8))) short bf16x8;
typedef __attribute__((ext_vector_type(8))) unsigned short ushort8v;
typedef __attribute__((ext_vector_type(4))) float f32x4;

// 1/sqrt(1+1e-5)
#define BN_INV 0.9999950000374997f

__device__ inline ushort f2bf(float f) {
    union { float f; unsigned u; } x; x.f = f;
    unsigned r = x.u + 0x7fffu + ((x.u >> 16) & 1u);
    return (ushort)(r >> 16);
}
__device__ inline float bf2f(ushort u) {
    union { unsigned u; float f; } x; x.u = ((unsigned)u) << 16;
    return x.f;
}

// async global->LDS, 16B per lane. LDS dest is wave-uniform base + lane*16.
__device__ __forceinline__ void gload16(const void* g, void* l) {
    __builtin_amdgcn_global_load_lds(
        (const __attribute__((address_space(1))) unsigned int*)g,
        (__attribute__((address_space(3))) unsigned int*)l, 16, 0, 0);
}

// ======================= MFMA bf16 GEMM ====================================
// C[M,N] = A[M,K] @ B[N,K]^T.  B always bf16.
// AMODE 0: A bf16 via global_load_lds w/ pre-swizzled source.
// AMODE 1: A f32 (reg-converted), reg-staged swizzled LDS writes.
// XCD-chunked bijective swizzle, N-INNER (A panels L2-resident, B via L3).
// EPIL 5: split-write at N/2: n<N/2 -> C, else -> C2 (row stride N/2)
template<int AMODE, int EPIL, typename OutT>
__global__ __launch_bounds__(256)
void mgemm(const void* __restrict__ Asrc, const ushort* __restrict__ Bsrc,
           OutT* __restrict__ C, int M, int N, int K,
           const float* __restrict__ bias, ushort* __restrict__ C2)
{
    __shared__ ushort As[128 * 64];
    __shared__ ushort Bs[128 * 64];

    const int tid  = threadIdx.x;
    const int lane = tid & 63;
    const int wid  = tid >> 6;
    const int wr   = wid >> 1;
    const int wc   = wid & 1;

    const int nwg  = gridDim.x * gridDim.y;
    const int orig = blockIdx.y * gridDim.x + blockIdx.x;
    const int q    = nwg >> 3, r = nwg & 7;
    const int xcd  = orig & 7, ii = orig >> 3;
    const int wg   = (xcd < r ? xcd * (q + 1) : r * (q + 1) + (xcd - r) * q) + ii;
    const int m0   = (wg / gridDim.x) * 128;
    const int n0   = (wg % gridDim.x) * 128;

    const int lr  = lane & 15;
    const int lg  = lane >> 4;
    const int swz = (lr & 7) << 4;

    f32x4 acc[4][4];
#pragma unroll
    for (int i = 0; i < 4; i++)
#pragma unroll
        for (int j = 0; j < 4; j++) acc[i][j] = (f32x4){0.f, 0.f, 0.f, 0.f};

    for (int k0 = 0; k0 < K; k0 += 64) {
        if (k0) __syncthreads();
        if constexpr (AMODE == 0) {
#pragma unroll
            for (int i = 0; i < 4; i++) {
                int ch = i * 256 + tid;
                int rr = ch >> 3, c8 = ch & 7;
                int c8p = c8 ^ (rr & 7);
                int srow = m0 + rr; if (srow > M - 1) srow = M - 1;
                gload16((const ushort*)Asrc + (size_t)srow * K + k0 + c8p * 8,
                        (char*)As + (i * 256 + wid * 64) * 16);
                gload16(Bsrc + (size_t)(n0 + rr) * K + k0 + c8p * 8,
                        (char*)Bs + (i * 256 + wid * 64) * 16);
            }
        } else {
#pragma unroll
            for (int i = 0; i < 4; i++) {
                int ch = i * 256 + tid;
                int rr = ch >> 3, c8 = ch & 7;
                int lb = rr * 128 + ((c8 * 16) ^ ((rr & 7) << 4));
                int srow = m0 + rr; if (srow > M - 1) srow = M - 1;
                const float* ap = (const float*)Asrc + (size_t)srow * K + k0 + c8 * 8;
                float4 f0 = *(const float4*)ap;
                float4 f1 = *(const float4*)(ap + 4);
                ushort8v va;
                va[0] = f2bf(f0.x); va[1] = f2bf(f0.y); va[2] = f2bf(f0.z); va[3] = f2bf(f0.w);
                va[4] = f2bf(f1.x); va[5] = f2bf(f1.y); va[6] = f2bf(f1.z); va[7] = f2bf(f1.w);
                *(ushort8v*)((char*)As + lb) = va;
                ushort8v vb = *(const ushort8v*)(Bsrc + (size_t)(n0 + rr) * K + k0 + c8 * 8);
                *(ushort8v*)((char*)Bs + lb) = vb;
            }
        }
        __syncthreads();

        const char* Ab = (const char*)As + (wr * 64 + lr) * 128;
        const char* Bb = (const char*)Bs + (wc * 64 + lr) * 128;
#pragma unroll
        for (int ks = 0; ks < 2; ks++) {
            int kx = (ks * 64 + lg * 16) ^ swz;
            bf16x8 a0 = *(const bf16x8*)(Ab + 0 * 2048 + kx);
            bf16x8 a1 = *(const bf16x8*)(Ab + 1 * 2048 + kx);
            bf16x8 a2 = *(const bf16x8*)(Ab + 2 * 2048 + kx);
            bf16x8 a3 = *(const bf16x8*)(Ab + 3 * 2048 + kx);
            bf16x8 b0 = *(const bf16x8*)(Bb + 0 * 2048 + kx);
            bf16x8 b1 = *(const bf16x8*)(Bb + 1 * 2048 + kx);
            bf16x8 b2 = *(const bf16x8*)(Bb + 2 * 2048 + kx);
            bf16x8 b3 = *(const bf16x8*)(Bb + 3 * 2048 + kx);
            acc[0][0] = __builtin_amdgcn_mfma_f32_16x16x32_bf16(a0, b0, acc[0][0], 0, 0, 0);
            acc[0][1] = __builtin_amdgcn_mfma_f32_16x16x32_bf16(a0, b1, acc[0][1], 0, 0, 0);
            acc[0][2] = __builtin_amdgcn_mfma_f32_16x16x32_bf16(a0, b2, acc[0][2], 0, 0, 0);
            acc[0][3] = __builtin_amdgcn_mfma_f32_16x16x32_bf16(a0, b3, acc[0][3], 0, 0, 0);
            acc[1][0] = __builtin_amdgcn_mfma_f32_16x16x32_bf16(a1, b0, acc[1][0], 0, 0, 0);
            acc[1][1] = __builtin_amdgcn_mfma_f32_16x16x32_bf16(a1, b1, acc[1][1], 0, 0, 0);
            acc[1][2] = __builtin_amdgcn_mfma_f32_16x16x32_bf16(a1, b2, acc[1][2], 0, 0, 0);
            acc[1][3] = __builtin_amdgcn_mfma_f32_16x16x32_bf16(a1, b3, acc[1][3], 0, 0, 0);
            acc[2][0] = __builtin_amdgcn_mfma_f32_16x16x32_bf16(a2, b0, acc[2][0], 0, 0, 0);
            acc[2][1] = __builtin_amdgcn_mfma_f32_16x16x32_bf16(a2, b1, acc[2][1], 0, 0, 0);
            acc[2][2] = __builtin_amdgcn_mfma_f32_16x16x32_bf16(a2, b2, acc[2][2], 0, 0, 0);
            acc[2][3] = __builtin_amdgcn_mfma_f32_16x16x32_bf16(a2, b3, acc[2][3], 0, 0, 0);
            acc[3][0] = __builtin_amdgcn_mfma_f32_16x16x32_bf16(a3, b0, acc[3][0], 0, 0, 0);
            acc[3][1] = __builtin_amdgcn_mfma_f32_16x16x32_bf16(a3, b1, acc[3][1], 0, 0, 0);
            acc[3][2] = __builtin_amdgcn_mfma_f32_16x16x32_bf16(a3, b2, acc[3][2], 0, 0, 0);
            acc[3][3] = __builtin_amdgcn_mfma_f32_16x16x32_bf16(a3, b3, acc[3][3], 0, 0, 0);
        }
    }

#pragma unroll
    for (int mi = 0; mi < 4; mi++) {
#pragma unroll
        for (int ni = 0; ni < 4; ni++) {
            f32x4 a = acc[mi][ni];
            int n = n0 + wc * 64 + ni * 16 + lr;
#pragma unroll
            for (int j = 0; j < 4; j++) {
                int m = m0 + wr * 64 + mi * 16 + lg * 4 + j;
                if (m >= M) continue;
                float v = a[j];
                if (EPIL == 5) {
                    int half = N >> 1;
                    ushort* dst = (n < half) ? (ushort*)C : C2;
                    dst[(size_t)m * half + (n & (half - 1))] = f2bf(v);
                } else {
                    if (sizeof(OutT) == 2) ((ushort*)C)[(size_t)m * N + n] = f2bf(v);
                    else                   ((float*)C)[(size_t)m * N + n] = v;
                }
            }
        }
    }
}

// ==== fused gather + SAGE-1 epilogue: H1 = bn(relu(mean_j YL_j + b1 + YR)) ==
__global__ void gather_h1(const ushort* __restrict__ YL, const int* __restrict__ eidx,
                          const int* __restrict__ off, const ushort* __restrict__ YR,
                          const float* __restrict__ b1, const float* __restrict__ g,
                          const float* __restrict__ bb, ushort* __restrict__ H1)
{
    int n = blockIdx.x;
    int beg = off[n], end = off[n + 1];
    float inv = 1.f / fmaxf((float)(end - beg), 1.f);
    float s0 = 0, s1 = 0, s2 = 0, s3 = 0, s4 = 0, s5 = 0, s6 = 0, s7 = 0;
    for (int e = beg; e < end; e++) {
        ushort8v v = *(const ushort8v*)(YL + (size_t)eidx[e] * 1024 + threadIdx.x * 8);
        s0 += bf2f(v[0]); s1 += bf2f(v[1]); s2 += bf2f(v[2]); s3 += bf2f(v[3]);
        s4 += bf2f(v[4]); s5 += bf2f(v[5]); s6 += bf2f(v[6]); s7 += bf2f(v[7]);
    }
    float sv[8] = {s0, s1, s2, s3, s4, s5, s6, s7};
    ushort8v yr = *(const ushort8v*)(YR + (size_t)n * 1024 + threadIdx.x * 8);
    ushort8v o;
#pragma unroll
    for (int qq = 0; qq < 8; qq++) {
        int c = threadIdx.x * 8 + qq;
        float v = sv[qq] * inv + b1[c] + bf2f(yr[qq]);
        v = fmaxf(v, 0.f);
        v = g[c] * v * BN_INV + bb[c];
        o[qq] = f2bf(v);
    }
    *(ushort8v*)(H1 + (size_t)n * 1024 + threadIdx.x * 8) = o;
}

// ==== fused gather + SAGE-2 epilogue: XB = mean_j ZL_j + b2 + ZR ===========
__global__ void gather_xb(const ushort* __restrict__ ZL, const int* __restrict__ eidx,
                          const int* __restrict__ off, const ushort* __restrict__ ZR,
                          const float* __restrict__ b2, ushort* __restrict__ XB)
{
    int n = blockIdx.x;
    int beg = off[n], end = off[n + 1];
    float inv = 1.f / fmaxf((float)(end - beg), 1.f);
    float s0 = 0, s1 = 0, s2 = 0, s3 = 0, s4 = 0, s5 = 0, s6 = 0, s7 = 0;
    for (int e = beg; e < end; e++) {
        ushort8v v = *(const ushort8v*)(ZL + (size_t)eidx[e] * 512 + threadIdx.x * 8);
        s0 += bf2f(v[0]); s1 += bf2f(v[1]); s2 += bf2f(v[2]); s3 += bf2f(v[3]);
        s4 += bf2f(v[4]); s5 += bf2f(v[5]); s6 += bf2f(v[6]); s7 += bf2f(v[7]);
    }
    float sv[8] = {s0, s1, s2, s3, s4, s5, s6, s7};
    ushort8v zr = *(const ushort8v*)(ZR + (size_t)n * 512 + threadIdx.x * 8);
    ushort8v o;
#pragma unroll
    for (int qq = 0; qq < 8; qq++) {
        int c = threadIdx.x * 8 + qq;
        o[qq] = f2bf(sv[qq] * inv + b2[c] + bf2f(zr[qq]));
    }
    *(ushort8v*)(XB + (size_t)n * 512 + threadIdx.x * 8) = o;
}

// ==== fused attention MLP: A2 = tanh(XB@FA1^T + b1f)@FA2^T + b2f ===========
__global__ __launch_bounds__(256)
void attn_a1a2(const ushort* __restrict__ XB, const ushort* __restrict__ FA1,
               const float* __restrict__ fa1b, const ushort* __restrict__ FA2,
               const float* __restrict__ fa2b, float* __restrict__ A2, int M)
{
    __shared__ ushort As[128 * 64];
    __shared__ ushort Bs[128 * 64];
    __shared__ ushort A1a[128 * 64];
    __shared__ ushort A1b[128 * 64];

    const int tid  = threadIdx.x;
    const int lane = tid & 63;
    const int wid  = tid >> 6;
    const int wr   = wid >> 1;
    const int wc   = wid & 1;
    const int m0   = blockIdx.x * 128;
    const int lr   = lane & 15;
    const int lg   = lane >> 4;
    const int swz  = (lr & 7) << 4;

    f32x4 acc[4][4];
#pragma unroll
    for (int i = 0; i < 4; i++)
#pragma unroll
        for (int j = 0; j < 4; j++) acc[i][j] = (f32x4){0.f, 0.f, 0.f, 0.f};

    for (int k0 = 0; k0 < 512; k0 += 64) {
        if (k0) __syncthreads();
#pragma unroll
        for (int i = 0; i < 4; i++) {
            int ch = i * 256 + tid;
            int rr = ch >> 3, c8 = ch & 7;
            int c8p = c8 ^ (rr & 7);
            int srow = m0 + rr; if (srow > M - 1) srow = M - 1;
            gload16(XB + (size_t)srow * 512 + k0 + c8p * 8,
                    (char*)As + (i * 256 + wid * 64) * 16);
            gload16(FA1 + (size_t)rr * 512 + k0 + c8p * 8,
                    (char*)Bs + (i * 256 + wid * 64) * 16);
        }
        __syncthreads();
        const char* Ab = (const char*)As + (wr * 64 + lr) * 128;
        const char* Bb = (const char*)Bs + (wc * 64 + lr) * 128;
#pragma unroll
        for (int ks = 0; ks < 2; ks++) {
            int kx = (ks * 64 + lg * 16) ^ swz;
            bf16x8 a0 = *(const bf16x8*)(Ab + 0 * 2048 + kx);
            bf16x8 a1 = *(const bf16x8*)(Ab + 1 * 2048 + kx);
            bf16x8 a2 = *(const bf16x8*)(Ab + 2 * 2048 + kx);
            bf16x8 a3 = *(const bf16x8*)(Ab + 3 * 2048 + kx);
            bf16x8 b0 = *(const bf16x8*)(Bb + 0 * 2048 + kx);
            bf16x8 b1 = *(const bf16x8*)(Bb + 1 * 2048 + kx);
            bf16x8 b2 = *(const bf16x8*)(Bb + 2 * 2048 + kx);
            bf16x8 b3 = *(const bf16x8*)(Bb + 3 * 2048 + kx);
            acc[0][0] = __builtin_amdgcn_mfma_f32_16x16x32_bf16(a0, b0, acc[0][0], 0, 0, 0);
            acc[0][1] = __builtin_amdgcn_mfma_f32_16x16x32_bf16(a0, b1, acc[0][1], 0, 0, 0);
            acc[0][2] = __builtin_amdgcn_mfma_f32_16x16x32_bf16(a0, b2, acc[0][2], 0, 0, 0);
            acc[0][3] = __builtin_amdgcn_mfma_f32_16x16x32_bf16(a0, b3, acc[0][3], 0, 0, 0);
            acc[1][0] = __builtin_amdgcn_mfma_f32_16x16x32_bf16(a1, b0, acc[1][0], 0, 0, 0);
            acc[1][1] = __builtin_amdgcn_mfma_f32_16x16x32_bf16(a1, b1, acc[1][1], 0, 0, 0);
            acc[1][2] = __builtin_amdgcn_mfma_f32_16x16x32_bf16(a1, b2, acc[1][2], 0, 0, 0);
            acc[1][3] = __builtin_amdgcn_mfma_f32_16x16x32_bf16(a1, b3, acc[1][3], 0, 0, 0);
            acc[2][0] = __builtin_amdgcn_mfma_f32_16x16x32_bf16(a2, b0, acc[2][0], 0, 0, 0);
            acc[2][1] = __builtin_amdgcn_mfma_f32_16x16x32_bf16(a2, b1, acc[2][1], 0, 0, 0);
            acc[2][2] = __builtin_amdgcn_mfma_f32_16x16x32_bf16(a2, b2, acc[2][2], 0, 0, 0);
            acc[2][3] = __builtin_amdgcn_mfma_f32_16x16x32_bf16(a2, b3, acc[2][3], 0, 0, 0);
            acc[3][0] = __builtin_amdgcn_mfma_f32_16x16x32_bf16(a3, b0, acc[3][0], 0, 0, 0);
            acc[3][1] = __builtin_amdgcn_mfma_f32_16x16x32_bf16(a3, b1, acc[3][1], 0, 0, 0);
            acc[3][2] = __builtin_amdgcn_mfma_f32_16x16x32_bf16(a3, b2, acc[3][2], 0, 0, 0);
            acc[3][3] = __builtin_amdgcn_mfma_f32_16x16x32_bf16(a3, b3, acc[3][3], 0, 0, 0);
        }
    }

    // tanh + bias -> A1 in LDS (swizzled bf16, two 64-col halves)
#pragma unroll
    for (int mi = 0; mi < 4; mi++)
#pragma unroll
    for (int ni = 0; ni < 4; ni++) {
        f32x4 a = acc[mi][ni];
        int n = wc * 64 + ni * 16 + lr;
        ushort* buf = (n < 64) ? A1a : A1b;
        int c = n & 63;
#pragma unroll
        for (int j = 0; j < 4; j++) {
            int m = wr * 64 + mi * 16 + lg * 4 + j;
            float v = tanhf(a[j] + fa1b[n]);
            int byo = m * 128 + (((c >> 3) * 16) ^ ((m & 7) << 4)) + (c & 7) * 2;
            *(ushort*)((char*)buf + byo) = f2bf(v);
        }
    }
    __syncthreads();

#pragma unroll
    for (int i = 0; i < 4; i++) {
        int ch = i * 256 + tid;
        int rr = ch >> 3, c8 = ch & 7;
        int c8p = c8 ^ (rr & 7);
        gload16(FA2 + (size_t)rr * 128 + c8p * 8,
                (char*)As + (i * 256 + wid * 64) * 16);
        gload16(FA2 + (size_t)rr * 128 + 64 + c8p * 8,
                (char*)Bs + (i * 256 + wid * 64) * 16);
    }
    __syncthreads();

    f32x4 acc2[4][4];
#pragma unroll
    for (int i = 0; i < 4; i++)
#pragma unroll
        for (int j = 0; j < 4; j++) acc2[i][j] = (f32x4){0.f, 0.f, 0.f, 0.f};

#pragma unroll
    for (int kb = 0; kb < 2; kb++) {
        const char* Ab = (const char*)(kb ? A1b : A1a) + (wr * 64 + lr) * 128;
        const char* Bb = (const char*)(kb ? Bs : As) + (wc * 64 + lr) * 128;
#pragma unroll
        for (int ks = 0; ks < 2; ks++) {
            int kx = (ks * 64 + lg * 16) ^ swz;
            bf16x8 a0 = *(const bf16x8*)(Ab + 0 * 2048 + kx);
            bf16x8 a1 = *(const bf16x8*)(Ab + 1 * 2048 + kx);
            bf16x8 a2 = *(const bf16x8*)(Ab + 2 * 2048 + kx);
            bf16x8 a3 = *(const bf16x8*)(Ab + 3 * 2048 + kx);
            bf16x8 b0 = *(const bf16x8*)(Bb + 0 * 2048 + kx);
            bf16x8 b1 = *(const bf16x8*)(Bb + 1 * 2048 + kx);
            bf16x8 b2 = *(const bf16x8*)(Bb + 2 * 2048 + kx);
            bf16x8 b3 = *(const bf16x8*)(Bb + 3 * 2048 + kx);
            acc2[0][0] = __builtin_amdgcn_mfma_f32_16x16x32_bf16(a0, b0, acc2[0][0], 0, 0, 0);
            acc2[0][1] = __builtin_amdgcn_mfma_f32_16x16x32_bf16(a0, b1, acc2[0][1], 0, 0, 0);
            acc2[0][2] = __builtin_amdgcn_mfma_f32_16x16x32_bf16(a0, b2, acc2[0][2], 0, 0, 0);
            acc2[0][3] = __builtin_amdgcn_mfma_f32_16x16x32_bf16(a0, b3, acc2[0][3], 0, 0, 0);
            acc2[1][0] = __builtin_amdgcn_mfma_f32_16x16x32_bf16(a1, b0, acc2[1][0], 0, 0, 0);
            acc2[1][1] = __builtin_amdgcn_mfma_f32_16x16x32_bf16(a1, b1, acc2[1][1], 0, 0, 0);
            acc2[1][2] = __builtin_amdgcn_mfma_f32_16x16x32_bf16(a1, b2, acc2[1][2], 0, 0, 0);
            acc2[1][3] = __builtin_amdgcn_mfma_f32_16x16x32_bf16(a1, b3, acc2[1][3], 0, 0, 0);
            acc2[2][0] = __builtin_amdgcn_mfma_f32_16x16x32_bf16(a2, b0, acc2[2][0], 0, 0, 0);
            acc2[2][1] = __builtin_amdgcn_mfma_f32_16x16x32_bf16(a2, b1, acc2[2][1], 0, 0, 0);
            acc2[2][2] = __builtin_amdgcn_mfma_f32_16x16x32_bf16(a2, b2, acc2[2][2], 0, 0, 0);
            acc2[2][3] = __builtin_amdgcn_mfma_f32_16x16x32_bf16(a2, b3, acc2[2][3], 0, 0, 0);
            acc2[3][0] = __builtin_amdgcn_mfma_f32_16x16x32_bf16(a3, b0, acc2[3][0], 0, 0, 0);
            acc2[3][1] = __builtin_amdgcn_mfma_f32_16x16x32_bf16(a3, b1, acc2[3][1], 0, 0, 0);
            acc2[3][2] = __builtin_amdgcn_mfma_f32_16x16x32_bf16(a3, b2, acc2[3][2], 0, 0, 0);
            acc2[3][3] = __builtin_amdgcn_mfma_f32_16x16x32_bf16(a3, b3, acc2[3][3], 0, 0, 0);
        }
    }

#pragma unroll
    for (int mi = 0; mi < 4; mi++)
#pragma unroll
    for (int ni = 0; ni < 4; ni++) {
        f32x4 a = acc2[mi][ni];
        int n = wc * 64 + ni * 16 + lr;
#pragma unroll
        for (int j = 0; j < 4; j++) {
            int m = m0 + wr * 64 + mi * 16 + lg * 4 + j;
            if (m >= M) continue;
            A2[(size_t)m * 128 + n] = a[j] + fa2b[n];
        }
    }
}

// ============ split-K MFMA GEMM for emb: PART[z] = A[128,Kc]@B[N,Kc]^T =====
__global__ __launch_bounds__(256)
void mgemm_splitk(const ushort* __restrict__ Asrc, const ushort* __restrict__ Bsrc,
                  float* __restrict__ PART, int N, int Kp, int nsteps, int spz)
{
    __shared__ ushort As[128 * 64];
    __shared__ ushort Bs[128 * 64];

    const int tid  = threadIdx.x;
    const int lane = tid & 63;
    const int wid  = tid >> 6;
    const int wr   = wid >> 1;
    const int wc   = wid & 1;
    const int n0   = blockIdx.x * 128;
    const int z    = blockIdx.z;

    const int lr  = lane & 15;
    const int lg  = lane >> 4;
    const int swz = (lr & 7) << 4;

    f32x4 acc[4][4];
#pragma unroll
    for (int i = 0; i < 4; i++)
#pragma unroll
        for (int j = 0; j < 4; j++) acc[i][j] = (f32x4){0.f, 0.f, 0.f, 0.f};

    const int sb = z * spz;
    const int se = min(sb + spz, nsteps);

    for (int s = sb; s < se; s++) {
        int k0 = s * 64;
        if (s != sb) __syncthreads();
#pragma unroll
        for (int i = 0; i < 4; i++) {
            int ch = i * 256 + tid;
            int rr = ch >> 3, c8 = ch & 7;
            int c8p = c8 ^ (rr & 7);
            gload16(Asrc + (size_t)rr * Kp + k0 + c8p * 8,
                    (char*)As + (i * 256 + wid * 64) * 16);
            gload16(Bsrc + (size_t)(n0 + rr) * Kp + k0 + c8p * 8,
                    (char*)Bs + (i * 256 + wid * 64) * 16);
        }
        __syncthreads();

        const char* Ab = (const char*)As + (wr * 64 + lr) * 128;
        const char* Bb = (const char*)Bs + (wc * 64 + lr) * 128;
#pragma unroll
        for (int ks = 0; ks < 2; ks++) {
            int kx = (ks * 64 + lg * 16) ^ swz;
            bf16x8 a0 = *(const bf16x8*)(Ab + 0 * 2048 + kx);
            bf16x8 a1 = *(const bf16x8*)(Ab + 1 * 2048 + kx);
            bf16x8 a2 = *(const bf16x8*)(Ab + 2 * 2048 + kx);
            bf16x8 a3 = *(const bf16x8*)(Ab + 3 * 2048 + kx);
            bf16x8 b0 = *(const bf16x8*)(Bb + 0 * 2048 + kx);
            bf16x8 b1 = *(const bf16x8*)(Bb + 1 * 2048 + kx);
            bf16x8 b2 = *(const bf16x8*)(Bb + 2 * 2048 + kx);
            bf16x8 b3 = *(const bf16x8*)(Bb + 3 * 2048 + kx);
            acc[0][0] = __builtin_amdgcn_mfma_f32_16x16x32_bf16(a0, b0, acc[0][0], 0, 0, 0);
            acc[0][1] = __builtin_amdgcn_mfma_f32_16x16x32_bf16(a0, b1, acc[0][1], 0, 0, 0);
            acc[0][2] = __builtin_amdgcn_mfma_f32_16x16x32_bf16(a0, b2, acc[0][2], 0, 0, 0);
            acc[0][3] = __builtin_amdgcn_mfma_f32_16x16x32_bf16(a0, b3, acc[0][3], 0, 0, 0);
            acc[1][0] = __builtin_amdgcn_mfma_f32_16x16x32_bf16(a1, b0, acc[1][0], 0, 0, 0);
            acc[1][1] = __builtin_amdgcn_mfma_f32_16x16x32_bf16(a1, b1, acc[1][1], 0, 0, 0);
            acc[1][2] = __builtin_amdgcn_mfma_f32_16x16x32_bf16(a1, b2, acc[1][2], 0, 0, 0);
            acc[1][3] = __builtin_amdgcn_mfma_f32_16x16x32_bf16(a1, b3, acc[1][3], 0, 0, 0);
            acc[2][0] = __builtin_amdgcn_mfma_f32_16x16x32_bf16(a2, b0, acc[2][0], 0, 0, 0);
            acc[2][1] = __builtin_amdgcn_mfma_f32_16x16x32_bf16(a2, b1, acc[2][1], 0, 0, 0);
            acc[2][2] = __builtin_amdgcn_mfma_f32_16x16x32_bf16(a2, b2, acc[2][2], 0, 0, 0);
            acc[2][3] = __builtin_amdgcn_mfma_f32_16x16x32_bf16(a2, b3, acc[2][3], 0, 0, 0);
            acc[3][0] = __builtin_amdgcn_mfma_f32_16x16x32_bf16(a3, b0, acc[3][0], 0, 0, 0);
            acc[3][1] = __builtin_amdgcn_mfma_f32_16x16x32_bf16(a3, b1, acc[3][1], 0, 0, 0);
            acc[3][2] = __builtin_amdgcn_mfma_f32_16x16x32_bf16(a3, b2, acc[3][2], 0, 0, 0);
            acc[3][3] = __builtin_amdgcn_mfma_f32_16x16x32_bf16(a3, b3, acc[3][3], 0, 0, 0);
        }
    }

    float* outp = PART + (size_t)z * 128 * 512;
#pragma unroll
    for (int mi = 0; mi < 4; mi++) {
#pragma unroll
        for (int ni = 0; ni < 4; ni++) {
            f32x4 a = acc[mi][ni];
            int n = n0 + wc * 64 + ni * 16 + lr;
#pragma unroll
            for (int j = 0; j < 4; j++) {
                int m = wr * 64 + mi * 16 + lg * 4 + j;
                outp[(size_t)m * 512 + n] = a[j];
            }
        }
    }
}

__global__ void reduce_part(const float* __restrict__ PART, float* __restrict__ EMB, int Z)
{
    int idx = blockIdx.x * blockDim.x + threadIdx.x;   // 0..65535
    float s = 0.f;
    for (int z = 0; z < Z; z++) s += PART[(size_t)z * 65536 + idx];
    EMB[idx] = s;
}

// attn weights, transposed + bf16 + zero-pad: ATTWT[c][n], n in [0,Kp)
__global__ void att_w_t(const float* __restrict__ a2, const float* __restrict__ ms,
                        const float* __restrict__ ss, ushort* __restrict__ W,
                        int Nn, int Kp)
{
    int idx = blockIdx.x * blockDim.x + threadIdx.x;
    if (idx >= 128 * Kp) return;
    int c = idx / Kp, n = idx % Kp;
    float v = 0.f;
    if (n < Nn) v = expf(a2[(size_t)n * 128 + c] - ms[c]) / ss[c];
    W[idx] = f2bf(v);
}

// XB [Nn][512] bf16 -> XBT [512][Kp] bf16 (zero-pad n >= Nn), 64x64 LDS tiles
__global__ __launch_bounds__(256)
void t_xb(const ushort* __restrict__ XB, ushort* __restrict__ XBT, int Nn, int Kp)
{
    __shared__ ushort tile[64][72];
    const int n0 = blockIdx.x * 64;
    const int d0 = blockIdx.y * 64;
    const int tid = threadIdx.x;
#pragma unroll
    for (int i = 0; i < 2; i++) {
        int ch = i * 256 + tid;
        int r = ch >> 3, c8 = ch & 7;
        int n = n0 + r;
        ushort8v v = {0, 0, 0, 0, 0, 0, 0, 0};
        if (n < Nn) v = *(const ushort8v*)(XB + (size_t)n * 512 + d0 + c8 * 8);
        *(ushort8v*)&tile[r][c8 * 8] = v;
    }
    __syncthreads();
#pragma unroll
    for (int i = 0; i < 2; i++) {
        int ch = i * 256 + tid;
        int dr = ch >> 3, n8 = ch & 7;
        ushort8v v;
#pragma unroll
        for (int q = 0; q < 8; q++) v[q] = tile[n8 * 8 + q][dr];
        *(ushort8v*)(XBT + (size_t)(d0 + dr) * Kp + n0 + n8 * 8) = v;
    }
}

// ============ implicit-GEMM conv 3x3 stride2 pad1, NHWC bf16, IC=64 ========
template<int NI>
__global__ __launch_bounds__(256)
void conv_mfma(const ushort* __restrict__ in, const ushort* __restrict__ Wk,
               const float* __restrict__ bias, const float* __restrict__ gamma,
               const float* __restrict__ beta, ushort* __restrict__ outp,
               int IH, int IW, int OH, int OW)
{
    const int OC = NI * 16;
    __shared__ ushort As[128 * 64];
    __shared__ ushort Bs[NI * 16 * 64];

    const int tid  = threadIdx.x;
    const int lane = tid & 63;
    const int wv   = tid >> 6;
    const int lr   = lane & 15;
    const int lg   = lane >> 4;
    const int swz  = (lr & 7) << 4;
    const int m0   = blockIdx.x * 128;
    const int M    = OH * OW;

    f32x4 acc[2][NI];
#pragma unroll
    for (int i = 0; i < 2; i++)
#pragma unroll
        for (int j = 0; j < NI; j++) acc[i][j] = (f32x4){0.f, 0.f, 0.f, 0.f};

    for (int r = 0; r < 9; r++) {
        const int kh = r / 3, kw = r % 3;
        if (r) __syncthreads();
#pragma unroll
        for (int i = 0; i < 4; i++) {
            int ch = i * 256 + tid;
            int p = ch >> 3, c8 = ch & 7;
            int lb = p * 128 + ((c8 * 16) ^ ((p & 7) << 4));
            int gp = m0 + p; if (gp > M - 1) gp = M - 1;
            int oh = gp / OW, ow = gp % OW;
            int ih = oh * 2 - 1 + kh, iw = ow * 2 - 1 + kw;
            ushort8v v = {0, 0, 0, 0, 0, 0, 0, 0};
            if (ih >= 0 && ih < IH && iw >= 0 && iw < IW)
                v = *(const ushort8v*)(in + ((size_t)ih * IW + iw) * 64 + c8 * 8);
            *(ushort8v*)((char*)As + lb) = v;
        }
        for (int ch = tid; ch < OC * 8; ch += 256) {
            int oc = ch >> 3, c8 = ch & 7;
            int lb = oc * 128 + ((c8 * 16) ^ ((oc & 7) << 4));
            ushort8v v = *(const ushort8v*)(Wk + (size_t)oc * 576 + r * 64 + c8 * 8);
            *(ushort8v*)((char*)Bs + lb) = v;
        }
        __syncthreads();

        const char* Ab = (const char*)As + (wv * 32 + lr) * 128;
        const char* Bb = (const char*)Bs + lr * 128;
#pragma unroll
        for (int ks = 0; ks < 2; ks++) {
            int kx = (ks * 64 + lg * 16) ^ swz;
            bf16x8 a0 = *(const bf16x8*)(Ab + 0 * 2048 + kx);
            bf16x8 a1 = *(const bf16x8*)(Ab + 1 * 2048 + kx);
#pragma unroll
            for (int ni = 0; ni < NI; ni++) {
                bf16x8 bfr = *(const bf16x8*)(Bb + ni * 2048 + kx);
                acc[0][ni] = __builtin_amdgcn_mfma_f32_16x16x32_bf16(a0, bfr, acc[0][ni], 0, 0, 0);
                acc[1][ni] = __builtin_amdgcn_mfma_f32_16x16x32_bf16(a1, bfr, acc[1][ni], 0, 0, 0);
            }
        }
    }

#pragma unroll
    for (int mi = 0; mi < 2; mi++)
#pragma unroll
    for (int ni = 0; ni < NI; ni++) {
        f32x4 a = acc[mi][ni];
        int oc = ni * 16 + lr;
        float bv = bias[oc], gv = gamma[oc], btv = beta[oc];
#pragma unroll
        for (int j = 0; j < 4; j++) {
            int gp = m0 + wv * 32 + mi * 16 + lg * 4 + j;
            if (gp >= M) continue;
            float v = a[j] + bv;
            v = gv * v * BN_INV + btv;
            v = fmaxf(v, 0.f);
            outp[(size_t)gp * OC + oc] = f2bf(v);
        }
    }
}

// conv1: emb[128][512] f32 (1ch) -> e0[132][516][64] NHWC bf16, k3 s1 pad3, bn+relu
__global__ void conv1_nhwc(const float* __restrict__ emb, const float* __restrict__ w,
                           const float* __restrict__ b, const float* __restrict__ g,
                           const float* __restrict__ bb, ushort* __restrict__ outp)
{
    int oh = blockIdx.x;  // 0..131
    for (int idx = threadIdx.x; idx < 516 * 8; idx += 256) {
        int ow = idx >> 3, c8 = idx & 7;
        float pv[9];
#pragma unroll
        for (int kh = 0; kh < 3; kh++)
#pragma unroll
            for (int kw = 0; kw < 3; kw++) {
                int ih = oh - 3 + kh, iw = ow - 3 + kw;
                pv[kh * 3 + kw] = (ih >= 0 && ih < 128 && iw >= 0 && iw < 512)
                                  ? emb[ih * 512 + iw] : 0.f;
            }
        ushort8v o;
#pragma unroll
        for (int q = 0; q < 8; q++) {
            int oc = c8 * 8 + q;
            float v = b[oc];
#pragma unroll
            for (int i = 0; i < 9; i++) v = fmaf(pv[i], w[oc * 9 + i], v);
            v = g[oc] * v * BN_INV + bb[oc];
            v = fmaxf(v, 0.f);
            o[q] = f2bf(v);
        }
        *(ushort8v*)(outp + ((size_t)oh * 516 + ow) * 64 + c8 * 8) = o;
    }
}

// 3x3 maxpool s1 p1, NHWC bf16 (valid cells only)
__global__ void maxpool_nhwc(const ushort* __restrict__ in, ushort* __restrict__ out,
                             int H, int W, int C8)
{
    int h = blockIdx.x;
    int tot = W * C8;
    for (int idx = threadIdx.x; idx < tot; idx += blockDim.x) {
        int w0 = idx / C8, cg = idx % C8;
        float mx[8];
#pragma unroll
        for (int q = 0; q < 8; q++) mx[q] = -1e30f;
        for (int dh = -1; dh <= 1; dh++) {
            int hh = h + dh; if (hh < 0 || hh >= H) continue;
            for (int dw = -1; dw <= 1; dw++) {
                int ww = w0 + dw; if (ww < 0 || ww >= W) continue;
                ushort8v v = *(const ushort8v*)(in + ((size_t)hh * W + ww) * C8 * 8 + cg * 8);
#pragma unroll
                for (int q = 0; q < 8; q++) mx[q] = fmaxf(mx[q], bf2f(v[q]));
            }
        }
        ushort8v o;
#pragma unroll
        for (int q = 0; q < 8; q++) o[q] = f2bf(mx[q]);
        *(ushort8v*)(out + ((size_t)h * W + w0) * C8 * 8 + cg * 8) = o;
    }
}

// ==== conv2 + maxpool, single block; conv output kept in LDS; FLAT[432] out =
__global__ __launch_bounds__(256)
void conv2_pool(const ushort* __restrict__ in, const ushort* __restrict__ WC2,
                const float* __restrict__ c2b, const float* __restrict__ c2g,
                const float* __restrict__ c2bb, float* __restrict__ FLAT,
                int IH, int IW)
{
    __shared__ ushort As[128 * 64];
    __shared__ ushort Bs[16 * 64];
    __shared__ float E[27][16];

    const int tid  = threadIdx.x;
    const int lane = tid & 63;
    const int wv   = tid >> 6;
    const int lr   = lane & 15;
    const int lg   = lane >> 4;
    const int swz  = (lr & 7) << 4;
    const int OH = 3, OW = 9, M = 27;

    f32x4 acc[2];
    acc[0] = (f32x4){0.f, 0.f, 0.f, 0.f};
    acc[1] = (f32x4){0.f, 0.f, 0.f, 0.f};

    for (int r = 0; r < 9; r++) {
        const int kh = r / 3, kw = r % 3;
        if (r) __syncthreads();
#pragma unroll
        for (int i = 0; i < 4; i++) {
            int ch = i * 256 + tid;
            int p = ch >> 3, c8 = ch & 7;
            int lb = p * 128 + ((c8 * 16) ^ ((p & 7) << 4));
            int gp = p; if (gp > M - 1) gp = M - 1;
            int oh = gp / OW, ow = gp % OW;
            int ih = oh * 2 - 1 + kh, iw = ow * 2 - 1 + kw;
            ushort8v v = {0, 0, 0, 0, 0, 0, 0, 0};
            if (ih >= 0 && ih < IH && iw >= 0 && iw < IW)
                v = *(const ushort8v*)(in + ((size_t)ih * IW + iw) * 64 + c8 * 8);
            *(ushort8v*)((char*)As + lb) = v;
        }
        for (int ch = tid; ch < 16 * 8; ch += 256) {
            int oc = ch >> 3, c8 = ch & 7;
            int lb = oc * 128 + ((c8 * 16) ^ ((oc & 7) << 4));
            ushort8v v = *(const ushort8v*)(WC2 + (size_t)oc * 576 + r * 64 + c8 * 8);
            *(ushort8v*)((char*)Bs + lb) = v;
        }
        __syncthreads();

        const char* Ab = (const char*)As + (wv * 32 + lr) * 128;
        const char* Bb = (const char*)Bs + lr * 128;
#pragma unroll
        for (int ks = 0; ks < 2; ks++) {
            int kx = (ks * 64 + lg * 16) ^ swz;
            bf16x8 a0 = *(const bf16x8*)(Ab + 0 * 2048 + kx);
            bf16x8 a1 = *(const bf16x8*)(Ab + 1 * 2048 + kx);
            bf16x8 bfr = *(const bf16x8*)(Bb + kx);
            acc[0] = __builtin_amdgcn_mfma_f32_16x16x32_bf16(a0, bfr, acc[0], 0, 0, 0);
            acc[1] = __builtin_amdgcn_mfma_f32_16x16x32_bf16(a1, bfr, acc[1], 0, 0, 0);
        }
    }

#pragma unroll
    for (int mi = 0; mi < 2; mi++) {
        f32x4 a = acc[mi];
        int oc = lr;
        float bv = c2b[oc], gv = c2g[oc], btv = c2bb[oc];
#pragma unroll
        for (int j = 0; j < 4; j++) {
            int gp = wv * 32 + mi * 16 + lg * 4 + j;
            if (gp >= M) continue;
            float v = a[j] + bv;
            v = gv * v * BN_INV + btv;
            v = fmaxf(v, 0.f);
            // bf16 round-trip to match previous numerics
            E[gp][oc] = bf2f(f2bf(v));
        }
    }
    __syncthreads();

    // maxpool 3x3 s1 p1 on [3][9][16] -> FLAT[c*27 + h*9 + w]
    for (int i = tid; i < 432; i += 256) {
        int c = i / 27, r = i % 27;
        int h = r / 9, w0 = r % 9;
        float m = -1e30f;
        for (int dh = -1; dh <= 1; dh++) {
            int hh = h + dh; if (hh < 0 || hh >= 3) continue;
            for (int dw = -1; dw <= 1; dw++) {
                int ww = w0 + dw; if (ww < 0 || ww >= 9) continue;
                m = fmaxf(m, E[hh * 9 + ww][c]);
            }
        }
        FLAT[i] = m;
    }
}

// ==== head fc1: T1[o] = fc1b[o] + sum_k FLAT[k]*fc1w[o][k]; 64 blocks ======
__global__ __launch_bounds__(256)
void head_fc1(const float* __restrict__ FLAT, const float* __restrict__ fc1w,
              const float* __restrict__ fc1b, float* __restrict__ T1)
{
    __shared__ float fl[432];
    const int tid = threadIdx.x;
    for (int i = tid; i < 432; i += 256) fl[i] = FLAT[i];
    __syncthreads();
    const int wv = tid >> 6, l = tid & 63;
    const int o = blockIdx.x * 16 + wv * 4;   // 4 outputs per wave
#pragma unroll
    for (int j = 0; j < 4; j++) {
        int oo = o + j;
        const float* wr = fc1w + (size_t)oo * 432;
        float s = 0.f;
        for (int k = l; k < 432; k += 64) s = fmaf(fl[k], wr[k], s);
        for (int sh = 32; sh > 0; sh >>= 1) s += __shfl_down(s, sh, 64);
        if (l == 0) T1[oo] = s + fc1b[oo];
    }
}

// ==== head fc2 + sigmoid: out[14]; 1 block x 1024 ==========================
__global__ __launch_bounds__(1024)
void head_fc2(const float* __restrict__ T1, const float* __restrict__ fc2w,
              const float* __restrict__ fc2b, float* __restrict__ outp)
{
    __shared__ float t1[1024];
    const int tid = threadIdx.x;
    t1[tid] = T1[tid];
    __syncthreads();
    int o = tid >> 6, l = tid & 63;
    if (o < 14) {
        float s = 0.f;
        const float* wr = fc2w + (size_t)o * 1024;
        for (int k = l; k < 1024; k += 64) s = fmaf(t1[k], wr[k], s);
        for (int sh = 32; sh > 0; sh >>= 1) s += __shfl_down(s, sh, 64);
        if (l == 0) outp[o] = 1.f / (1.f + expf(-(s + fc2b[o])));
    }
}

// ---------------- fused weight prep (cvt + conv reorder) --------------------
__global__ void prep_all(const float* w1l, const float* w1r, const float* w2l,
                         const float* w2r, const float* fa1, const float* fa2,
                         const float* c1w, const float* c2w,
                         ushort* W1L, ushort* W1R, ushort* W2L, ushort* W2R,
                         ushort* FA1, ushort* FA2, ushort* WC1, ushort* WC2)
{
    int i = blockIdx.x * blockDim.x + threadIdx.x;
    if (i < 796672) {
        const float* s; ushort* d; int j;
        if      (i < 327680)  { s = w1l; d = W1L; j = i; }
        else if (i < 655360)  { s = w1r; d = W1R; j = i - 327680; }
        else if (i < 720896)  { s = w2l; d = W2L; j = i - 655360; }
        else if (i < 786432)  { s = w2r; d = W2R; j = i - 720896; }
        else if (i < 794624)  { s = fa1; d = FA1; j = i - 786432; }
        else                  { s = fa2; d = FA2; j = i - 794624; }
        const float4 f0 = *(const float4*)(s + (size_t)j * 8);
        const float4 f1 = *(const float4*)(s + (size_t)j * 8 + 4);
        ushort8v v;
        v[0] = f2bf(f0.x); v[1] = f2bf(f0.y); v[2] = f2bf(f0.z); v[3] = f2bf(f0.w);
        v[4] = f2bf(f1.x); v[5] = f2bf(f1.y); v[6] = f2bf(f1.z); v[7] = f2bf(f1.w);
        *(ushort8v*)(d + (size_t)j * 8) = v;
    } else {
        int k = i - 796672;
        if (k >= 80 * 576) return;
        const float* w; ushort* wk; int idx;
        if (k < 64 * 576) { w = c1w; wk = WC1; idx = k; }
        else              { w = c2w; wk = WC2; idx = k - 64 * 576; }
        int oc = idx / 576, t = idx % 576;
        int r = t / 64, ic = t % 64;
        int kh = r / 3, kw = r % 3;
        wk[idx] = f2bf(w[((oc * 64 + ic) * 3 + kh) * 3 + kw]);
    }
}

// ---------------- parallel CSR build (4 dispatches) -------------------------
__global__ void hist_k(const int* __restrict__ dst, int* __restrict__ hist, int E)
{
    int e = blockIdx.x * blockDim.x + threadIdx.x;
    if (e < E) atomicAdd(&hist[dst[e]], 1);
}

__global__ __launch_bounds__(1024)
void scan_k(const int* __restrict__ hist, int* __restrict__ off, int n)
{
    __shared__ int tmp[1024];
    const int PT = (n + 1023) / 1024;
    int t = threadIdx.x;
    int b = t * PT;
    int ls = 0;
    for (int k = 0; k < PT; k++) { int i = b + k; if (i < n) ls += hist[i]; }
    tmp[t] = ls;
    __syncthreads();
    for (int s = 1; s < 1024; s <<= 1) {
        int v = (t >= s) ? tmp[t - s] : 0;
        __syncthreads();
        tmp[t] += v;
        __syncthreads();
    }
    int run = tmp[t] - ls;
    for (int k = 0; k < PT; k++) {
        int i = b + k;
        if (i < n) { off[i] = run; run += hist[i]; }
    }
    if (t == 1023) off[n] = tmp[1023];
}

__global__ void fill_k(const int* __restrict__ src, const int* __restrict__ dst,
                       const int* __restrict__ off, int* __restrict__ cursor,
                       int* __restrict__ eidx, int E)
{
    int e = blockIdx.x * blockDim.x + threadIdx.x;
    if (e >= E) return;
    int d = dst[e];
    int pos = atomicAdd(&cursor[d], 1);
    eidx[off[d] + pos] = src[e];
}

// ---------------- f32 -> bf16 convert (x -> XBF) ----------------------------
__global__ void cvt_k(const float* __restrict__ in, ushort* __restrict__ out, int n8)
{
    int i = blockIdx.x * blockDim.x + threadIdx.x;
    if (i >= n8) return;
    const float4 f0 = *(const float4*)(in + (size_t)i * 8);
    const float4 f1 = *(const float4*)(in + (size_t)i * 8 + 4);
    ushort8v v;
    v[0] = f2bf(f0.x); v[1] = f2bf(f0.y); v[2] = f2bf(f0.z); v[3] = f2bf(f0.w);
    v[4] = f2bf(f1.x); v[5] = f2bf(f1.y); v[6] = f2bf(f1.z); v[7] = f2bf(f1.w);
    *(ushort8v*)(out + (size_t)i * 8) = v;
}

// ---------------- attention softmax over nodes ------------------------------
__global__ __launch_bounds__(256)
void softmax_stats(const float* __restrict__ a2, float* __restrict__ ms,
                   float* __restrict__ ss, int Nn)
{
    int c = blockIdx.x;
    __shared__ float red[256];
    float mx = -1e30f;
    for (int n = threadIdx.x; n < Nn; n += 256)
        mx = fmaxf(mx, a2[(size_t)n * 128 + c]);
    red[threadIdx.x] = mx;
    __syncthreads();
    for (int s = 128; s > 0; s >>= 1) {
        if (threadIdx.x < s) red[threadIdx.x] = fmaxf(red[threadIdx.x], red[threadIdx.x + s]);
        __syncthreads();
    }
    mx = red[0];
    __syncthreads();
    float sum = 0.f;
    for (int n = threadIdx.x; n < Nn; n += 256)
        sum += expf(a2[(size_t)n * 128 + c] - mx);
    red[threadIdx.x] = sum;
    __syncthreads();
    for (int s = 128; s > 0; s >>= 1) {
        if (threadIdx.x < s) red[threadIdx.x] += red[threadIdx.x + s];
        __syncthreads();
    }
    if (threadIdx.x == 0) { ms[c] = mx; ss[c] = red[0]; }
}

// ---------------------------------------------------------------------------
extern "C" void kernel_launch(void* const* d_in, const int* in_sizes, int n_in,
                              void* d_out, int out_size, void* d_ws, size_t ws_size,
                              hipStream_t stream)
{
    const float* x     = (const float*)d_in[0];
    const int*   ei    = (const int*)d_in[1];
    const float* w1l   = (const float*)d_in[2];
    const float* b1    = (const float*)d_in[3];
    const float* w1r   = (const float*)d_in[4];
    const float* bn1g  = (const float*)d_in[5];
    const float* bn1b  = (const float*)d_in[6];
    const float* w2l   = (const float*)d_in[7];
    const float* b2    = (const float*)d_in[8];
    const float* w2r   = (const float*)d_in[9];
    const float* fa1w  = (const float*)d_in[10];
    const float* fa1b  = (const float*)d_in[11];
    const float* fa2w  = (const float*)d_in[12];
    const float* fa2b  = (const float*)d_in[13];
    const float* cnn1w = (const float*)d_in[14];
    const float* cnn1b = (const float*)d_in[15];
    const float* normg = (const float*)d_in[16];
    const float* normb = (const float*)d_in[17];
    const float* c1w   = (const float*)d_in[18];
    const float* c1b   = (const float*)d_in[19];
    const float* c1g   = (const float*)d_in[20];
    const float* c1bb  = (const float*)d_in[21];
    const float* c2w   = (const float*)d_in[22];
    const float* c2b   = (const float*)d_in[23];
    const float* c2g   = (const float*)d_in[24];
    const float* c2bb  = (const float*)d_in[25];
    const float* fc1w  = (const float*)d_in[26];
    const float* fc1b  = (const float*)d_in[27];
    const float* fc2w  = (const float*)d_in[28];
    const float* fc2b  = (const float*)d_in[29];
    float* out = (float*)d_out;

    const int Nn = 10000, E = 160000;
    const int Kp = 10048;   // 157*64
    char* ws = (char*)d_ws;

    // ---- workspace layout (bytes) — phase-checked, no live overlaps ----
    ushort* YL    = (ushort*)(ws + 0);           // 20,480,000
    ushort* ATTWT = (ushort*)(ws + 0);           // 2,572,288 (YL dead after gather_h1)
    ushort* XBT   = (ushort*)(ws + 2572288);     // -> 12,861,440
    ushort* P16   = (ushort*)(ws + 0);           // 8,718,336
    ushort* Q16   = (ushort*)(ws + 13000000);    // -> 15,179,584
    ushort* H1   = (ushort*)(ws + 20480000);     // 20,480,000
    ushort* XB   = (ushort*)(ws + 20480000);     // 10,240,000
    float*  A2   = (float*)(ws + 33280000);      // 5,120,000 -> 38,400,000
    ushort* YR   = (ushort*)(ws + 40960000);     // 20,480,000
    ushort* ZL   = (ushort*)(ws + 40960000);     // 10,240,000
    ushort* ZR   = (ushort*)(ws + 51200000);     // -> 61,440,000
    float*  PART = (float*)(ws + 40960000);      // 10,485,760 (ZL/ZR dead by splitk)
    int*   hist   = (int*)(ws + 61440000);       // 40,000
    int*   cursor = (int*)(ws + 61480000);       // 40,000
    int*   off    = (int*)(ws + 61520000);       // 40,004
    int*   eidx   = (int*)(ws + 61560128);       // 640,000 -> 62,200,128
    float* FLAT  = (float*)(ws + 62300032);      // 432 f32
    float* T1    = (float*)(ws + 62310016);      // 1024 f32
    float*  MS   = (float*)(ws + 67360128);
    float*  SS   = (float*)(ws + 67360640);
    float*  EMB  = (float*)(ws + 67361152);      // -> 67,623,296
    ushort* W1L = (ushort*)(ws + 67623296);      // W1L+W1R contiguous = [2048][2560]
    ushort* W1R = (ushort*)(ws + 72866176);
    ushort* W2L = (ushort*)(ws + 78109056);      // W2L+W2R contiguous = [1024][1024]
    ushort* W2R = (ushort*)(ws + 79157632);
    ushort* FA1 = (ushort*)(ws + 80206208);
    ushort* FA2 = (ushort*)(ws + 80337280);
    ushort* WC1 = (ushort*)(ws + 80370048);
    ushort* WC2 = (ushort*)(ws + 80443776);      // -> 80,462,208
    ushort* XBF = (ushort*)(ws + 80462208);      // 51,200,000 -> 131,662,208
    const bool use_xbf = (ws_size >= (size_t)131662208);

    const int* src = ei;
    const int* dst = ei + E;

    // ---- weight prep (1) + parallel CSR build (4) ----
    prep_all<<<(796672 + 80 * 576 + 255) / 256, 256, 0, stream>>>(
        w1l, w1r, w2l, w2r, fa1w, fa2w, c1w, c2w,
        W1L, W1R, W2L, W2R, FA1, FA2, WC1, WC2);
    hipMemsetAsync(hist, 0, 80000, stream);   // hist + cursor (adjacent)
    hist_k<<<(E + 255) / 256, 256, 0, stream>>>(dst, hist, E);
    scan_k<<<1, 1024, 0, stream>>>(hist, off, Nn);
    fill_k<<<(E + 255) / 256, 256, 0, stream>>>(src, dst, off, cursor, eidx, E);

    const int GY = (Nn + 127) / 128;   // 79

    // ---- SAGE layer 1: fused [YL | YR] = x @ [W1L;W1R]^T (N=2048) ----
    if (use_xbf) {
        cvt_k<<<(3200000 + 255) / 256, 256, 0, stream>>>(x, XBF, 3200000);
        mgemm<0, 5, ushort><<<dim3(2048 / 128, GY), 256, 0, stream>>>(
            XBF, W1L, YL, Nn, 2048, 2560, nullptr, YR);
    } else {
        mgemm<1, 5, ushort><<<dim3(2048 / 128, GY), 256, 0, stream>>>(
            x, W1L, YL, Nn, 2048, 2560, nullptr, YR);
    }
    gather_h1<<<Nn, 128, 0, stream>>>(YL, eidx, off, YR, b1, bn1g, bn1b, H1);

    // ---- SAGE layer 2: fused [ZL | ZR] = h1 @ [W2L;W2R]^T (N=1024) ----
    mgemm<0, 5, ushort><<<dim3(1024 / 128, GY), 256, 0, stream>>>(
        H1, W2L, ZL, Nn, 1024, 1024, nullptr, ZR);
    gather_xb<<<Nn, 64, 0, stream>>>(ZL, eidx, off, ZR, b2, XB);

    // ---- attention (fused MLP) ----
    attn_a1a2<<<GY, 256, 0, stream>>>(XB, FA1, fa1b, FA2, fa2b, A2, Nn);
    softmax_stats<<<128, 256, 0, stream>>>(A2, MS, SS, Nn);
    att_w_t<<<(128 * Kp + 255) / 256, 256, 0, stream>>>(A2, MS, SS, ATTWT, Nn, Kp);
    t_xb<<<dim3(Kp / 64, 8), 256, 0, stream>>>(XB, XBT, Nn, Kp);
    mgemm_splitk<<<dim3(4, 1, 40), 256, 0, stream>>>(ATTWT, XBT, PART, 512, Kp, 157, 4);
    reduce_part<<<256, 256, 0, stream>>>(PART, EMB, 40);

    // ---- CNN (separate kernels) ----
    conv1_nhwc<<<132, 256, 0, stream>>>(EMB, cnn1w, cnn1b, normg, normb, P16);
    int H = 132, W = 516;
    for (int it = 0; it < 5; it++) {
        int OH = (H - 1) / 2 + 1, OW = (W - 1) / 2 + 1;
        int M = OH * OW;
        conv_mfma<4><<<(M + 127) / 128, 256, 0, stream>>>(
            P16, WC1, c1b, c1g, c1bb, Q16, H, W, OH, OW);
        maxpool_nhwc<<<OH, 256, 0, stream>>>(Q16, P16, OH, OW, 8);
        H = OH; W = OW;
    }
    // conv2 + pool (single block, LDS-resident), then parallel head
    conv2_pool<<<1, 256, 0, stream>>>(P16, WC2, c2b, c2g, c2bb, FLAT, H, W);
    head_fc1<<<64, 256, 0, stream>>>(FLAT, fc1w, fc1b, T1);
    head_fc2<<<1, 1024, 0, stream>>>(T1, fc2w, fc2b, out);
}

// Round 14
// 560.612 us; speedup vs baseline: 1.8478x; 1.0086x over previous
//
#include <hip/hip_runtime.h>
#include <cstdint>
#include <cstddef>

typedef unsigned short ushort;
typedef __attribute__((ext_vector_type(8))) short bf16x8;
typedef __attribute__((ext_vector_type(8))) unsigned short ushort8v;
typedef __attribute__((ext_vector_type(4))) float f32x4;

// 1/sqrt(1+1e-5)
#define BN_INV 0.9999950000374997f

__device__ inline ushort f2bf(float f) {
    union { float f; unsigned u; } x; x.f = f;
    unsigned r = x.u + 0x7fffu + ((x.u >> 16) & 1u);
    return (ushort)(r >> 16);
}
__device__ inline float bf2f(ushort u) {
    union { unsigned u; float f; } x; x.u = ((unsigned)u) << 16;
    return x.f;
}

// async global->LDS, 16B per lane. LDS dest is wave-uniform base + lane*16.
__device__ __forceinline__ void gload16(const void* g, void* l) {
    __builtin_amdgcn_global_load_lds(
        (const __attribute__((address_space(1))) unsigned int*)g,
        (__attribute__((address_space(3))) unsigned int*)l, 16, 0, 0);
}

// ======================= MFMA bf16 GEMM ====================================
// C[M,N] = A[M,K] @ B[N,K]^T.  B always bf16.
// AMODE 0: A bf16 via global_load_lds w/ pre-swizzled source.
// AMODE 1: A f32 (reg-converted), reg-staged swizzled LDS writes.
// XCD-chunked bijective swizzle, N-INNER (A panels L2-resident, B via L3).
// EPIL 5: split-write at N/2: n<N/2 -> C, else -> C2 (row stride N/2)
template<int AMODE, int EPIL, typename OutT>
__global__ __launch_bounds__(256)
void mgemm(const void* __restrict__ Asrc, const ushort* __restrict__ Bsrc,
           OutT* __restrict__ C, int M, int N, int K,
           const float* __restrict__ bias, ushort* __restrict__ C2)
{
    __shared__ ushort As[128 * 64];
    __shared__ ushort Bs[128 * 64];

    const int tid  = threadIdx.x;
    const int lane = tid & 63;
    const int wid  = tid >> 6;
    const int wr   = wid >> 1;
    const int wc   = wid & 1;

    const int nwg  = gridDim.x * gridDim.y;
    const int orig = blockIdx.y * gridDim.x + blockIdx.x;
    const int q    = nwg >> 3, r = nwg & 7;
    const int xcd  = orig & 7, ii = orig >> 3;
    const int wg   = (xcd < r ? xcd * (q + 1) : r * (q + 1) + (xcd - r) * q) + ii;
    const int m0   = (wg / gridDim.x) * 128;
    const int n0   = (wg % gridDim.x) * 128;

    const int lr  = lane & 15;
    const int lg  = lane >> 4;
    const int swz = (lr & 7) << 4;

    f32x4 acc[4][4];
#pragma unroll
    for (int i = 0; i < 4; i++)
#pragma unroll
        for (int j = 0; j < 4; j++) acc[i][j] = (f32x4){0.f, 0.f, 0.f, 0.f};

    for (int k0 = 0; k0 < K; k0 += 64) {
        if (k0) __syncthreads();
        if constexpr (AMODE == 0) {
#pragma unroll
            for (int i = 0; i < 4; i++) {
                int ch = i * 256 + tid;
                int rr = ch >> 3, c8 = ch & 7;
                int c8p = c8 ^ (rr & 7);
                int srow = m0 + rr; if (srow > M - 1) srow = M - 1;
                gload16((const ushort*)Asrc + (size_t)srow * K + k0 + c8p * 8,
                        (char*)As + (i * 256 + wid * 64) * 16);
                gload16(Bsrc + (size_t)(n0 + rr) * K + k0 + c8p * 8,
                        (char*)Bs + (i * 256 + wid * 64) * 16);
            }
        } else {
#pragma unroll
            for (int i = 0; i < 4; i++) {
                int ch = i * 256 + tid;
                int rr = ch >> 3, c8 = ch & 7;
                int lb = rr * 128 + ((c8 * 16) ^ ((rr & 7) << 4));
                int srow = m0 + rr; if (srow > M - 1) srow = M - 1;
                const float* ap = (const float*)Asrc + (size_t)srow * K + k0 + c8 * 8;
                float4 f0 = *(const float4*)ap;
                float4 f1 = *(const float4*)(ap + 4);
                ushort8v va;
                va[0] = f2bf(f0.x); va[1] = f2bf(f0.y); va[2] = f2bf(f0.z); va[3] = f2bf(f0.w);
                va[4] = f2bf(f1.x); va[5] = f2bf(f1.y); va[6] = f2bf(f1.z); va[7] = f2bf(f1.w);
                *(ushort8v*)((char*)As + lb) = va;
                ushort8v vb = *(const ushort8v*)(Bsrc + (size_t)(n0 + rr) * K + k0 + c8 * 8);
                *(ushort8v*)((char*)Bs + lb) = vb;
            }
        }
        __syncthreads();

        const char* Ab = (const char*)As + (wr * 64 + lr) * 128;
        const char* Bb = (const char*)Bs + (wc * 64 + lr) * 128;
#pragma unroll
        for (int ks = 0; ks < 2; ks++) {
            int kx = (ks * 64 + lg * 16) ^ swz;
            bf16x8 a0 = *(const bf16x8*)(Ab + 0 * 2048 + kx);
            bf16x8 a1 = *(const bf16x8*)(Ab + 1 * 2048 + kx);
            bf16x8 a2 = *(const bf16x8*)(Ab + 2 * 2048 + kx);
            bf16x8 a3 = *(const bf16x8*)(Ab + 3 * 2048 + kx);
            bf16x8 b0 = *(const bf16x8*)(Bb + 0 * 2048 + kx);
            bf16x8 b1 = *(const bf16x8*)(Bb + 1 * 2048 + kx);
            bf16x8 b2 = *(const bf16x8*)(Bb + 2 * 2048 + kx);
            bf16x8 b3 = *(const bf16x8*)(Bb + 3 * 2048 + kx);
            acc[0][0] = __builtin_amdgcn_mfma_f32_16x16x32_bf16(a0, b0, acc[0][0], 0, 0, 0);
            acc[0][1] = __builtin_amdgcn_mfma_f32_16x16x32_bf16(a0, b1, acc[0][1], 0, 0, 0);
            acc[0][2] = __builtin_amdgcn_mfma_f32_16x16x32_bf16(a0, b2, acc[0][2], 0, 0, 0);
            acc[0][3] = __builtin_amdgcn_mfma_f32_16x16x32_bf16(a0, b3, acc[0][3], 0, 0, 0);
            acc[1][0] = __builtin_amdgcn_mfma_f32_16x16x32_bf16(a1, b0, acc[1][0], 0, 0, 0);
            acc[1][1] = __builtin_amdgcn_mfma_f32_16x16x32_bf16(a1, b1, acc[1][1], 0, 0, 0);
            acc[1][2] = __builtin_amdgcn_mfma_f32_16x16x32_bf16(a1, b2, acc[1][2], 0, 0, 0);
            acc[1][3] = __builtin_amdgcn_mfma_f32_16x16x32_bf16(a1, b3, acc[1][3], 0, 0, 0);
            acc[2][0] = __builtin_amdgcn_mfma_f32_16x16x32_bf16(a2, b0, acc[2][0], 0, 0, 0);
            acc[2][1] = __builtin_amdgcn_mfma_f32_16x16x32_bf16(a2, b1, acc[2][1], 0, 0, 0);
            acc[2][2] = __builtin_amdgcn_mfma_f32_16x16x32_bf16(a2, b2, acc[2][2], 0, 0, 0);
            acc[2][3] = __builtin_amdgcn_mfma_f32_16x16x32_bf16(a2, b3, acc[2][3], 0, 0, 0);
            acc[3][0] = __builtin_amdgcn_mfma_f32_16x16x32_bf16(a3, b0, acc[3][0], 0, 0, 0);
            acc[3][1] = __builtin_amdgcn_mfma_f32_16x16x32_bf16(a3, b1, acc[3][1], 0, 0, 0);
            acc[3][2] = __builtin_amdgcn_mfma_f32_16x16x32_bf16(a3, b2, acc[3][2], 0, 0, 0);
            acc[3][3] = __builtin_amdgcn_mfma_f32_16x16x32_bf16(a3, b3, acc[3][3], 0, 0, 0);
        }
    }

#pragma unroll
    for (int mi = 0; mi < 4; mi++) {
#pragma unroll
        for (int ni = 0; ni < 4; ni++) {
            f32x4 a = acc[mi][ni];
            int n = n0 + wc * 64 + ni * 16 + lr;
#pragma unroll
            for (int j = 0; j < 4; j++) {
                int m = m0 + wr * 64 + mi * 16 + lg * 4 + j;
                if (m >= M) continue;
                float v = a[j];
                if (EPIL == 5) {
                    int half = N >> 1;
                    ushort* dst = (n < half) ? (ushort*)C : C2;
                    dst[(size_t)m * half + (n & (half - 1))] = f2bf(v);
                } else {
                    if (sizeof(OutT) == 2) ((ushort*)C)[(size_t)m * N + n] = f2bf(v);
                    else                   ((float*)C)[(size_t)m * N + n] = v;
                }
            }
        }
    }
}

// ==== fused gather + SAGE-1 epilogue: H1 = bn(relu(mean_j YL_j + b1 + YR)) ==
__global__ void gather_h1(const ushort* __restrict__ YL, const int* __restrict__ eidx,
                          const int* __restrict__ off, const ushort* __restrict__ YR,
                          const float* __restrict__ b1, const float* __restrict__ g,
                          const float* __restrict__ bb, ushort* __restrict__ H1)
{
    int n = blockIdx.x;
    int beg = off[n], end = off[n + 1];
    float inv = 1.f / fmaxf((float)(end - beg), 1.f);
    float s0 = 0, s1 = 0, s2 = 0, s3 = 0, s4 = 0, s5 = 0, s6 = 0, s7 = 0;
    for (int e = beg; e < end; e++) {
        ushort8v v = *(const ushort8v*)(YL + (size_t)eidx[e] * 1024 + threadIdx.x * 8);
        s0 += bf2f(v[0]); s1 += bf2f(v[1]); s2 += bf2f(v[2]); s3 += bf2f(v[3]);
        s4 += bf2f(v[4]); s5 += bf2f(v[5]); s6 += bf2f(v[6]); s7 += bf2f(v[7]);
    }
    float sv[8] = {s0, s1, s2, s3, s4, s5, s6, s7};
    ushort8v yr = *(const ushort8v*)(YR + (size_t)n * 1024 + threadIdx.x * 8);
    ushort8v o;
#pragma unroll
    for (int qq = 0; qq < 8; qq++) {
        int c = threadIdx.x * 8 + qq;
        float v = sv[qq] * inv + b1[c] + bf2f(yr[qq]);
        v = fmaxf(v, 0.f);
        v = g[c] * v * BN_INV + bb[c];
        o[qq] = f2bf(v);
    }
    *(ushort8v*)(H1 + (size_t)n * 1024 + threadIdx.x * 8) = o;
}

// ==== fused gather + SAGE-2 epilogue: XB = mean_j ZL_j + b2 + ZR ===========
__global__ void gather_xb(const ushort* __restrict__ ZL, const int* __restrict__ eidx,
                          const int* __restrict__ off, const ushort* __restrict__ ZR,
                          const float* __restrict__ b2, ushort* __restrict__ XB)
{
    int n = blockIdx.x;
    int beg = off[n], end = off[n + 1];
    float inv = 1.f / fmaxf((float)(end - beg), 1.f);
    float s0 = 0, s1 = 0, s2 = 0, s3 = 0, s4 = 0, s5 = 0, s6 = 0, s7 = 0;
    for (int e = beg; e < end; e++) {
        ushort8v v = *(const ushort8v*)(ZL + (size_t)eidx[e] * 512 + threadIdx.x * 8);
        s0 += bf2f(v[0]); s1 += bf2f(v[1]); s2 += bf2f(v[2]); s3 += bf2f(v[3]);
        s4 += bf2f(v[4]); s5 += bf2f(v[5]); s6 += bf2f(v[6]); s7 += bf2f(v[7]);
    }
    float sv[8] = {s0, s1, s2, s3, s4, s5, s6, s7};
    ushort8v zr = *(const ushort8v*)(ZR + (size_t)n * 512 + threadIdx.x * 8);
    ushort8v o;
#pragma unroll
    for (int qq = 0; qq < 8; qq++) {
        int c = threadIdx.x * 8 + qq;
        o[qq] = f2bf(sv[qq] * inv + b2[c] + bf2f(zr[qq]));
    }
    *(ushort8v*)(XB + (size_t)n * 512 + threadIdx.x * 8) = o;
}

// ==== fused attention MLP: A2 = tanh(XB@FA1^T + b1f)@FA2^T + b2f ===========
__global__ __launch_bounds__(256)
void attn_a1a2(const ushort* __restrict__ XB, const ushort* __restrict__ FA1,
               const float* __restrict__ fa1b, const ushort* __restrict__ FA2,
               const float* __restrict__ fa2b, float* __restrict__ A2, int M)
{
    __shared__ ushort As[128 * 64];
    __shared__ ushort Bs[128 * 64];
    __shared__ ushort A1a[128 * 64];
    __shared__ ushort A1b[128 * 64];

    const int tid  = threadIdx.x;
    const int lane = tid & 63;
    const int wid  = tid >> 6;
    const int wr   = wid >> 1;
    const int wc   = wid & 1;
    const int m0   = blockIdx.x * 128;
    const int lr   = lane & 15;
    const int lg   = lane >> 4;
    const int swz  = (lr & 7) << 4;

    f32x4 acc[4][4];
#pragma unroll
    for (int i = 0; i < 4; i++)
#pragma unroll
        for (int j = 0; j < 4; j++) acc[i][j] = (f32x4){0.f, 0.f, 0.f, 0.f};

    for (int k0 = 0; k0 < 512; k0 += 64) {
        if (k0) __syncthreads();
#pragma unroll
        for (int i = 0; i < 4; i++) {
            int ch = i * 256 + tid;
            int rr = ch >> 3, c8 = ch & 7;
            int c8p = c8 ^ (rr & 7);
            int srow = m0 + rr; if (srow > M - 1) srow = M - 1;
            gload16(XB + (size_t)srow * 512 + k0 + c8p * 8,
                    (char*)As + (i * 256 + wid * 64) * 16);
            gload16(FA1 + (size_t)rr * 512 + k0 + c8p * 8,
                    (char*)Bs + (i * 256 + wid * 64) * 16);
        }
        __syncthreads();
        const char* Ab = (const char*)As + (wr * 64 + lr) * 128;
        const char* Bb = (const char*)Bs + (wc * 64 + lr) * 128;
#pragma unroll
        for (int ks = 0; ks < 2; ks++) {
            int kx = (ks * 64 + lg * 16) ^ swz;
            bf16x8 a0 = *(const bf16x8*)(Ab + 0 * 2048 + kx);
            bf16x8 a1 = *(const bf16x8*)(Ab + 1 * 2048 + kx);
            bf16x8 a2 = *(const bf16x8*)(Ab + 2 * 2048 + kx);
            bf16x8 a3 = *(const bf16x8*)(Ab + 3 * 2048 + kx);
            bf16x8 b0 = *(const bf16x8*)(Bb + 0 * 2048 + kx);
            bf16x8 b1 = *(const bf16x8*)(Bb + 1 * 2048 + kx);
            bf16x8 b2 = *(const bf16x8*)(Bb + 2 * 2048 + kx);
            bf16x8 b3 = *(const bf16x8*)(Bb + 3 * 2048 + kx);
            acc[0][0] = __builtin_amdgcn_mfma_f32_16x16x32_bf16(a0, b0, acc[0][0], 0, 0, 0);
            acc[0][1] = __builtin_amdgcn_mfma_f32_16x16x32_bf16(a0, b1, acc[0][1], 0, 0, 0);
            acc[0][2] = __builtin_amdgcn_mfma_f32_16x16x32_bf16(a0, b2, acc[0][2], 0, 0, 0);
            acc[0][3] = __builtin_amdgcn_mfma_f32_16x16x32_bf16(a0, b3, acc[0][3], 0, 0, 0);
            acc[1][0] = __builtin_amdgcn_mfma_f32_16x16x32_bf16(a1, b0, acc[1][0], 0, 0, 0);
            acc[1][1] = __builtin_amdgcn_mfma_f32_16x16x32_bf16(a1, b1, acc[1][1], 0, 0, 0);
            acc[1][2] = __builtin_amdgcn_mfma_f32_16x16x32_bf16(a1, b2, acc[1][2], 0, 0, 0);
            acc[1][3] = __builtin_amdgcn_mfma_f32_16x16x32_bf16(a1, b3, acc[1][3], 0, 0, 0);
            acc[2][0] = __builtin_amdgcn_mfma_f32_16x16x32_bf16(a2, b0, acc[2][0], 0, 0, 0);
            acc[2][1] = __builtin_amdgcn_mfma_f32_16x16x32_bf16(a2, b1, acc[2][1], 0, 0, 0);
            acc[2][2] = __builtin_amdgcn_mfma_f32_16x16x32_bf16(a2, b2, acc[2][2], 0, 0, 0);
            acc[2][3] = __builtin_amdgcn_mfma_f32_16x16x32_bf16(a2, b3, acc[2][3], 0, 0, 0);
            acc[3][0] = __builtin_amdgcn_mfma_f32_16x16x32_bf16(a3, b0, acc[3][0], 0, 0, 0);
            acc[3][1] = __builtin_amdgcn_mfma_f32_16x16x32_bf16(a3, b1, acc[3][1], 0, 0, 0);
            acc[3][2] = __builtin_amdgcn_mfma_f32_16x16x32_bf16(a3, b2, acc[3][2], 0, 0, 0);
            acc[3][3] = __builtin_amdgcn_mfma_f32_16x16x32_bf16(a3, b3, acc[3][3], 0, 0, 0);
        }
    }

    // tanh + bias -> A1 in LDS (swizzled bf16, two 64-col halves)
#pragma unroll
    for (int mi = 0; mi < 4; mi++)
#pragma unroll
    for (int ni = 0; ni < 4; ni++) {
        f32x4 a = acc[mi][ni];
        int n = wc * 64 + ni * 16 + lr;
        ushort* buf = (n < 64) ? A1a : A1b;
        int c = n & 63;
#pragma unroll
        for (int j = 0; j < 4; j++) {
            int m = wr * 64 + mi * 16 + lg * 4 + j;
            float v = tanhf(a[j] + fa1b[n]);
            int byo = m * 128 + (((c >> 3) * 16) ^ ((m & 7) << 4)) + (c & 7) * 2;
            *(ushort*)((char*)buf + byo) = f2bf(v);
        }
    }
    __syncthreads();

#pragma unroll
    for (int i = 0; i < 4; i++) {
        int ch = i * 256 + tid;
        int rr = ch >> 3, c8 = ch & 7;
        int c8p = c8 ^ (rr & 7);
        gload16(FA2 + (size_t)rr * 128 + c8p * 8,
                (char*)As + (i * 256 + wid * 64) * 16);
        gload16(FA2 + (size_t)rr * 128 + 64 + c8p * 8,
                (char*)Bs + (i * 256 + wid * 64) * 16);
    }
    __syncthreads();

    f32x4 acc2[4][4];
#pragma unroll
    for (int i = 0; i < 4; i++)
#pragma unroll
        for (int j = 0; j < 4; j++) acc2[i][j] = (f32x4){0.f, 0.f, 0.f, 0.f};

#pragma unroll
    for (int kb = 0; kb < 2; kb++) {
        const char* Ab = (const char*)(kb ? A1b : A1a) + (wr * 64 + lr) * 128;
        const char* Bb = (const char*)(kb ? Bs : As) + (wc * 64 + lr) * 128;
#pragma unroll
        for (int ks = 0; ks < 2; ks++) {
            int kx = (ks * 64 + lg * 16) ^ swz;
            bf16x8 a0 = *(const bf16x8*)(Ab + 0 * 2048 + kx);
            bf16x8 a1 = *(const bf16x8*)(Ab + 1 * 2048 + kx);
            bf16x8 a2 = *(const bf16x8*)(Ab + 2 * 2048 + kx);
            bf16x8 a3 = *(const bf16x8*)(Ab + 3 * 2048 + kx);
            bf16x8 b0 = *(const bf16x8*)(Bb + 0 * 2048 + kx);
            bf16x8 b1 = *(const bf16x8*)(Bb + 1 * 2048 + kx);
            bf16x8 b2 = *(const bf16x8*)(Bb + 2 * 2048 + kx);
            bf16x8 b3 = *(const bf16x8*)(Bb + 3 * 2048 + kx);
            acc2[0][0] = __builtin_amdgcn_mfma_f32_16x16x32_bf16(a0, b0, acc2[0][0], 0, 0, 0);
            acc2[0][1] = __builtin_amdgcn_mfma_f32_16x16x32_bf16(a0, b1, acc2[0][1], 0, 0, 0);
            acc2[0][2] = __builtin_amdgcn_mfma_f32_16x16x32_bf16(a0, b2, acc2[0][2], 0, 0, 0);
            acc2[0][3] = __builtin_amdgcn_mfma_f32_16x16x32_bf16(a0, b3, acc2[0][3], 0, 0, 0);
            acc2[1][0] = __builtin_amdgcn_mfma_f32_16x16x32_bf16(a1, b0, acc2[1][0], 0, 0, 0);
            acc2[1][1] = __builtin_amdgcn_mfma_f32_16x16x32_bf16(a1, b1, acc2[1][1], 0, 0, 0);
            acc2[1][2] = __builtin_amdgcn_mfma_f32_16x16x32_bf16(a1, b2, acc2[1][2], 0, 0, 0);
            acc2[1][3] = __builtin_amdgcn_mfma_f32_16x16x32_bf16(a1, b3, acc2[1][3], 0, 0, 0);
            acc2[2][0] = __builtin_amdgcn_mfma_f32_16x16x32_bf16(a2, b0, acc2[2][0], 0, 0, 0);
            acc2[2][1] = __builtin_amdgcn_mfma_f32_16x16x32_bf16(a2, b1, acc2[2][1], 0, 0, 0);
            acc2[2][2] = __builtin_amdgcn_mfma_f32_16x16x32_bf16(a2, b2, acc2[2][2], 0, 0, 0);
            acc2[2][3] = __builtin_amdgcn_mfma_f32_16x16x32_bf16(a2, b3, acc2[2][3], 0, 0, 0);
            acc2[3][0] = __builtin_amdgcn_mfma_f32_16x16x32_bf16(a3, b0, acc2[3][0], 0, 0, 0);
            acc2[3][1] = __builtin_amdgcn_mfma_f32_16x16x32_bf16(a3, b1, acc2[3][1], 0, 0, 0);
            acc2[3][2] = __builtin_amdgcn_mfma_f32_16x16x32_bf16(a3, b2, acc2[3][2], 0, 0, 0);
            acc2[3][3] = __builtin_amdgcn_mfma_f32_16x16x32_bf16(a3, b3, acc2[3][3], 0, 0, 0);
        }
    }

#pragma unroll
    for (int mi = 0; mi < 4; mi++)
#pragma unroll
    for (int ni = 0; ni < 4; ni++) {
        f32x4 a = acc2[mi][ni];
        int n = wc * 64 + ni * 16 + lr;
#pragma unroll
        for (int j = 0; j < 4; j++) {
            int m = m0 + wr * 64 + mi * 16 + lg * 4 + j;
            if (m >= M) continue;
            A2[(size_t)m * 128 + n] = a[j] + fa2b[n];
        }
    }
}

// ============ split-K MFMA GEMM for emb: PART[z] = A[128,Kc]@B[N,Kc]^T =====
__global__ __launch_bounds__(256)
void mgemm_splitk(const ushort* __restrict__ Asrc, const ushort* __restrict__ Bsrc,
                  float* __restrict__ PART, int N, int Kp, int nsteps, int spz)
{
    __shared__ ushort As[128 * 64];
    __shared__ ushort Bs[128 * 64];

    const int tid  = threadIdx.x;
    const int lane = tid & 63;
    const int wid  = tid >> 6;
    const int wr   = wid >> 1;
    const int wc   = wid & 1;
    const int n0   = blockIdx.x * 128;
    const int z    = blockIdx.z;

    const int lr  = lane & 15;
    const int lg  = lane >> 4;
    const int swz = (lr & 7) << 4;

    f32x4 acc[4][4];
#pragma unroll
    for (int i = 0; i < 4; i++)
#pragma unroll
        for (int j = 0; j < 4; j++) acc[i][j] = (f32x4){0.f, 0.f, 0.f, 0.f};

    const int sb = z * spz;
    const int se = min(sb + spz, nsteps);

    for (int s = sb; s < se; s++) {
        int k0 = s * 64;
        if (s != sb) __syncthreads();
#pragma unroll
        for (int i = 0; i < 4; i++) {
            int ch = i * 256 + tid;
            int rr = ch >> 3, c8 = ch & 7;
            int c8p = c8 ^ (rr & 7);
            gload16(Asrc + (size_t)rr * Kp + k0 + c8p * 8,
                    (char*)As + (i * 256 + wid * 64) * 16);
            gload16(Bsrc + (size_t)(n0 + rr) * Kp + k0 + c8p * 8,
                    (char*)Bs + (i * 256 + wid * 64) * 16);
        }
        __syncthreads();

        const char* Ab = (const char*)As + (wr * 64 + lr) * 128;
        const char* Bb = (const char*)Bs + (wc * 64 + lr) * 128;
#pragma unroll
        for (int ks = 0; ks < 2; ks++) {
            int kx = (ks * 64 + lg * 16) ^ swz;
            bf16x8 a0 = *(const bf16x8*)(Ab + 0 * 2048 + kx);
            bf16x8 a1 = *(const bf16x8*)(Ab + 1 * 2048 + kx);
            bf16x8 a2 = *(const bf16x8*)(Ab + 2 * 2048 + kx);
            bf16x8 a3 = *(const bf16x8*)(Ab + 3 * 2048 + kx);
            bf16x8 b0 = *(const bf16x8*)(Bb + 0 * 2048 + kx);
            bf16x8 b1 = *(const bf16x8*)(Bb + 1 * 2048 + kx);
            bf16x8 b2 = *(const bf16x8*)(Bb + 2 * 2048 + kx);
            bf16x8 b3 = *(const bf16x8*)(Bb + 3 * 2048 + kx);
            acc[0][0] = __builtin_amdgcn_mfma_f32_16x16x32_bf16(a0, b0, acc[0][0], 0, 0, 0);
            acc[0][1] = __builtin_amdgcn_mfma_f32_16x16x32_bf16(a0, b1, acc[0][1], 0, 0, 0);
            acc[0][2] = __builtin_amdgcn_mfma_f32_16x16x32_bf16(a0, b2, acc[0][2], 0, 0, 0);
            acc[0][3] = __builtin_amdgcn_mfma_f32_16x16x32_bf16(a0, b3, acc[0][3], 0, 0, 0);
            acc[1][0] = __builtin_amdgcn_mfma_f32_16x16x32_bf16(a1, b0, acc[1][0], 0, 0, 0);
            acc[1][1] = __builtin_amdgcn_mfma_f32_16x16x32_bf16(a1, b1, acc[1][1], 0, 0, 0);
            acc[1][2] = __builtin_amdgcn_mfma_f32_16x16x32_bf16(a1, b2, acc[1][2], 0, 0, 0);
            acc[1][3] = __builtin_amdgcn_mfma_f32_16x16x32_bf16(a1, b3, acc[1][3], 0, 0, 0);
            acc[2][0] = __builtin_amdgcn_mfma_f32_16x16x32_bf16(a2, b0, acc[2][0], 0, 0, 0);
            acc[2][1] = __builtin_amdgcn_mfma_f32_16x16x32_bf16(a2, b1, acc[2][1], 0, 0, 0);
            acc[2][2] = __builtin_amdgcn_mfma_f32_16x16x32_bf16(a2, b2, acc[2][2], 0, 0, 0);
            acc[2][3] = __builtin_amdgcn_mfma_f32_16x16x32_bf16(a2, b3, acc[2][3], 0, 0, 0);
            acc[3][0] = __builtin_amdgcn_mfma_f32_16x16x32_bf16(a3, b0, acc[3][0], 0, 0, 0);
            acc[3][1] = __builtin_amdgcn_mfma_f32_16x16x32_bf16(a3, b1, acc[3][1], 0, 0, 0);
            acc[3][2] = __builtin_amdgcn_mfma_f32_16x16x32_bf16(a3, b2, acc[3][2], 0, 0, 0);
            acc[3][3] = __builtin_amdgcn_mfma_f32_16x16x32_bf16(a3, b3, acc[3][3], 0, 0, 0);
        }
    }

    float* outp = PART + (size_t)z * 128 * 512;
#pragma unroll
    for (int mi = 0; mi < 4; mi++) {
#pragma unroll
        for (int ni = 0; ni < 4; ni++) {
            f32x4 a = acc[mi][ni];
            int n = n0 + wc * 64 + ni * 16 + lr;
#pragma unroll
            for (int j = 0; j < 4; j++) {
                int m = wr * 64 + mi * 16 + lg * 4 + j;
                outp[(size_t)m * 512 + n] = a[j];
            }
        }
    }
}

__global__ void reduce_part(const float* __restrict__ PART, float* __restrict__ EMB, int Z)
{
    int idx = blockIdx.x * blockDim.x + threadIdx.x;   // 0..65535
    float s = 0.f;
    for (int z = 0; z < Z; z++) s += PART[(size_t)z * 65536 + idx];
    EMB[idx] = s;
}

// ==== fused attention prep: att_w_t (5024 blocks) + t_xb (1256 blocks) =====
__global__ __launch_bounds__(256)
void att_prep(const float* __restrict__ a2, const float* __restrict__ ms,
              const float* __restrict__ ss, ushort* __restrict__ W,
              const ushort* __restrict__ XB, ushort* __restrict__ XBT,
              int Nn, int Kp)
{
    __shared__ ushort tile[64][72];
    const int nAtt = (128 * Kp) >> 8;   // 5024
    const int bid = blockIdx.x;
    const int tid = threadIdx.x;
    if (bid < nAtt) {
        int idx = bid * 256 + tid;
        int c = idx / Kp, n = idx % Kp;
        float v = 0.f;
        if (n < Nn) v = expf(a2[(size_t)n * 128 + c] - ms[c]) / ss[c];
        W[idx] = f2bf(v);
    } else {
        int b2 = bid - nAtt;
        const int nx = Kp >> 6;          // 157
        const int n0 = (b2 % nx) * 64;
        const int d0 = (b2 / nx) * 64;
#pragma unroll
        for (int i = 0; i < 2; i++) {
            int ch = i * 256 + tid;
            int r = ch >> 3, c8 = ch & 7;
            int n = n0 + r;
            ushort8v v = {0, 0, 0, 0, 0, 0, 0, 0};
            if (n < Nn) v = *(const ushort8v*)(XB + (size_t)n * 512 + d0 + c8 * 8);
            *(ushort8v*)&tile[r][c8 * 8] = v;
        }
        __syncthreads();
#pragma unroll
        for (int i = 0; i < 2; i++) {
            int ch = i * 256 + tid;
            int dr = ch >> 3, n8 = ch & 7;
            ushort8v v;
#pragma unroll
            for (int q = 0; q < 8; q++) v[q] = tile[n8 * 8 + q][dr];
            *(ushort8v*)(XBT + (size_t)(d0 + dr) * Kp + n0 + n8 * 8) = v;
        }
    }
}

// ============ implicit-GEMM conv 3x3 stride2 pad1, NHWC bf16, IC=64 ========
template<int NI>
__global__ __launch_bounds__(256)
void conv_mfma(const ushort* __restrict__ in, const ushort* __restrict__ Wk,
               const float* __restrict__ bias, const float* __restrict__ gamma,
               const float* __restrict__ beta, ushort* __restrict__ outp,
               int IH, int IW, int OH, int OW)
{
    const int OC = NI * 16;
    __shared__ ushort As[128 * 64];
    __shared__ ushort Bs[NI * 16 * 64];

    const int tid  = threadIdx.x;
    const int lane = tid & 63;
    const int wv   = tid >> 6;
    const int lr   = lane & 15;
    const int lg   = lane >> 4;
    const int swz  = (lr & 7) << 4;
    const int m0   = blockIdx.x * 128;
    const int M    = OH * OW;

    f32x4 acc[2][NI];
#pragma unroll
    for (int i = 0; i < 2; i++)
#pragma unroll
        for (int j = 0; j < NI; j++) acc[i][j] = (f32x4){0.f, 0.f, 0.f, 0.f};

    for (int r = 0; r < 9; r++) {
        const int kh = r / 3, kw = r % 3;
        if (r) __syncthreads();
#pragma unroll
        for (int i = 0; i < 4; i++) {
            int ch = i * 256 + tid;
            int p = ch >> 3, c8 = ch & 7;
            int lb = p * 128 + ((c8 * 16) ^ ((p & 7) << 4));
            int gp = m0 + p; if (gp > M - 1) gp = M - 1;
            int oh = gp / OW, ow = gp % OW;
            int ih = oh * 2 - 1 + kh, iw = ow * 2 - 1 + kw;
            ushort8v v = {0, 0, 0, 0, 0, 0, 0, 0};
            if (ih >= 0 && ih < IH && iw >= 0 && iw < IW)
                v = *(const ushort8v*)(in + ((size_t)ih * IW + iw) * 64 + c8 * 8);
            *(ushort8v*)((char*)As + lb) = v;
        }
        for (int ch = tid; ch < OC * 8; ch += 256) {
            int oc = ch >> 3, c8 = ch & 7;
            int lb = oc * 128 + ((c8 * 16) ^ ((oc & 7) << 4));
            ushort8v v = *(const ushort8v*)(Wk + (size_t)oc * 576 + r * 64 + c8 * 8);
            *(ushort8v*)((char*)Bs + lb) = v;
        }
        __syncthreads();

        const char* Ab = (const char*)As + (wv * 32 + lr) * 128;
        const char* Bb = (const char*)Bs + lr * 128;
#pragma unroll
        for (int ks = 0; ks < 2; ks++) {
            int kx = (ks * 64 + lg * 16) ^ swz;
            bf16x8 a0 = *(const bf16x8*)(Ab + 0 * 2048 + kx);
            bf16x8 a1 = *(const bf16x8*)(Ab + 1 * 2048 + kx);
#pragma unroll
            for (int ni = 0; ni < NI; ni++) {
                bf16x8 bfr = *(const bf16x8*)(Bb + ni * 2048 + kx);
                acc[0][ni] = __builtin_amdgcn_mfma_f32_16x16x32_bf16(a0, bfr, acc[0][ni], 0, 0, 0);
                acc[1][ni] = __builtin_amdgcn_mfma_f32_16x16x32_bf16(a1, bfr, acc[1][ni], 0, 0, 0);
            }
        }
    }

#pragma unroll
    for (int mi = 0; mi < 2; mi++)
#pragma unroll
    for (int ni = 0; ni < NI; ni++) {
        f32x4 a = acc[mi][ni];
        int oc = ni * 16 + lr;
        float bv = bias[oc], gv = gamma[oc], btv = beta[oc];
#pragma unroll
        for (int j = 0; j < 4; j++) {
            int gp = m0 + wv * 32 + mi * 16 + lg * 4 + j;
            if (gp >= M) continue;
            float v = a[j] + bv;
            v = gv * v * BN_INV + btv;
            v = fmaxf(v, 0.f);
            outp[(size_t)gp * OC + oc] = f2bf(v);
        }
    }
}

// conv1: emb[128][512] f32 (1ch) -> e0[132][516][64] NHWC bf16, k3 s1 pad3, bn+relu
__global__ void conv1_nhwc(const float* __restrict__ emb, const float* __restrict__ w,
                           const float* __restrict__ b, const float* __restrict__ g,
                           const float* __restrict__ bb, ushort* __restrict__ outp)
{
    int oh = blockIdx.x;  // 0..131
    for (int idx = threadIdx.x; idx < 516 * 8; idx += 256) {
        int ow = idx >> 3, c8 = idx & 7;
        float pv[9];
#pragma unroll
        for (int kh = 0; kh < 3; kh++)
#pragma unroll
            for (int kw = 0; kw < 3; kw++) {
                int ih = oh - 3 + kh, iw = ow - 3 + kw;
                pv[kh * 3 + kw] = (ih >= 0 && ih < 128 && iw >= 0 && iw < 512)
                                  ? emb[ih * 512 + iw] : 0.f;
            }
        ushort8v o;
#pragma unroll
        for (int q = 0; q < 8; q++) {
            int oc = c8 * 8 + q;
            float v = b[oc];
#pragma unroll
            for (int i = 0; i < 9; i++) v = fmaf(pv[i], w[oc * 9 + i], v);
            v = g[oc] * v * BN_INV + bb[oc];
            v = fmaxf(v, 0.f);
            o[q] = f2bf(v);
        }
        *(ushort8v*)(outp + ((size_t)oh * 516 + ow) * 64 + c8 * 8) = o;
    }
}

// 3x3 maxpool s1 p1, NHWC bf16 (valid cells only)
__global__ void maxpool_nhwc(const ushort* __restrict__ in, ushort* __restrict__ out,
                             int H, int W, int C8)
{
    int h = blockIdx.x;
    int tot = W * C8;
    for (int idx = threadIdx.x; idx < tot; idx += blockDim.x) {
        int w0 = idx / C8, cg = idx % C8;
        float mx[8];
#pragma unroll
        for (int q = 0; q < 8; q++) mx[q] = -1e30f;
        for (int dh = -1; dh <= 1; dh++) {
            int hh = h + dh; if (hh < 0 || hh >= H) continue;
            for (int dw = -1; dw <= 1; dw++) {
                int ww = w0 + dw; if (ww < 0 || ww >= W) continue;
                ushort8v v = *(const ushort8v*)(in + ((size_t)hh * W + ww) * C8 * 8 + cg * 8);
#pragma unroll
                for (int q = 0; q < 8; q++) mx[q] = fmaxf(mx[q], bf2f(v[q]));
            }
        }
        ushort8v o;
#pragma unroll
        for (int q = 0; q < 8; q++) o[q] = f2bf(mx[q]);
        *(ushort8v*)(out + ((size_t)h * W + w0) * C8 * 8 + cg * 8) = o;
    }
}

// ==== conv2 + maxpool, single block; conv output kept in LDS; FLAT[432] out =
__global__ __launch_bounds__(256)
void conv2_pool(const ushort* __restrict__ in, const ushort* __restrict__ WC2,
                const float* __restrict__ c2b, const float* __restrict__ c2g,
                const float* __restrict__ c2bb, float* __restrict__ FLAT,
                int IH, int IW)
{
    __shared__ ushort As[128 * 64];
    __shared__ ushort Bs[16 * 64];
    __shared__ float E[27][16];

    const int tid  = threadIdx.x;
    const int lane = tid & 63;
    const int wv   = tid >> 6;
    const int lr   = lane & 15;
    const int lg   = lane >> 4;
    const int swz  = (lr & 7) << 4;
    const int OH = 3, OW = 9, M = 27;

    f32x4 acc[2];
    acc[0] = (f32x4){0.f, 0.f, 0.f, 0.f};
    acc[1] = (f32x4){0.f, 0.f, 0.f, 0.f};

    for (int r = 0; r < 9; r++) {
        const int kh = r / 3, kw = r % 3;
        if (r) __syncthreads();
#pragma unroll
        for (int i = 0; i < 4; i++) {
            int ch = i * 256 + tid;
            int p = ch >> 3, c8 = ch & 7;
            int lb = p * 128 + ((c8 * 16) ^ ((p & 7) << 4));
            int gp = p; if (gp > M - 1) gp = M - 1;
            int oh = gp / OW, ow = gp % OW;
            int ih = oh * 2 - 1 + kh, iw = ow * 2 - 1 + kw;
            ushort8v v = {0, 0, 0, 0, 0, 0, 0, 0};
            if (ih >= 0 && ih < IH && iw >= 0 && iw < IW)
                v = *(const ushort8v*)(in + ((size_t)ih * IW + iw) * 64 + c8 * 8);
            *(ushort8v*)((char*)As + lb) = v;
        }
        for (int ch = tid; ch < 16 * 8; ch += 256) {
            int oc = ch >> 3, c8 = ch & 7;
            int lb = oc * 128 + ((c8 * 16) ^ ((oc & 7) << 4));
            ushort8v v = *(const ushort8v*)(WC2 + (size_t)oc * 576 + r * 64 + c8 * 8);
            *(ushort8v*)((char*)Bs + lb) = v;
        }
        __syncthreads();

        const char* Ab = (const char*)As + (wv * 32 + lr) * 128;
        const char* Bb = (const char*)Bs + lr * 128;
#pragma unroll
        for (int ks = 0; ks < 2; ks++) {
            int kx = (ks * 64 + lg * 16) ^ swz;
            bf16x8 a0 = *(const bf16x8*)(Ab + 0 * 2048 + kx);
            bf16x8 a1 = *(const bf16x8*)(Ab + 1 * 2048 + kx);
            bf16x8 bfr = *(const bf16x8*)(Bb + kx);
            acc[0] = __builtin_amdgcn_mfma_f32_16x16x32_bf16(a0, bfr, acc[0], 0, 0, 0);
            acc[1] = __builtin_amdgcn_mfma_f32_16x16x32_bf16(a1, bfr, acc[1], 0, 0, 0);
        }
    }

#pragma unroll
    for (int mi = 0; mi < 2; mi++) {
        f32x4 a = acc[mi];
        int oc = lr;
        float bv = c2b[oc], gv = c2g[oc], btv = c2bb[oc];
#pragma unroll
        for (int j = 0; j < 4; j++) {
            int gp = wv * 32 + mi * 16 + lg * 4 + j;
            if (gp >= M) continue;
            float v = a[j] + bv;
            v = gv * v * BN_INV + btv;
            v = fmaxf(v, 0.f);
            E[gp][oc] = bf2f(f2bf(v));
        }
    }
    __syncthreads();

    for (int i = tid; i < 432; i += 256) {
        int c = i / 27, r = i % 27;
        int h = r / 9, w0 = r % 9;
        float m = -1e30f;
        for (int dh = -1; dh <= 1; dh++) {
            int hh = h + dh; if (hh < 0 || hh >= 3) continue;
            for (int dw = -1; dw <= 1; dw++) {
                int ww = w0 + dw; if (ww < 0 || ww >= 9) continue;
                m = fmaxf(m, E[hh * 9 + ww][c]);
            }
        }
        FLAT[i] = m;
    }
}

// ==== head fc1: T1[o] = fc1b[o] + sum_k FLAT[k]*fc1w[o][k]; 64 blocks ======
__global__ __launch_bounds__(256)
void head_fc1(const float* __restrict__ FLAT, const float* __restrict__ fc1w,
              const float* __restrict__ fc1b, float* __restrict__ T1)
{
    __shared__ float fl[432];
    const int tid = threadIdx.x;
    for (int i = tid; i < 432; i += 256) fl[i] = FLAT[i];
    __syncthreads();
    const int wv = tid >> 6, l = tid & 63;
    const int o = blockIdx.x * 16 + wv * 4;
#pragma unroll
    for (int j = 0; j < 4; j++) {
        int oo = o + j;
        const float* wr = fc1w + (size_t)oo * 432;
        float s = 0.f;
        for (int k = l; k < 432; k += 64) s = fmaf(fl[k], wr[k], s);
        for (int sh = 32; sh > 0; sh >>= 1) s += __shfl_down(s, sh, 64);
        if (l == 0) T1[oo] = s + fc1b[oo];
    }
}

// ==== head fc2 + sigmoid: out[14]; 1 block x 1024 ==========================
__global__ __launch_bounds__(1024)
void head_fc2(const float* __restrict__ T1, const float* __restrict__ fc2w,
              const float* __restrict__ fc2b, float* __restrict__ outp)
{
    __shared__ float t1[1024];
    const int tid = threadIdx.x;
    t1[tid] = T1[tid];
    __syncthreads();
    int o = tid >> 6, l = tid & 63;
    if (o < 14) {
        float s = 0.f;
        const float* wr = fc2w + (size_t)o * 1024;
        for (int k = l; k < 1024; k += 64) s = fmaf(t1[k], wr[k], s);
        for (int sh = 32; sh > 0; sh >>= 1) s += __shfl_down(s, sh, 64);
        if (l == 0) outp[o] = 1.f / (1.f + expf(-(s + fc2b[o])));
    }
}

// ---------------- fused weight prep + x convert -----------------------------
// items: [0, nx) -> x f32->bf16 (8/thread); [nx, nx+796672) -> weight cvt;
//        [nx+796672, nx+796672+46080) -> conv weight reorder.
__global__ void prep_cvt(const float* __restrict__ x, ushort* __restrict__ XBF, int nx,
                         const float* w1l, const float* w1r, const float* w2l,
                         const float* w2r, const float* fa1, const float* fa2,
                         const float* c1w, const float* c2w,
                         ushort* W1L, ushort* W1R, ushort* W2L, ushort* W2R,
                         ushort* FA1, ushort* FA2, ushort* WC1, ushort* WC2)
{
    int gi = blockIdx.x * blockDim.x + threadIdx.x;
    if (gi < nx) {
        const float4 f0 = *(const float4*)(x + (size_t)gi * 8);
        const float4 f1 = *(const float4*)(x + (size_t)gi * 8 + 4);
        ushort8v v;
        v[0] = f2bf(f0.x); v[1] = f2bf(f0.y); v[2] = f2bf(f0.z); v[3] = f2bf(f0.w);
        v[4] = f2bf(f1.x); v[5] = f2bf(f1.y); v[6] = f2bf(f1.z); v[7] = f2bf(f1.w);
        *(ushort8v*)(XBF + (size_t)gi * 8) = v;
        return;
    }
    int i = gi - nx;
    if (i < 796672) {
        const float* s; ushort* d; int j;
        if      (i < 327680)  { s = w1l; d = W1L; j = i; }
        else if (i < 655360)  { s = w1r; d = W1R; j = i - 327680; }
        else if (i < 720896)  { s = w2l; d = W2L; j = i - 655360; }
        else if (i < 786432)  { s = w2r; d = W2R; j = i - 720896; }
        else if (i < 794624)  { s = fa1; d = FA1; j = i - 786432; }
        else                  { s = fa2; d = FA2; j = i - 794624; }
        const float4 f0 = *(const float4*)(s + (size_t)j * 8);
        const float4 f1 = *(const float4*)(s + (size_t)j * 8 + 4);
        ushort8v v;
        v[0] = f2bf(f0.x); v[1] = f2bf(f0.y); v[2] = f2bf(f0.z); v[3] = f2bf(f0.w);
        v[4] = f2bf(f1.x); v[5] = f2bf(f1.y); v[6] = f2bf(f1.z); v[7] = f2bf(f1.w);
        *(ushort8v*)(d + (size_t)j * 8) = v;
    } else {
        int k = i - 796672;
        if (k >= 80 * 576) return;
        const float* w; ushort* wk; int idx;
        if (k < 64 * 576) { w = c1w; wk = WC1; idx = k; }
        else              { w = c2w; wk = WC2; idx = k - 64 * 576; }
        int oc = idx / 576, t = idx % 576;
        int r = t / 64, ic = t % 64;
        int kh = r / 3, kw = r % 3;
        wk[idx] = f2bf(w[((oc * 64 + ic) * 3 + kh) * 3 + kw]);
    }
}

// ---------------- parallel CSR build (4 dispatches) -------------------------
__global__ void hist_k(const int* __restrict__ dst, int* __restrict__ hist, int E)
{
    int e = blockIdx.x * blockDim.x + threadIdx.x;
    if (e < E) atomicAdd(&hist[dst[e]], 1);
}

__global__ __launch_bounds__(1024)
void scan_k(const int* __restrict__ hist, int* __restrict__ off, int n)
{
    __shared__ int tmp[1024];
    const int PT = (n + 1023) / 1024;
    int t = threadIdx.x;
    int b = t * PT;
    int ls = 0;
    for (int k = 0; k < PT; k++) { int i = b + k; if (i < n) ls += hist[i]; }
    tmp[t] = ls;
    __syncthreads();
    for (int s = 1; s < 1024; s <<= 1) {
        int v = (t >= s) ? tmp[t - s] : 0;
        __syncthreads();
        tmp[t] += v;
        __syncthreads();
    }
    int run = tmp[t] - ls;
    for (int k = 0; k < PT; k++) {
        int i = b + k;
        if (i < n) { off[i] = run; run += hist[i]; }
    }
    if (t == 1023) off[n] = tmp[1023];
}

__global__ void fill_k(const int* __restrict__ src, const int* __restrict__ dst,
                       const int* __restrict__ off, int* __restrict__ cursor,
                       int* __restrict__ eidx, int E)
{
    int e = blockIdx.x * blockDim.x + threadIdx.x;
    if (e >= E) return;
    int d = dst[e];
    int pos = atomicAdd(&cursor[d], 1);
    eidx[off[d] + pos] = src[e];
}

// ---------------- attention softmax over nodes ------------------------------
__global__ __launch_bounds__(256)
void softmax_stats(const float* __restrict__ a2, float* __restrict__ ms,
                   float* __restrict__ ss, int Nn)
{
    int c = blockIdx.x;
    __shared__ float red[256];
    float mx = -1e30f;
    for (int n = threadIdx.x; n < Nn; n += 256)
        mx = fmaxf(mx, a2[(size_t)n * 128 + c]);
    red[threadIdx.x] = mx;
    __syncthreads();
    for (int s = 128; s > 0; s >>= 1) {
        if (threadIdx.x < s) red[threadIdx.x] = fmaxf(red[threadIdx.x], red[threadIdx.x + s]);
        __syncthreads();
    }
    mx = red[0];
    __syncthreads();
    float sum = 0.f;
    for (int n = threadIdx.x; n < Nn; n += 256)
        sum += expf(a2[(size_t)n * 128 + c] - mx);
    red[threadIdx.x] = sum;
    __syncthreads();
    for (int s = 128; s > 0; s >>= 1) {
        if (threadIdx.x < s) red[threadIdx.x] += red[threadIdx.x + s];
        __syncthreads();
    }
    if (threadIdx.x == 0) { ms[c] = mx; ss[c] = red[0]; }
}

// ---------------------------------------------------------------------------
extern "C" void kernel_launch(void* const* d_in, const int* in_sizes, int n_in,
                              void* d_out, int out_size, void* d_ws, size_t ws_size,
                              hipStream_t stream)
{
    const float* x     = (const float*)d_in[0];
    const int*   ei    = (const int*)d_in[1];
    const float* w1l   = (const float*)d_in[2];
    const float* b1    = (const float*)d_in[3];
    const float* w1r   = (const float*)d_in[4];
    const float* bn1g  = (const float*)d_in[5];
    const float* bn1b  = (const float*)d_in[6];
    const float* w2l   = (const float*)d_in[7];
    const float* b2    = (const float*)d_in[8];
    const float* w2r   = (const float*)d_in[9];
    const float* fa1w  = (const float*)d_in[10];
    const float* fa1b  = (const float*)d_in[11];
    const float* fa2w  = (const float*)d_in[12];
    const float* fa2b  = (const float*)d_in[13];
    const float* cnn1w = (const float*)d_in[14];
    const float* cnn1b = (const float*)d_in[15];
    const float* normg = (const float*)d_in[16];
    const float* normb = (const float*)d_in[17];
    const float* c1w   = (const float*)d_in[18];
    const float* c1b   = (const float*)d_in[19];
    const float* c1g   = (const float*)d_in[20];
    const float* c1bb  = (const float*)d_in[21];
    const float* c2w   = (const float*)d_in[22];
    const float* c2b   = (const float*)d_in[23];
    const float* c2g   = (const float*)d_in[24];
    const float* c2bb  = (const float*)d_in[25];
    const float* fc1w  = (const float*)d_in[26];
    const float* fc1b  = (const float*)d_in[27];
    const float* fc2w  = (const float*)d_in[28];
    const float* fc2b  = (const float*)d_in[29];
    float* out = (float*)d_out;

    const int Nn = 10000, E = 160000;
    const int Kp = 10048;   // 157*64
    char* ws = (char*)d_ws;

    // ---- workspace layout (bytes) — phase-checked, no live overlaps ----
    ushort* YL    = (ushort*)(ws + 0);           // 20,480,000
    ushort* ATTWT = (ushort*)(ws + 0);           // 2,572,288 (YL dead after gather_h1)
    ushort* XBT   = (ushort*)(ws + 2572288);     // -> 12,861,440
    ushort* P16   = (ushort*)(ws + 0);           // 8,718,336
    ushort* Q16   = (ushort*)(ws + 13000000);    // -> 15,179,584
    ushort* H1   = (ushort*)(ws + 20480000);     // 20,480,000
    ushort* XB   = (ushort*)(ws + 20480000);     // 10,240,000
    float*  A2   = (float*)(ws + 33280000);      // 5,120,000 -> 38,400,000
    ushort* YR   = (ushort*)(ws + 40960000);     // 20,480,000
    ushort* ZL   = (ushort*)(ws + 40960000);     // 10,240,000
    ushort* ZR   = (ushort*)(ws + 51200000);     // -> 61,440,000
    float*  PART = (float*)(ws + 40960000);      // 10,485,760 (ZL/ZR dead by splitk)
    int*   hist   = (int*)(ws + 61440000);       // 40,000
    int*   cursor = (int*)(ws + 61480000);       // 40,000
    int*   off    = (int*)(ws + 61520000);       // 40,004
    int*   eidx   = (int*)(ws + 61560128);       // 640,000 -> 62,200,128
    float* FLAT  = (float*)(ws + 62300032);      // 432 f32
    float* T1    = (float*)(ws + 62310016);      // 1024 f32
    float*  MS   = (float*)(ws + 67360128);
    float*  SS   = (float*)(ws + 67360640);
    float*  EMB  = (float*)(ws + 67361152);      // -> 67,623,296
    ushort* W1L = (ushort*)(ws + 67623296);      // W1L+W1R contiguous = [2048][2560]
    ushort* W1R = (ushort*)(ws + 72866176);
    ushort* W2L = (ushort*)(ws + 78109056);      // W2L+W2R contiguous = [1024][1024]
    ushort* W2R = (ushort*)(ws + 79157632);
    ushort* FA1 = (ushort*)(ws + 80206208);
    ushort* FA2 = (ushort*)(ws + 80337280);
    ushort* WC1 = (ushort*)(ws + 80370048);
    ushort* WC2 = (ushort*)(ws + 80443776);      // -> 80,462,208
    ushort* XBF = (ushort*)(ws + 80462208);      // 51,200,000 -> 131,662,208
    const bool use_xbf = (ws_size >= (size_t)131662208);

    const int* src = ei;
    const int* dst = ei + E;

    // ---- fused weight prep + x convert (1) + parallel CSR build (4) ----
    {
        int nx = use_xbf ? 3200000 : 0;
        int items = nx + 796672 + 80 * 576;
        prep_cvt<<<(items + 255) / 256, 256, 0, stream>>>(
            x, XBF, nx, w1l, w1r, w2l, w2r, fa1w, fa2w, c1w, c2w,
            W1L, W1R, W2L, W2R, FA1, FA2, WC1, WC2);
    }
    hipMemsetAsync(hist, 0, 80000, stream);   // hist + cursor (adjacent)
    hist_k<<<(E + 255) / 256, 256, 0, stream>>>(dst, hist, E);
    scan_k<<<1, 1024, 0, stream>>>(hist, off, Nn);
    fill_k<<<(E + 255) / 256, 256, 0, stream>>>(src, dst, off, cursor, eidx, E);

    const int GY = (Nn + 127) / 128;   // 79

    // ---- SAGE layer 1: fused [YL | YR] = x @ [W1L;W1R]^T (N=2048) ----
    if (use_xbf) {
        mgemm<0, 5, ushort><<<dim3(2048 / 128, GY), 256, 0, stream>>>(
            XBF, W1L, YL, Nn, 2048, 2560, nullptr, YR);
    } else {
        mgemm<1, 5, ushort><<<dim3(2048 / 128, GY), 256, 0, stream>>>(
            x, W1L, YL, Nn, 2048, 2560, nullptr, YR);
    }
    gather_h1<<<Nn, 128, 0, stream>>>(YL, eidx, off, YR, b1, bn1g, bn1b, H1);

    // ---- SAGE layer 2: fused [ZL | ZR] = h1 @ [W2L;W2R]^T (N=1024) ----
    mgemm<0, 5, ushort><<<dim3(1024 / 128, GY), 256, 0, stream>>>(
        H1, W2L, ZL, Nn, 1024, 1024, nullptr, ZR);
    gather_xb<<<Nn, 64, 0, stream>>>(ZL, eidx, off, ZR, b2, XB);

    // ---- attention (fused MLP + fused prep) ----
    attn_a1a2<<<GY, 256, 0, stream>>>(XB, FA1, fa1b, FA2, fa2b, A2, Nn);
    softmax_stats<<<128, 256, 0, stream>>>(A2, MS, SS, Nn);
    att_prep<<<(128 * Kp) / 256 + (Kp / 64) * 8, 256, 0, stream>>>(
        A2, MS, SS, ATTWT, XB, XBT, Nn, Kp);
    mgemm_splitk<<<dim3(4, 1, 40), 256, 0, stream>>>(ATTWT, XBT, PART, 512, Kp, 157, 4);
    reduce_part<<<256, 256, 0, stream>>>(PART, EMB, 40);

    // ---- CNN (separate kernels) ----
    conv1_nhwc<<<132, 256, 0, stream>>>(EMB, cnn1w, cnn1b, normg, normb, P16);
    int H = 132, W = 516;
    for (int it = 0; it < 5; it++) {
        int OH = (H - 1) / 2 + 1, OW = (W - 1) / 2 + 1;
        int M = OH * OW;
        conv_mfma<4><<<(M + 127) / 128, 256, 0, stream>>>(
            P16, WC1, c1b, c1g, c1bb, Q16, H, W, OH, OW);
        maxpool_nhwc<<<OH, 256, 0, stream>>>(Q16, P16, OH, OW, 8);
        H = OH; W = OW;
    }
    // conv2 + pool (single block, LDS-resident), then parallel head
    conv2_pool<<<1, 256, 0, stream>>>(P16, WC2, c2b, c2g, c2bb, FLAT, H, W);
    head_fc1<<<64, 256, 0, stream>>>(FLAT, fc1w, fc1b, T1);
    head_fc2<<<1, 1024, 0, stream>>>(T1, fc2w, fc2b, out);
}